// Round 1
// baseline (13993.871 us; speedup 1.0000x reference)
//
#include <hip/hip_runtime.h>
#include <hip/hip_bf16.h>
#include <math.h>

#define IMG   128
#define PATCH 8
#define Hdim  768
#define Edim  1536
#define Kdim  128
#define Ltok  256
#define PDim  192
#define NLAY  24
#define Bsz   16
#define Mrows 4096          // B * L
#define UVW   3328          // 2E + 2K

// ---------------- RoPE table: pe[l][j], l in [0,256), j in [0,128) ----------
__global__ void pe_kernel(float* __restrict__ pe) {
    int l = blockIdx.x;
    int j = threadIdx.x;
    const float c = -logf(1000.0f) / 31.0f;
    int   sub = j & 31;
    float f   = expf(c * (float)sub);
    float pos = (j < 64) ? (float)(l >> 4) : (float)(l & 15);
    float ang = pos * f;
    pe[l * 128 + j] = ((j & 32) == 0) ? sinf(ang) : cosf(ang);
}

// ---------------- patchify: x (B,3,128,128) -> xp (B*L, 192) ----------------
__global__ void patchify_kernel(const float* __restrict__ x, float* __restrict__ xp) {
    int bc = blockIdx.x;              // b*384 + c*128 + iy
    int iy = bc & 127;
    int t  = bc >> 7;
    int c  = t % 3;
    int b  = t / 3;
    int ix = threadIdx.x;
    float v = x[((size_t)(b * 3 + c) * IMG + iy) * IMG + ix];
    int gy = iy >> 3, py = iy & 7, gx = ix >> 3, px = ix & 7;
    xp[(size_t)(b * Ltok + gy * 16 + gx) * PDim + (py * 8 + px) * 3 + c] = v;
}

// ---------------- generic fp32 GEMM: C[M,N] (+)= A[M,K] @ B[K,N] ------------
// grid: (N/64, M/64, batch); block 256. 64x64 tile, 4x4 per thread.
template <int ACC>
__launch_bounds__(256)
__global__ void gemm_kernel(const float* __restrict__ A, int lda, long long sA,
                            const float* __restrict__ B, int ldb, long long sB,
                            float* __restrict__ C, int ldc, long long sC,
                            int Kt) {
    A += (long long)blockIdx.z * sA;
    B += (long long)blockIdx.z * sB;
    C += (long long)blockIdx.z * sC;
    __shared__ float As[16][64];
    __shared__ float Bs[16][64];
    int tid = threadIdx.x;
    int tx = tid & 15, ty = tid >> 4;
    int row0 = blockIdx.y * 64, col0 = blockIdx.x * 64;
    int am = tid >> 2;            // 0..63
    int ak = (tid & 3) * 4;       // 0,4,8,12
    int bk = tid >> 4;            // 0..15
    int bn = (tid & 15) * 4;      // 0..60
    float acc[4][4] = {};
    for (int k0 = 0; k0 < Kt; k0 += 16) {
        float4 av = *(const float4*)&A[(size_t)(row0 + am) * lda + k0 + ak];
        float4 bv = *(const float4*)&B[(size_t)(k0 + bk) * ldb + col0 + bn];
        As[ak + 0][am] = av.x;
        As[ak + 1][am] = av.y;
        As[ak + 2][am] = av.z;
        As[ak + 3][am] = av.w;
        *(float4*)&Bs[bk][bn] = bv;
        __syncthreads();
#pragma unroll
        for (int k = 0; k < 16; ++k) {
            float4 a = *(const float4*)&As[k][ty * 4];
            float4 b = *(const float4*)&Bs[k][tx * 4];
            float ar[4] = {a.x, a.y, a.z, a.w};
            float br[4] = {b.x, b.y, b.z, b.w};
#pragma unroll
            for (int i = 0; i < 4; ++i)
#pragma unroll
                for (int j = 0; j < 4; ++j)
                    acc[i][j] = fmaf(ar[i], br[j], acc[i][j]);
        }
        __syncthreads();
    }
#pragma unroll
    for (int i = 0; i < 4; ++i) {
        float* cp = &C[(size_t)(row0 + ty * 4 + i) * ldc + col0 + tx * 4];
        float4 cv;
        if (ACC) {
            cv = *(const float4*)cp;
            cv.x += acc[i][0]; cv.y += acc[i][1]; cv.z += acc[i][2]; cv.w += acc[i][3];
        } else {
            cv.x = acc[i][0]; cv.y = acc[i][1]; cv.z = acc[i][2]; cv.w = acc[i][3];
        }
        *(float4*)cp = cv;
    }
}

// ---------------- h += t_emb[t_idx[b]] --------------------------------------
__global__ void bias_kernel(float* __restrict__ h, const float* __restrict__ t_emb,
                            const int* __restrict__ t_idx) {
    int r = blockIdx.x;
    int b = r >> 8;
    const float* e = t_emb + (size_t)t_idx[b] * Hdim;
    float* hr = h + (size_t)r * Hdim;
    for (int i = threadIdx.x; i < Hdim; i += 256) hr[i] += e[i];
}

// ---------------- rmsnorm: y = x / (rms + 1e-6) * w --------------------------
__global__ void rmsnorm_kernel(const float* __restrict__ x, const float* __restrict__ w,
                               float* __restrict__ y) {
    int r = blockIdx.x, tid = threadIdx.x;
    const float* xr = x + (size_t)r * Hdim;
    float v0 = xr[tid], v1 = xr[tid + 256], v2 = xr[tid + 512];
    __shared__ float red[256];
    red[tid] = v0 * v0 + v1 * v1 + v2 * v2;
    __syncthreads();
    for (int off = 128; off; off >>= 1) {
        if (tid < off) red[tid] += red[tid + off];
        __syncthreads();
    }
    float rms = sqrtf(red[0] / (float)Hdim);
    float s = 1.0f / (rms + 1e-6f);
    float* yr = y + (size_t)r * Hdim;
    yr[tid]       = v0 * s * w[tid];
    yr[tid + 256] = v1 * s * w[tid + 256];
    yr[tid + 512] = v2 * s * w[tid + 512];
}

// ---------------- silu(u), silu(v), rope(q), rope(k) in place ----------------
__global__ void act_kernel(float* __restrict__ uvqk, const float* __restrict__ pe) {
    int r = blockIdx.x;
    int tid = threadIdx.x;
    size_t base = (size_t)r * UVW;
    for (int i = tid; i < 2 * Edim; i += 256) {
        float xv = uvqk[base + i];
        uvqk[base + i] = xv / (1.0f + expf(-xv));
    }
    int l = r & 255;
    const float* p = pe + l * 128;
    if (tid < 128) {
        int qb = (tid < 64) ? 3072 : 3200;   // q block or k block
        int d  = tid & 63;
        float x1 = uvqk[base + qb + d];
        float x2 = uvqk[base + qb + 64 + d];
        float sn = p[d];        // pe[:, :64]  (the "sin" var in reference)
        float cs = p[64 + d];   // pe[:, 64:]  (the "cos" var)
        uvqk[base + qb + d]      = x1 * cs - x2 * sn;
        uvqk[base + qb + 64 + d] = x2 * cs + x1 * sn;
    }
}

// ---------------- scores + softmax: attn[b,i,:] ------------------------------
__global__ void attn_kernel(const float* __restrict__ uvqk, float* __restrict__ attn) {
    int bi = blockIdx.x;
    int b = bi >> 8, i = bi & 255;
    int tid = threadIdx.x;
    __shared__ float qs[128];
    __shared__ float red[256];
    if (tid < 128) qs[tid] = uvqk[(size_t)(b * Ltok + i) * UVW + 3072 + tid];
    __syncthreads();
    const float* kr = uvqk + (size_t)(b * Ltok + tid) * UVW + 3200;
    float s = 0.f;
#pragma unroll
    for (int d = 0; d < 128; d += 4) {
        float4 kv = *(const float4*)&kr[d];
        float4 qv = *(const float4*)&qs[d];
        s += qv.x * kv.x + qv.y * kv.y + qv.z * kv.z + qv.w * kv.w;
    }
    s *= 0.08838834764831845f;   // 128^-0.5
    red[tid] = s;
    __syncthreads();
    for (int off = 128; off; off >>= 1) {
        if (tid < off) red[tid] = fmaxf(red[tid], red[tid + off]);
        __syncthreads();
    }
    float mx = red[0];
    __syncthreads();
    float e = expf(s - mx);
    red[tid] = e;
    __syncthreads();
    for (int off = 128; off; off >>= 1) {
        if (tid < off) red[tid] += red[tid + off];
        __syncthreads();
    }
    attn[(size_t)bi * 256 + tid] = e / red[0];
}

// ---------------- o *= silu(u) -----------------------------------------------
__global__ void umul_kernel(float* __restrict__ o, const float* __restrict__ uvqk) {
    int r = blockIdx.x, tid = threadIdx.x;          // block 384
    float4* o4 = (float4*)(o + (size_t)r * Edim);
    const float4* u4 = (const float4*)(uvqk + (size_t)r * UVW);
    float4 ov = o4[tid], uv = u4[tid];
    ov.x *= uv.x; ov.y *= uv.y; ov.z *= uv.z; ov.w *= uv.w;
    o4[tid] = ov;
}

// ---------------- unpatchify: y (B*L,192) -> out (B,3,128,128) ---------------
__global__ void unpatch_kernel(const float* __restrict__ y, float* __restrict__ out) {
    int bc = blockIdx.x;
    int iy = bc & 127;
    int t  = bc >> 7;
    int c  = t % 3;
    int b  = t / 3;
    int ix = threadIdx.x;
    int gy = iy >> 3, py = iy & 7, gx = ix >> 3, px = ix & 7;
    out[((size_t)(b * 3 + c) * IMG + iy) * IMG + ix] =
        y[(size_t)(b * Ltok + gy * 16 + gx) * PDim + (py * 8 + px) * 3 + c];
}

extern "C" void kernel_launch(void* const* d_in, const int* in_sizes, int n_in,
                              void* d_out, int out_size, void* d_ws, size_t ws_size,
                              hipStream_t stream) {
    const float* x        = (const float*)d_in[0];
    const int*   t_idx    = (const int*)  d_in[1];
    const float* patch_W  = (const float*)d_in[2];
    const float* t_emb    = (const float*)d_in[3];
    const float* Wuv      = (const float*)d_in[4];
    const float* Wout     = (const float*)d_in[5];
    const float* gnorm    = (const float*)d_in[6];
    const float* fnorm    = (const float*)d_in[7];
    const float* unpatchW = (const float*)d_in[8];
    float* out = (float*)d_out;

    // workspace layout (floats)
    float* ws = (float*)d_ws;
    size_t need = 0;
    float* pe   = ws + need; need += 256 * 128;
    float* xp   = ws + need; need += (size_t)Mrows * PDim;   // reused for final y
    float* h    = ws + need; need += (size_t)Mrows * Hdim;
    float* xn   = ws + need; need += (size_t)Mrows * Hdim;
    float* uvqk = ws + need; need += (size_t)Mrows * UVW;
    float* attn = ws + need; need += (size_t)Bsz * Ltok * Ltok;
    float* o    = ws + need; need += (size_t)Mrows * Edim;
    if (ws_size < need * sizeof(float)) return;   // distinct failure signature (out stays 0)

    pe_kernel<<<256, 128, 0, stream>>>(pe);
    patchify_kernel<<<Bsz * 3 * IMG, IMG, 0, stream>>>(x, xp);
    gemm_kernel<0><<<dim3(Hdim / 64, Mrows / 64, 1), 256, 0, stream>>>(
        xp, PDim, 0, patch_W, Hdim, 0, h, Hdim, 0, PDim);
    bias_kernel<<<Mrows, 256, 0, stream>>>(h, t_emb, t_idx);

    for (int l = 0; l < NLAY; ++l) {
        rmsnorm_kernel<<<Mrows, 256, 0, stream>>>(h, gnorm + (size_t)l * Hdim, xn);
        gemm_kernel<0><<<dim3(UVW / 64, Mrows / 64, 1), 256, 0, stream>>>(
            xn, Hdim, 0, Wuv + (size_t)l * Hdim * UVW, UVW, 0, uvqk, UVW, 0, Hdim);
        act_kernel<<<Mrows, 256, 0, stream>>>(uvqk, pe);
        attn_kernel<<<Bsz * Ltok, 256, 0, stream>>>(uvqk, attn);
        gemm_kernel<0><<<dim3(Edim / 64, Ltok / 64, Bsz), 256, 0, stream>>>(
            attn, Ltok, (long long)Ltok * Ltok,
            uvqk + Edim, UVW, (long long)Ltok * UVW,
            o, Edim, (long long)Ltok * Edim, Ltok);
        umul_kernel<<<Mrows, 384, 0, stream>>>(o, uvqk);
        gemm_kernel<1><<<dim3(Hdim / 64, Mrows / 64, 1), 256, 0, stream>>>(
            o, Edim, 0, Wout + (size_t)l * Edim * Hdim, Hdim, 0, h, Hdim, 0, Edim);
    }

    rmsnorm_kernel<<<Mrows, 256, 0, stream>>>(h, fnorm, xn);
    gemm_kernel<0><<<dim3(PDim / 64, Mrows / 64, 1), 256, 0, stream>>>(
        xn, Hdim, 0, unpatchW, PDim, 0, xp, PDim, 0, Hdim);
    unpatch_kernel<<<Bsz * 3 * IMG, IMG, 0, stream>>>(xp, out);
}

// Round 2
// 5592.381 us; speedup vs baseline: 2.5023x; 2.5023x over previous
//
#include <hip/hip_runtime.h>
#include <math.h>

#define IMG   128
#define Hdim  768
#define Edim  1536
#define Kdim  128
#define Ltok  256
#define PDim  192
#define NLAY  24
#define Bsz   16
#define Mrows 4096          // B * L
#define UVW   3328          // 2E + 2K

typedef __bf16 bf16x8 __attribute__((ext_vector_type(8)));
typedef float  f32x4  __attribute__((ext_vector_type(4)));

__device__ __forceinline__ unsigned short f2b(float f) {
    unsigned int u = __float_as_uint(f);
    unsigned int r = (u + 0x7FFF + ((u >> 16) & 1)) >> 16;
    return (unsigned short)r;
}

__device__ __forceinline__ void gload16(const void* g, void* l) {
    __builtin_amdgcn_global_load_lds(
        (const __attribute__((address_space(1))) void*)g,
        (__attribute__((address_space(3))) void*)l, 16, 0, 0);
}

// ---------------- RoPE table ----------------
__global__ void pe_kernel(float* __restrict__ pe) {
    int l = blockIdx.x;
    int j = threadIdx.x;
    const float c = -logf(1000.0f) / 31.0f;
    int   sub = j & 31;
    float f   = expf(c * (float)sub);
    float pos = (j < 64) ? (float)(l >> 4) : (float)(l & 15);
    float ang = pos * f;
    pe[l * 128 + j] = ((j & 32) == 0) ? sinf(ang) : cosf(ang);
}

// ---------------- patchify -> bf16 ----------------
__global__ void patchify_kernel(const float* __restrict__ x, unsigned short* __restrict__ xp) {
    int bc = blockIdx.x;
    int iy = bc & 127;
    int t  = bc >> 7;
    int c  = t % 3;
    int b  = t / 3;
    int ix = threadIdx.x;
    float v = x[((size_t)(b * 3 + c) * IMG + iy) * IMG + ix];
    int gy = iy >> 3, py = iy & 7, gx = ix >> 3, px = ix & 7;
    xp[(size_t)(b * Ltok + gy * 16 + gx) * PDim + (py * 8 + px) * 3 + c] = f2b(v);
}

// ---------------- fp32 [R][C] (ldS) -> bf16 transposed [C][R] (ldD) ----------------
__global__ void trans_kernel(const float* __restrict__ src, int ldS, long long sS,
                             unsigned short* __restrict__ dst, int ldD, long long sD) {
    src += (long long)blockIdx.z * sS;
    dst += (long long)blockIdx.z * sD;
    __shared__ float t[32][33];
    int c0 = blockIdx.x * 32, r0 = blockIdx.y * 32;
    int tx = threadIdx.x, ty = threadIdx.y;   // (32,8)
#pragma unroll
    for (int i = 0; i < 4; ++i)
        t[ty + 8 * i][tx] = src[(size_t)(r0 + ty + 8 * i) * ldS + c0 + tx];
    __syncthreads();
#pragma unroll
    for (int i = 0; i < 4; ++i)
        dst[(size_t)(c0 + ty + 8 * i) * ldD + r0 + tx] = f2b(t[tx][ty + 8 * i]);
}

// ---------------- bf16 MFMA GEMM (m97 structure) ----------------
// C[M,N] (+)= A[M,K] @ Bt[N,K]^T ; 128x128 tile, BK=32, 4 waves of 64x64.
template <int ACC>
__launch_bounds__(256)
__global__ void gemm_bf16(const unsigned short* __restrict__ A, int lda, long long sA,
                          const unsigned short* __restrict__ Bt, int ldb, long long sB,
                          float* __restrict__ C, int ldc, long long sC,
                          int Kt, int Nt) {
    A  += (long long)blockIdx.z * sA;
    Bt += (long long)blockIdx.z * sB;
    C  += (long long)blockIdx.z * sC;
    __shared__ unsigned short lsA[128 * 32];
    __shared__ unsigned short lsB[128 * 32];
    int tid  = threadIdx.x;
    int lane = tid & 63, w = tid >> 6, wr = w >> 1, wc = w & 1;
    int row0 = blockIdx.y * 128, col0 = blockIdx.x * 128;
    int fr = lane & 15, fk = (lane >> 4) * 8;
    f32x4 acc[4][4] = {};

    for (int k0 = 0; k0 < Kt; k0 += 32) {
#pragma unroll
        for (int i = 0; i < 2; ++i) {
            int c  = tid + 256 * i;
            int ar = row0 + (c >> 2);
            gload16(A + (size_t)ar * lda + k0 + (c & 3) * 8, lsA + (size_t)c * 8);
            int bn = col0 + (c >> 2);
            if (bn > Nt - 1) bn = Nt - 1;
            gload16(Bt + (size_t)bn * ldb + k0 + (c & 3) * 8, lsB + (size_t)c * 8);
        }
        __syncthreads();
        bf16x8 af[4], bfr[4];
#pragma unroll
        for (int m = 0; m < 4; ++m)
            af[m] = *(const bf16x8*)(lsA + (wr * 64 + m * 16 + fr) * 32 + fk);
#pragma unroll
        for (int n = 0; n < 4; ++n)
            bfr[n] = *(const bf16x8*)(lsB + (wc * 64 + n * 16 + fr) * 32 + fk);
#pragma unroll
        for (int m = 0; m < 4; ++m)
#pragma unroll
            for (int n = 0; n < 4; ++n)
                acc[m][n] = __builtin_amdgcn_mfma_f32_16x16x32_bf16(af[m], bfr[n], acc[m][n], 0, 0, 0);
        __syncthreads();
    }

    int crow = (lane >> 4) * 4;
#pragma unroll
    for (int m = 0; m < 4; ++m) {
#pragma unroll
        for (int n = 0; n < 4; ++n) {
            int gc = col0 + wc * 64 + n * 16 + fr;
            if (gc >= Nt) continue;
#pragma unroll
            for (int j = 0; j < 4; ++j) {
                size_t idx = (size_t)(row0 + wr * 64 + m * 16 + crow + j) * ldc + gc;
                if (ACC) C[idx] += acc[m][n][j];
                else     C[idx]  = acc[m][n][j];
            }
        }
    }
}

// ---------------- h += t_emb[t_idx[b]] ----------------
__global__ void bias_kernel(float* __restrict__ h, const float* __restrict__ t_emb,
                            const int* __restrict__ t_idx) {
    int r = blockIdx.x;
    int b = r >> 8;
    const float* e = t_emb + (size_t)t_idx[b] * Hdim;
    float* hr = h + (size_t)r * Hdim;
    for (int i = threadIdx.x; i < Hdim; i += 256) hr[i] += e[i];
}

// ---------------- rmsnorm -> bf16 ----------------
__global__ void rmsnorm_kernel(const float* __restrict__ x, const float* __restrict__ w,
                               unsigned short* __restrict__ y) {
    int r = blockIdx.x, tid = threadIdx.x;
    const float* xr = x + (size_t)r * Hdim;
    float v0 = xr[tid], v1 = xr[tid + 256], v2 = xr[tid + 512];
    __shared__ float red[256];
    red[tid] = v0 * v0 + v1 * v1 + v2 * v2;
    __syncthreads();
    for (int off = 128; off; off >>= 1) {
        if (tid < off) red[tid] += red[tid + off];
        __syncthreads();
    }
    float rms = sqrtf(red[0] / (float)Hdim);
    float s = 1.0f / (rms + 1e-6f);
    unsigned short* yr = y + (size_t)r * Hdim;
    yr[tid]       = f2b(v0 * s * w[tid]);
    yr[tid + 256] = f2b(v1 * s * w[tid + 256]);
    yr[tid + 512] = f2b(v2 * s * w[tid + 512]);
}

// ---------------- silu(u), silu(v), rope(q), rope(k) in place ----------------
__global__ void act_kernel(float* __restrict__ uvqk, const float* __restrict__ pe) {
    int r = blockIdx.x;
    int tid = threadIdx.x;
    size_t base = (size_t)r * UVW;
    float4* p4 = (float4*)(uvqk + base);
#pragma unroll
    for (int i = 0; i < 3; ++i) {
        float4 xv = p4[tid + 256 * i];
        xv.x = xv.x / (1.0f + expf(-xv.x));
        xv.y = xv.y / (1.0f + expf(-xv.y));
        xv.z = xv.z / (1.0f + expf(-xv.z));
        xv.w = xv.w / (1.0f + expf(-xv.w));
        p4[tid + 256 * i] = xv;
    }
    int l = r & 255;
    const float* p = pe + l * 128;
    if (tid < 128) {
        int qb = (tid < 64) ? 3072 : 3200;
        int d  = tid & 63;
        float x1 = uvqk[base + qb + d];
        float x2 = uvqk[base + qb + 64 + d];
        float sn = p[d];
        float cs = p[64 + d];
        uvqk[base + qb + d]      = x1 * cs - x2 * sn;
        uvqk[base + qb + 64 + d] = x2 * cs + x1 * sn;
    }
}

// ---------------- scores + softmax -> bf16 ----------------
__global__ void attn_kernel(const float* __restrict__ uvqk, unsigned short* __restrict__ attn) {
    int bi = blockIdx.x;
    int b = bi >> 8, i = bi & 255;
    int tid = threadIdx.x;
    __shared__ float qs[128];
    __shared__ float red[256];
    if (tid < 128) qs[tid] = uvqk[(size_t)(b * Ltok + i) * UVW + 3072 + tid];
    __syncthreads();
    const float* kr = uvqk + (size_t)(b * Ltok + tid) * UVW + 3200;
    float s = 0.f;
#pragma unroll
    for (int d = 0; d < 128; d += 4) {
        float4 kv = *(const float4*)&kr[d];
        float4 qv = *(const float4*)&qs[d];
        s += qv.x * kv.x + qv.y * kv.y + qv.z * kv.z + qv.w * kv.w;
    }
    s *= 0.08838834764831845f;
    red[tid] = s;
    __syncthreads();
    for (int off = 128; off; off >>= 1) {
        if (tid < off) red[tid] = fmaxf(red[tid], red[tid + off]);
        __syncthreads();
    }
    float mx = red[0];
    __syncthreads();
    float e = expf(s - mx);
    red[tid] = e;
    __syncthreads();
    for (int off = 128; off; off >>= 1) {
        if (tid < off) red[tid] += red[tid + off];
        __syncthreads();
    }
    attn[(size_t)bi * 256 + tid] = f2b(e / red[0]);
}

// ---------------- o_bf16 = f2b(o * silu_u) ----------------
__global__ void umul_kernel(const float* __restrict__ o, const float* __restrict__ uvqk,
                            unsigned short* __restrict__ ob) {
    int r = blockIdx.x, tid = threadIdx.x;          // block 384
    float4 ov = ((const float4*)(o + (size_t)r * Edim))[tid];
    float4 uv = ((const float4*)(uvqk + (size_t)r * UVW))[tid];
    ushort4 wv;
    wv.x = f2b(ov.x * uv.x);
    wv.y = f2b(ov.y * uv.y);
    wv.z = f2b(ov.z * uv.z);
    wv.w = f2b(ov.w * uv.w);
    ((ushort4*)(ob + (size_t)r * Edim))[tid] = wv;
}

// ---------------- unpatchify ----------------
__global__ void unpatch_kernel(const float* __restrict__ y, float* __restrict__ out) {
    int bc = blockIdx.x;
    int iy = bc & 127;
    int t  = bc >> 7;
    int c  = t % 3;
    int b  = t / 3;
    int ix = threadIdx.x;
    int gy = iy >> 3, py = iy & 7, gx = ix >> 3, px = ix & 7;
    out[((size_t)(b * 3 + c) * IMG + iy) * IMG + ix] =
        y[(size_t)(b * Ltok + gy * 16 + gx) * PDim + (py * 8 + px) * 3 + c];
}

extern "C" void kernel_launch(void* const* d_in, const int* in_sizes, int n_in,
                              void* d_out, int out_size, void* d_ws, size_t ws_size,
                              hipStream_t stream) {
    const float* x        = (const float*)d_in[0];
    const int*   t_idx    = (const int*)  d_in[1];
    const float* patch_W  = (const float*)d_in[2];
    const float* t_emb    = (const float*)d_in[3];
    const float* Wuv      = (const float*)d_in[4];
    const float* Wout     = (const float*)d_in[5];
    const float* gnorm    = (const float*)d_in[6];
    const float* fnorm    = (const float*)d_in[7];
    const float* unpatchW = (const float*)d_in[8];
    float* out = (float*)d_out;

    // ---- workspace layout ----
    char* wsb = (char*)d_ws;
    size_t off = 0;
    auto alloc = [&](size_t bytes) { char* p = wsb + off; off += (bytes + 255) & ~(size_t)255; return p; };
    float* pe      = (float*)alloc(256 * 128 * 4);
    float* h       = (float*)alloc((size_t)Mrows * Hdim * 4);
    float* uvqk    = (float*)alloc((size_t)Mrows * UVW * 4);
    float* o_f32   = (float*)alloc((size_t)Mrows * Edim * 4);     // reused for final y
    unsigned short* xp     = (unsigned short*)alloc((size_t)Mrows * PDim * 2);
    unsigned short* xn     = (unsigned short*)alloc((size_t)Mrows * Hdim * 2);
    unsigned short* vT     = (unsigned short*)alloc((size_t)Bsz * Edim * Ltok * 2);
    unsigned short* attn   = (unsigned short*)alloc((size_t)Bsz * Ltok * Ltok * 2);
    unsigned short* o_bf   = (unsigned short*)alloc((size_t)Mrows * Edim * 2);
    unsigned short* WuvT   = (unsigned short*)alloc((size_t)UVW * Hdim * 2);
    unsigned short* WoutT  = (unsigned short*)alloc((size_t)Hdim * Edim * 2);
    unsigned short* patchWT   = (unsigned short*)alloc((size_t)Hdim * PDim * 2);
    unsigned short* unpatchWT = (unsigned short*)alloc((size_t)PDim * Hdim * 2);
    if (off > ws_size) return;   // distinct failure signature (out stays 0)

    pe_kernel<<<256, 128, 0, stream>>>(pe);
    patchify_kernel<<<Bsz * 3 * IMG, IMG, 0, stream>>>(x, xp);

    // patch_W [192][768] -> patchWT [768][192]
    trans_kernel<<<dim3(Hdim / 32, PDim / 32, 1), dim3(32, 8), 0, stream>>>(
        patch_W, Hdim, 0, patchWT, PDim, 0);
    gemm_bf16<0><<<dim3(Hdim / 128, Mrows / 128, 1), 256, 0, stream>>>(
        xp, PDim, 0, patchWT, PDim, 0, h, Hdim, 0, PDim, Hdim);
    bias_kernel<<<Mrows, 256, 0, stream>>>(h, t_emb, t_idx);
    // unpatch_W [768][192] -> unpatchWT [192][768]
    trans_kernel<<<dim3(PDim / 32, Hdim / 32, 1), dim3(32, 8), 0, stream>>>(
        unpatchW, PDim, 0, unpatchWT, Hdim, 0);

    for (int l = 0; l < NLAY; ++l) {
        // Wuv_l [768][3328] -> WuvT [3328][768]
        trans_kernel<<<dim3(UVW / 32, Hdim / 32, 1), dim3(32, 8), 0, stream>>>(
            Wuv + (size_t)l * Hdim * UVW, UVW, 0, WuvT, Hdim, 0);
        rmsnorm_kernel<<<Mrows, 256, 0, stream>>>(h, gnorm + (size_t)l * Hdim, xn);
        gemm_bf16<0><<<dim3(UVW / 128, Mrows / 128, 1), 256, 0, stream>>>(
            xn, Hdim, 0, WuvT, Hdim, 0, uvqk, UVW, 0, Hdim, UVW);
        act_kernel<<<Mrows, 256, 0, stream>>>(uvqk, pe);
        attn_kernel<<<Bsz * Ltok, 256, 0, stream>>>(uvqk, attn);
        // v (fp32, rows m, ld UVW) -> vT bf16 [e][m] per batch
        trans_kernel<<<dim3(Edim / 32, Ltok / 32, Bsz), dim3(32, 8), 0, stream>>>(
            uvqk + Edim, UVW, (long long)Ltok * UVW, vT, Ltok, (long long)Edim * Ltok);
        gemm_bf16<0><<<dim3(Edim / 128, Ltok / 128, Bsz), 256, 0, stream>>>(
            attn, Ltok, (long long)Ltok * Ltok,
            vT, Ltok, (long long)Edim * Ltok,
            o_f32, Edim, (long long)Ltok * Edim, Ltok, Edim);
        umul_kernel<<<Mrows, 384, 0, stream>>>(o_f32, uvqk, o_bf);
        // Wout_l [1536][768] -> WoutT [768][1536]
        trans_kernel<<<dim3(Hdim / 32, Edim / 32, 1), dim3(32, 8), 0, stream>>>(
            Wout + (size_t)l * Edim * Hdim, Hdim, 0, WoutT, Edim, 0);
        gemm_bf16<1><<<dim3(Hdim / 128, Mrows / 128, 1), 256, 0, stream>>>(
            o_bf, Edim, 0, WoutT, Edim, 0, h, Hdim, 0, Edim, Hdim);
    }

    rmsnorm_kernel<<<Mrows, 256, 0, stream>>>(h, fnorm, xn);
    gemm_bf16<0><<<dim3(2, Mrows / 128, 1), 256, 0, stream>>>(
        xn, Hdim, 0, unpatchWT, Hdim, 0, o_f32, PDim, 0, Hdim, PDim);
    unpatch_kernel<<<Bsz * 3 * IMG, IMG, 0, stream>>>(o_f32, out);
}

// Round 3
// 4725.780 us; speedup vs baseline: 2.9612x; 1.1834x over previous
//
#include <hip/hip_runtime.h>
#include <math.h>

#define IMG   128
#define Hdim  768
#define Edim  1536
#define Kdim  128
#define Ltok  256
#define PDim  192
#define NLAY  24
#define Bsz   16
#define Mrows 4096          // B * L
#define UVW   3328          // 2E + 2K

typedef __bf16 bf16x8 __attribute__((ext_vector_type(8)));
typedef float  f32x4  __attribute__((ext_vector_type(4)));

__device__ __forceinline__ unsigned short f2b(float f) {
    unsigned int u = __float_as_uint(f);
    unsigned int r = (u + 0x7FFF + ((u >> 16) & 1)) >> 16;
    return (unsigned short)r;
}
__device__ __forceinline__ float b2f(unsigned short s) {
    return __uint_as_float((unsigned int)s << 16);
}
__device__ __forceinline__ float silu(float x) {
    return x / (1.0f + expf(-x));
}
__device__ __forceinline__ void gload16(const void* g, void* l) {
    __builtin_amdgcn_global_load_lds(
        (const __attribute__((address_space(1))) void*)g,
        (__attribute__((address_space(3))) void*)l, 16, 0, 0);
}

// ---------------- RoPE table ----------------
__global__ void pe_kernel(float* __restrict__ pe) {
    int l = blockIdx.x;
    int j = threadIdx.x;
    const float c = -logf(1000.0f) / 31.0f;
    int   sub = j & 31;
    float f   = expf(c * (float)sub);
    float pos = (j < 64) ? (float)(l >> 4) : (float)(l & 15);
    float ang = pos * f;
    pe[l * 128 + j] = ((j & 32) == 0) ? sinf(ang) : cosf(ang);
}

// ---------------- patchify -> bf16 ----------------
__global__ void patchify_kernel(const float* __restrict__ x, unsigned short* __restrict__ xp) {
    int bc = blockIdx.x;
    int iy = bc & 127;
    int t  = bc >> 7;
    int c  = t % 3;
    int b  = t / 3;
    int ix = threadIdx.x;
    float v = x[((size_t)(b * 3 + c) * IMG + iy) * IMG + ix];
    int gy = iy >> 3, py = iy & 7, gx = ix >> 3, px = ix & 7;
    xp[(size_t)(b * Ltok + gy * 16 + gx) * PDim + (py * 8 + px) * 3 + c] = f2b(v);
}

// ---------------- fp32 [R][C] (ldS) -> bf16 transposed [C][R] (ldD) ----------------
__global__ void trans_kernel(const float* __restrict__ src, int ldS, long long sS,
                             unsigned short* __restrict__ dst, int ldD, long long sD) {
    src += (long long)blockIdx.z * sS;
    dst += (long long)blockIdx.z * sD;
    __shared__ float t[32][33];
    int c0 = blockIdx.x * 32, r0 = blockIdx.y * 32;
    int tx = threadIdx.x, ty = threadIdx.y;   // (32,8)
#pragma unroll
    for (int i = 0; i < 4; ++i)
        t[ty + 8 * i][tx] = src[(size_t)(r0 + ty + 8 * i) * ldS + c0 + tx];
    __syncthreads();
#pragma unroll
    for (int i = 0; i < 4; ++i)
        dst[(size_t)(c0 + ty + 8 * i) * ldD + r0 + tx] = f2b(t[tx][ty + 8 * i]);
}

// ================= generic bf16 MFMA GEMM (m97 structure) =================
// C[M,N] (+)= A[M,K] @ Bt[N,K]^T ; 128x128 tile, BK=32, 4 waves of 64x64.
template <int ACC>
__launch_bounds__(256)
__global__ void gemm_bf16(const unsigned short* __restrict__ A, int lda, long long sA,
                          const unsigned short* __restrict__ Bt, int ldb, long long sB,
                          float* __restrict__ C, int ldc, long long sC,
                          int Kt, int Nt) {
    A  += (long long)blockIdx.z * sA;
    Bt += (long long)blockIdx.z * sB;
    C  += (long long)blockIdx.z * sC;
    __shared__ unsigned short lsA[128 * 32];
    __shared__ unsigned short lsB[128 * 32];
    int tid  = threadIdx.x;
    int lane = tid & 63, w = tid >> 6, wr = w >> 1, wc = w & 1;
    int row0 = blockIdx.y * 128, col0 = blockIdx.x * 128;
    int fr = lane & 15, fk = (lane >> 4) * 8;
    f32x4 acc[4][4] = {};

    for (int k0 = 0; k0 < Kt; k0 += 32) {
#pragma unroll
        for (int i = 0; i < 2; ++i) {
            int c  = tid + 256 * i;
            int ar = row0 + (c >> 2);
            gload16(A + (size_t)ar * lda + k0 + (c & 3) * 8, lsA + (size_t)c * 8);
            int bn = col0 + (c >> 2);
            if (bn > Nt - 1) bn = Nt - 1;
            gload16(Bt + (size_t)bn * ldb + k0 + (c & 3) * 8, lsB + (size_t)c * 8);
        }
        __syncthreads();
        bf16x8 af[4], bfr[4];
#pragma unroll
        for (int m = 0; m < 4; ++m)
            af[m] = *(const bf16x8*)(lsA + (wr * 64 + m * 16 + fr) * 32 + fk);
#pragma unroll
        for (int n = 0; n < 4; ++n)
            bfr[n] = *(const bf16x8*)(lsB + (wc * 64 + n * 16 + fr) * 32 + fk);
#pragma unroll
        for (int m = 0; m < 4; ++m)
#pragma unroll
            for (int n = 0; n < 4; ++n)
                acc[m][n] = __builtin_amdgcn_mfma_f32_16x16x32_bf16(af[m], bfr[n], acc[m][n], 0, 0, 0);
        __syncthreads();
    }

    int crow = (lane >> 4) * 4;
#pragma unroll
    for (int m = 0; m < 4; ++m) {
#pragma unroll
        for (int n = 0; n < 4; ++n) {
            int gc = col0 + wc * 64 + n * 16 + fr;
            if (gc >= Nt) continue;
#pragma unroll
            for (int j = 0; j < 4; ++j) {
                size_t idx = (size_t)(row0 + wr * 64 + m * 16 + crow + j) * ldc + gc;
                if (ACC) C[idx] += acc[m][n][j];
                else     C[idx]  = acc[m][n][j];
            }
        }
    }
}

// ================= uvqk GEMM, fused epilogue =================
// A = xn [4096][768] bf16, Bt = WuvT_l [3328][768] bf16.
// tiles 0-11: silu -> uT [1536][4096] bf16 (transposed)
// tiles 12-23: silu -> vT [16][1536][256] bf16
// tiles 24/25: raw fp32 -> qk [4096][256]
__launch_bounds__(256)
__global__ void gemm_uvqk(const unsigned short* __restrict__ A,
                          const unsigned short* __restrict__ Bt,
                          unsigned short* __restrict__ uT,
                          unsigned short* __restrict__ vT,
                          float* __restrict__ qk) {
    __shared__ unsigned short lsA[128 * 32];
    __shared__ unsigned short lsB[128 * 32];
    int tid  = threadIdx.x;
    int lane = tid & 63, w = tid >> 6, wr = w >> 1, wc = w & 1;
    int row0 = blockIdx.y * 128, col0 = blockIdx.x * 128;
    int fr = lane & 15, fk = (lane >> 4) * 8;
    f32x4 acc[4][4] = {};

    for (int k0 = 0; k0 < Hdim; k0 += 32) {
#pragma unroll
        for (int i = 0; i < 2; ++i) {
            int c  = tid + 256 * i;
            gload16(A  + (size_t)(row0 + (c >> 2)) * Hdim + k0 + (c & 3) * 8, lsA + (size_t)c * 8);
            gload16(Bt + (size_t)(col0 + (c >> 2)) * Hdim + k0 + (c & 3) * 8, lsB + (size_t)c * 8);
        }
        __syncthreads();
        bf16x8 af[4], bfr[4];
#pragma unroll
        for (int m = 0; m < 4; ++m)
            af[m] = *(const bf16x8*)(lsA + (wr * 64 + m * 16 + fr) * 32 + fk);
#pragma unroll
        for (int n = 0; n < 4; ++n)
            bfr[n] = *(const bf16x8*)(lsB + (wc * 64 + n * 16 + fr) * 32 + fk);
#pragma unroll
        for (int m = 0; m < 4; ++m)
#pragma unroll
            for (int n = 0; n < 4; ++n)
                acc[m][n] = __builtin_amdgcn_mfma_f32_16x16x32_bf16(af[m], bfr[n], acc[m][n], 0, 0, 0);
        __syncthreads();
    }

    int crow = (lane >> 4) * 4;
    int bx = blockIdx.x;
#pragma unroll
    for (int m = 0; m < 4; ++m) {
        int row = row0 + wr * 64 + m * 16 + crow;       // multiple of 4
#pragma unroll
        for (int n = 0; n < 4; ++n) {
            int gc = col0 + wc * 64 + n * 16 + fr;
            if (bx < 12) {
                // u: silu -> uT[gc][row..row+3]
                ushort4 pk;
                pk.x = f2b(silu(acc[m][n][0]));
                pk.y = f2b(silu(acc[m][n][1]));
                pk.z = f2b(silu(acc[m][n][2]));
                pk.w = f2b(silu(acc[m][n][3]));
                *(ushort4*)(uT + (size_t)gc * Mrows + row) = pk;
            } else if (bx < 24) {
                // v: silu -> vT[b][e][l..l+3]
                int e = gc - Edim;
                int b = row >> 8, l = row & 255;
                ushort4 pk;
                pk.x = f2b(silu(acc[m][n][0]));
                pk.y = f2b(silu(acc[m][n][1]));
                pk.z = f2b(silu(acc[m][n][2]));
                pk.w = f2b(silu(acc[m][n][3]));
                *(ushort4*)(vT + ((size_t)b * Edim + e) * Ltok + l) = pk;
            } else {
                int col = gc - 2 * Edim;   // 0..255 (q:0-127, k:128-255)
#pragma unroll
                for (int j = 0; j < 4; ++j)
                    qk[(size_t)(row + j) * 256 + col] = acc[m][n][j];
            }
        }
    }
}

// ================= PV GEMM, fused u-multiply =================
// per batch z: C[l][e] = attn[l][:] @ vT[z][e][:]; out o_bf = f2b(C * uT)
__launch_bounds__(256)
__global__ void gemm_pv(const unsigned short* __restrict__ attn,
                        const unsigned short* __restrict__ vT,
                        const unsigned short* __restrict__ uT,
                        unsigned short* __restrict__ ob) {
    const unsigned short* A  = attn + (size_t)blockIdx.z * Ltok * Ltok;
    const unsigned short* Bt = vT   + (size_t)blockIdx.z * Edim * Ltok;
    __shared__ unsigned short lsA[128 * 32];
    __shared__ unsigned short lsB[128 * 32];
    int tid  = threadIdx.x;
    int lane = tid & 63, w = tid >> 6, wr = w >> 1, wc = w & 1;
    int row0 = blockIdx.y * 128, col0 = blockIdx.x * 128;
    int fr = lane & 15, fk = (lane >> 4) * 8;
    f32x4 acc[4][4] = {};

    for (int k0 = 0; k0 < Ltok; k0 += 32) {
#pragma unroll
        for (int i = 0; i < 2; ++i) {
            int c  = tid + 256 * i;
            gload16(A  + (size_t)(row0 + (c >> 2)) * Ltok + k0 + (c & 3) * 8, lsA + (size_t)c * 8);
            gload16(Bt + (size_t)(col0 + (c >> 2)) * Ltok + k0 + (c & 3) * 8, lsB + (size_t)c * 8);
        }
        __syncthreads();
        bf16x8 af[4], bfr[4];
#pragma unroll
        for (int m = 0; m < 4; ++m)
            af[m] = *(const bf16x8*)(lsA + (wr * 64 + m * 16 + fr) * 32 + fk);
#pragma unroll
        for (int n = 0; n < 4; ++n)
            bfr[n] = *(const bf16x8*)(lsB + (wc * 64 + n * 16 + fr) * 32 + fk);
#pragma unroll
        for (int m = 0; m < 4; ++m)
#pragma unroll
            for (int n = 0; n < 4; ++n)
                acc[m][n] = __builtin_amdgcn_mfma_f32_16x16x32_bf16(af[m], bfr[n], acc[m][n], 0, 0, 0);
        __syncthreads();
    }

    int crow = (lane >> 4) * 4;
#pragma unroll
    for (int m = 0; m < 4; ++m) {
        int grow = (int)blockIdx.z * Ltok + row0 + wr * 64 + m * 16 + crow;  // mult of 4
#pragma unroll
        for (int n = 0; n < 4; ++n) {
            int gc = col0 + wc * 64 + n * 16 + fr;
            ushort4 uv = *(const ushort4*)(uT + (size_t)gc * Mrows + grow);
            ob[(size_t)(grow + 0) * Edim + gc] = f2b(acc[m][n][0] * b2f(uv.x));
            ob[(size_t)(grow + 1) * Edim + gc] = f2b(acc[m][n][1] * b2f(uv.y));
            ob[(size_t)(grow + 2) * Edim + gc] = f2b(acc[m][n][2] * b2f(uv.z));
            ob[(size_t)(grow + 3) * Edim + gc] = f2b(acc[m][n][3] * b2f(uv.w));
        }
    }
}

// ---------------- h += t_emb[t_idx[b]] ----------------
__global__ void bias_kernel(float* __restrict__ h, const float* __restrict__ t_emb,
                            const int* __restrict__ t_idx) {
    int r = blockIdx.x;
    int b = r >> 8;
    const float* e = t_emb + (size_t)t_idx[b] * Hdim;
    float* hr = h + (size_t)r * Hdim;
    for (int i = threadIdx.x; i < Hdim; i += 256) hr[i] += e[i];
}

// ---------------- rmsnorm -> bf16 ----------------
__global__ void rmsnorm_kernel(const float* __restrict__ x, const float* __restrict__ w,
                               unsigned short* __restrict__ y) {
    int r = blockIdx.x, tid = threadIdx.x;
    const float* xr = x + (size_t)r * Hdim;
    float v0 = xr[tid], v1 = xr[tid + 256], v2 = xr[tid + 512];
    __shared__ float red[256];
    red[tid] = v0 * v0 + v1 * v1 + v2 * v2;
    __syncthreads();
    for (int off = 128; off; off >>= 1) {
        if (tid < off) red[tid] += red[tid + off];
        __syncthreads();
    }
    float rms = sqrtf(red[0] / (float)Hdim);
    float s = 1.0f / (rms + 1e-6f);
    unsigned short* yr = y + (size_t)r * Hdim;
    yr[tid]       = f2b(v0 * s * w[tid]);
    yr[tid + 256] = f2b(v1 * s * w[tid + 256]);
    yr[tid + 512] = f2b(v2 * s * w[tid + 512]);
}

// ---------------- rope on compact qk [4096][256], in place ----------------
__global__ void rope_kernel(float* __restrict__ qk, const float* __restrict__ pe) {
    int r = blockIdx.x;
    int d = threadIdx.x;      // 64
    int l = r & 255;
    float sn = pe[l * 128 + d];
    float cs = pe[l * 128 + 64 + d];
    float* row = qk + (size_t)r * 256;
    float q1 = row[d], q2 = row[d + 64];
    row[d]       = q1 * cs - q2 * sn;
    row[d + 64]  = q2 * cs + q1 * sn;
    float k1 = row[128 + d], k2 = row[192 + d];
    row[128 + d] = k1 * cs - k2 * sn;
    row[192 + d] = k2 * cs + k1 * sn;
}

// ---------------- scores + softmax -> bf16 ----------------
__global__ void attn_kernel(const float* __restrict__ qk, unsigned short* __restrict__ attn) {
    int bi = blockIdx.x;
    int b = bi >> 8;
    int tid = threadIdx.x;
    __shared__ float qs[128];
    __shared__ float red[256];
    if (tid < 128) qs[tid] = qk[(size_t)bi * 256 + tid];
    __syncthreads();
    const float* kr = qk + (size_t)(b * Ltok + tid) * 256 + 128;
    float s = 0.f;
#pragma unroll
    for (int d = 0; d < 128; d += 4) {
        float4 kv = *(const float4*)&kr[d];
        float4 qv = *(const float4*)&qs[d];
        s += qv.x * kv.x + qv.y * kv.y + qv.z * kv.z + qv.w * kv.w;
    }
    s *= 0.08838834764831845f;
    red[tid] = s;
    __syncthreads();
    for (int off = 128; off; off >>= 1) {
        if (tid < off) red[tid] = fmaxf(red[tid], red[tid + off]);
        __syncthreads();
    }
    float mx = red[0];
    __syncthreads();
    float e = expf(s - mx);
    red[tid] = e;
    __syncthreads();
    for (int off = 128; off; off >>= 1) {
        if (tid < off) red[tid] += red[tid + off];
        __syncthreads();
    }
    attn[(size_t)bi * 256 + tid] = f2b(e / red[0]);
}

// ---------------- unpatchify ----------------
__global__ void unpatch_kernel(const float* __restrict__ y, float* __restrict__ out) {
    int bc = blockIdx.x;
    int iy = bc & 127;
    int t  = bc >> 7;
    int c  = t % 3;
    int b  = t / 3;
    int ix = threadIdx.x;
    int gy = iy >> 3, py = iy & 7, gx = ix >> 3, px = ix & 7;
    out[((size_t)(b * 3 + c) * IMG + iy) * IMG + ix] =
        y[(size_t)(b * Ltok + gy * 16 + gx) * PDim + (py * 8 + px) * 3 + c];
}

extern "C" void kernel_launch(void* const* d_in, const int* in_sizes, int n_in,
                              void* d_out, int out_size, void* d_ws, size_t ws_size,
                              hipStream_t stream) {
    const float* x        = (const float*)d_in[0];
    const int*   t_idx    = (const int*)  d_in[1];
    const float* patch_W  = (const float*)d_in[2];
    const float* t_emb    = (const float*)d_in[3];
    const float* Wuv      = (const float*)d_in[4];
    const float* Wout     = (const float*)d_in[5];
    const float* gnorm    = (const float*)d_in[6];
    const float* fnorm    = (const float*)d_in[7];
    const float* unpatchW = (const float*)d_in[8];
    float* out = (float*)d_out;

    // ---- workspace layout ----
    char* wsb = (char*)d_ws;
    size_t off = 0;
    auto alloc = [&](size_t bytes) { char* p = wsb + off; off += (bytes + 255) & ~(size_t)255; return p; };
    float* pe   = (float*)alloc(256 * 128 * 4);
    float* h    = (float*)alloc((size_t)Mrows * Hdim * 4);
    float* qk   = (float*)alloc((size_t)Mrows * 256 * 4);
    float* y    = (float*)alloc((size_t)Mrows * PDim * 4);
    unsigned short* xp   = (unsigned short*)alloc((size_t)Mrows * PDim * 2);
    unsigned short* xn   = (unsigned short*)alloc((size_t)Mrows * Hdim * 2);
    unsigned short* uT   = (unsigned short*)alloc((size_t)Edim * Mrows * 2);
    unsigned short* vT   = (unsigned short*)alloc((size_t)Bsz * Edim * Ltok * 2);
    unsigned short* attn = (unsigned short*)alloc((size_t)Bsz * Ltok * Ltok * 2);
    unsigned short* o_bf = (unsigned short*)alloc((size_t)Mrows * Edim * 2);
    unsigned short* WuvT  = (unsigned short*)alloc((size_t)NLAY * UVW * Hdim * 2);
    unsigned short* WoutT = (unsigned short*)alloc((size_t)NLAY * Hdim * Edim * 2);
    unsigned short* patchWT   = (unsigned short*)alloc((size_t)Hdim * PDim * 2);
    unsigned short* unpatchWT = (unsigned short*)alloc((size_t)PDim * Hdim * 2);
    if (off > ws_size) return;   // distinct failure signature (out stays 0)

    pe_kernel<<<256, 128, 0, stream>>>(pe);
    patchify_kernel<<<Bsz * 3 * IMG, IMG, 0, stream>>>(x, xp);

    // all weight transposes upfront (batched over layers)
    trans_kernel<<<dim3(Hdim / 32, PDim / 32, 1), dim3(32, 8), 0, stream>>>(
        patch_W, Hdim, 0, patchWT, PDim, 0);
    trans_kernel<<<dim3(PDim / 32, Hdim / 32, 1), dim3(32, 8), 0, stream>>>(
        unpatchW, PDim, 0, unpatchWT, Hdim, 0);
    trans_kernel<<<dim3(UVW / 32, Hdim / 32, NLAY), dim3(32, 8), 0, stream>>>(
        Wuv, UVW, (long long)Hdim * UVW, WuvT, Hdim, (long long)UVW * Hdim);
    trans_kernel<<<dim3(Hdim / 32, Edim / 32, NLAY), dim3(32, 8), 0, stream>>>(
        Wout, Hdim, (long long)Edim * Hdim, WoutT, Edim, (long long)Hdim * Edim);

    gemm_bf16<0><<<dim3(Hdim / 128, Mrows / 128, 1), 256, 0, stream>>>(
        xp, PDim, 0, patchWT, PDim, 0, h, Hdim, 0, PDim, Hdim);
    bias_kernel<<<Mrows, 256, 0, stream>>>(h, t_emb, t_idx);

    for (int l = 0; l < NLAY; ++l) {
        rmsnorm_kernel<<<Mrows, 256, 0, stream>>>(h, gnorm + (size_t)l * Hdim, xn);
        gemm_uvqk<<<dim3(UVW / 128, Mrows / 128, 1), 256, 0, stream>>>(
            xn, WuvT + (size_t)l * UVW * Hdim, uT, vT, qk);
        rope_kernel<<<Mrows, 64, 0, stream>>>(qk, pe);
        attn_kernel<<<Bsz * Ltok, 256, 0, stream>>>(qk, attn);
        gemm_pv<<<dim3(Edim / 128, Ltok / 128, Bsz), 256, 0, stream>>>(
            attn, vT, uT, o_bf);
        gemm_bf16<1><<<dim3(Hdim / 128, Mrows / 128, 1), 256, 0, stream>>>(
            o_bf, Edim, 0, WoutT + (size_t)l * Hdim * Edim, Edim, 0, h, Hdim, 0, Edim, Hdim);
    }

    rmsnorm_kernel<<<Mrows, 256, 0, stream>>>(h, fnorm, xn);
    gemm_bf16<0><<<dim3(2, Mrows / 128, 1), 256, 0, stream>>>(
        xn, Hdim, 0, unpatchWT, Hdim, 0, y, PDim, 0, Hdim, PDim);
    unpatch_kernel<<<Bsz * 3 * IMG, IMG, 0, stream>>>(y, out);
}

// Round 4
// 3701.104 us; speedup vs baseline: 3.7810x; 1.2769x over previous
//
#include <hip/hip_runtime.h>
#include <math.h>

#define IMG   128
#define Hdim  768
#define Edim  1536
#define Ltok  256
#define PDim  192
#define NLAY  24
#define Bsz   16
#define Mrows 4096          // B * L
#define UVW   3328          // 2E + 2K

typedef __bf16 bf16x8 __attribute__((ext_vector_type(8)));
typedef float  f32x4  __attribute__((ext_vector_type(4)));

__device__ __forceinline__ unsigned short f2b(float f) {
    unsigned int u = __float_as_uint(f);
    unsigned int r = (u + 0x7FFF + ((u >> 16) & 1)) >> 16;
    return (unsigned short)r;
}
__device__ __forceinline__ float b2f(unsigned short s) {
    return __uint_as_float((unsigned int)s << 16);
}
__device__ __forceinline__ unsigned int pk2(float lo, float hi) {
    return (unsigned int)f2b(lo) | ((unsigned int)f2b(hi) << 16);
}
__device__ __forceinline__ float silu(float x) {
    return x / (1.0f + expf(-x));
}
__device__ __forceinline__ void gload16(const void* g, void* l) {
    __builtin_amdgcn_global_load_lds(
        (const __attribute__((address_space(1))) void*)g,
        (__attribute__((address_space(3))) void*)l, 16, 0, 0);
}

// ---------------- RoPE table ----------------
__global__ void pe_kernel(float* __restrict__ pe) {
    int l = blockIdx.x;
    int j = threadIdx.x;
    const float c = -logf(1000.0f) / 31.0f;
    int   sub = j & 31;
    float f   = expf(c * (float)sub);
    float pos = (j < 64) ? (float)(l >> 4) : (float)(l & 15);
    float ang = pos * f;
    pe[l * 128 + j] = ((j & 32) == 0) ? sinf(ang) : cosf(ang);
}

// ---------------- patchify -> bf16 ----------------
__global__ void patchify_kernel(const float* __restrict__ x, unsigned short* __restrict__ xp) {
    int bc = blockIdx.x;
    int iy = bc & 127;
    int t  = bc >> 7;
    int c  = t % 3;
    int b  = t / 3;
    int ix = threadIdx.x;
    float v = x[((size_t)(b * 3 + c) * IMG + iy) * IMG + ix];
    int gy = iy >> 3, py = iy & 7, gx = ix >> 3, px = ix & 7;
    xp[(size_t)(b * Ltok + gy * 16 + gx) * PDim + (py * 8 + px) * 3 + c] = f2b(v);
}

// ---------------- fp32 [R][C] -> bf16 transposed [C][R] ----------------
__global__ void trans_kernel(const float* __restrict__ src, int ldS, long long sS,
                             unsigned short* __restrict__ dst, int ldD, long long sD) {
    src += (long long)blockIdx.z * sS;
    dst += (long long)blockIdx.z * sD;
    __shared__ float t[32][33];
    int c0 = blockIdx.x * 32, r0 = blockIdx.y * 32;
    int tx = threadIdx.x, ty = threadIdx.y;   // (32,8)
#pragma unroll
    for (int i = 0; i < 4; ++i)
        t[ty + 8 * i][tx] = src[(size_t)(r0 + ty + 8 * i) * ldS + c0 + tx];
    __syncthreads();
#pragma unroll
    for (int i = 0; i < 4; ++i)
        dst[(size_t)(c0 + ty + 8 * i) * ldD + r0 + tx] = f2b(t[tx][ty + 8 * i]);
}

// ================= generic bf16 MFMA GEMM, double-buffered =================
// C[M,N] (+)= A[M,K] @ Bt[N,K]^T ; 128x128 tile, BK=32, 4 waves of 64x64.
template <int ACC>
__launch_bounds__(256)
__global__ void gemm_bf16(const unsigned short* __restrict__ A, int lda, long long sA,
                          const unsigned short* __restrict__ Bt, int ldb, long long sB,
                          float* __restrict__ C, int ldc, long long sC,
                          int Kt, int Nt) {
    A  += (long long)blockIdx.z * sA;
    Bt += (long long)blockIdx.z * sB;
    C  += (long long)blockIdx.z * sC;
    __shared__ unsigned short lsA[2][128 * 32];
    __shared__ unsigned short lsB[2][128 * 32];
    int tid  = threadIdx.x;
    int lane = tid & 63, w = tid >> 6, wr = w >> 1, wc = w & 1;
    int row0 = blockIdx.y * 128, col0 = blockIdx.x * 128;
    int fr = lane & 15, fk = (lane >> 4) * 8;
    f32x4 acc[4][4] = {};

    int c0 = tid, c1 = tid + 256;
    int ar0 = row0 + (c0 >> 2), ar1 = row0 + (c1 >> 2);
    int bn0 = col0 + (c0 >> 2), bn1 = col0 + (c1 >> 2);
    if (bn0 > Nt - 1) bn0 = Nt - 1;
    if (bn1 > Nt - 1) bn1 = Nt - 1;
    int ka0 = (c0 & 3) * 8, ka1 = (c1 & 3) * 8;

#define STAGE_G(buf, k0)                                                       \
    gload16(A  + (size_t)ar0 * lda + (k0) + ka0, &lsA[buf][c0 * 8]);           \
    gload16(A  + (size_t)ar1 * lda + (k0) + ka1, &lsA[buf][c1 * 8]);           \
    gload16(Bt + (size_t)bn0 * ldb + (k0) + ka0, &lsB[buf][c0 * 8]);           \
    gload16(Bt + (size_t)bn1 * ldb + (k0) + ka1, &lsB[buf][c1 * 8]);

    STAGE_G(0, 0);
    __syncthreads();
    int nt = Kt >> 5, cur = 0;
    for (int t = 0; t < nt; ++t) {
        if (t + 1 < nt) { STAGE_G(cur ^ 1, (t + 1) * 32); }
        bf16x8 af[4], bfr[4];
#pragma unroll
        for (int m = 0; m < 4; ++m)
            af[m] = *(const bf16x8*)(&lsA[cur][(wr * 64 + m * 16 + fr) * 32 + fk]);
#pragma unroll
        for (int n = 0; n < 4; ++n)
            bfr[n] = *(const bf16x8*)(&lsB[cur][(wc * 64 + n * 16 + fr) * 32 + fk]);
#pragma unroll
        for (int m = 0; m < 4; ++m)
#pragma unroll
            for (int n = 0; n < 4; ++n)
                acc[m][n] = __builtin_amdgcn_mfma_f32_16x16x32_bf16(af[m], bfr[n], acc[m][n], 0, 0, 0);
        __syncthreads();
        cur ^= 1;
    }
#undef STAGE_G

    int crow = (lane >> 4) * 4;
#pragma unroll
    for (int m = 0; m < 4; ++m) {
#pragma unroll
        for (int n = 0; n < 4; ++n) {
            int gc = col0 + wc * 64 + n * 16 + fr;
            if (gc >= Nt) continue;
#pragma unroll
            for (int j = 0; j < 4; ++j) {
                size_t idx = (size_t)(row0 + wr * 64 + m * 16 + crow + j) * ldc + gc;
                if (ACC) C[idx] += acc[m][n][j];
                else     C[idx]  = acc[m][n][j];
            }
        }
    }
}

// ================= uvqk GEMM, double-buffered, fused epilogue =================
__launch_bounds__(256)
__global__ void gemm_uvqk(const unsigned short* __restrict__ A,
                          const unsigned short* __restrict__ Bt,
                          unsigned short* __restrict__ uT,
                          unsigned short* __restrict__ vT,
                          float* __restrict__ qk) {
    __shared__ unsigned short lsA[2][128 * 32];
    __shared__ unsigned short lsB[2][128 * 32];
    int tid  = threadIdx.x;
    int lane = tid & 63, w = tid >> 6, wr = w >> 1, wc = w & 1;
    int row0 = blockIdx.y * 128, col0 = blockIdx.x * 128;
    int fr = lane & 15, fk = (lane >> 4) * 8;
    f32x4 acc[4][4] = {};

    int c0 = tid, c1 = tid + 256;
    int ar0 = row0 + (c0 >> 2), ar1 = row0 + (c1 >> 2);
    int bn0 = col0 + (c0 >> 2), bn1 = col0 + (c1 >> 2);
    int ka0 = (c0 & 3) * 8, ka1 = (c1 & 3) * 8;

#define STAGE_U(buf, k0)                                                        \
    gload16(A  + (size_t)ar0 * Hdim + (k0) + ka0, &lsA[buf][c0 * 8]);           \
    gload16(A  + (size_t)ar1 * Hdim + (k0) + ka1, &lsA[buf][c1 * 8]);           \
    gload16(Bt + (size_t)bn0 * Hdim + (k0) + ka0, &lsB[buf][c0 * 8]);           \
    gload16(Bt + (size_t)bn1 * Hdim + (k0) + ka1, &lsB[buf][c1 * 8]);

    STAGE_U(0, 0);
    __syncthreads();
    int cur = 0;
    for (int t = 0; t < Hdim / 32; ++t) {
        if (t + 1 < Hdim / 32) { STAGE_U(cur ^ 1, (t + 1) * 32); }
        bf16x8 af[4], bfr[4];
#pragma unroll
        for (int m = 0; m < 4; ++m)
            af[m] = *(const bf16x8*)(&lsA[cur][(wr * 64 + m * 16 + fr) * 32 + fk]);
#pragma unroll
        for (int n = 0; n < 4; ++n)
            bfr[n] = *(const bf16x8*)(&lsB[cur][(wc * 64 + n * 16 + fr) * 32 + fk]);
#pragma unroll
        for (int m = 0; m < 4; ++m)
#pragma unroll
            for (int n = 0; n < 4; ++n)
                acc[m][n] = __builtin_amdgcn_mfma_f32_16x16x32_bf16(af[m], bfr[n], acc[m][n], 0, 0, 0);
        __syncthreads();
        cur ^= 1;
    }
#undef STAGE_U

    int crow = (lane >> 4) * 4;
    int bx = blockIdx.x;
#pragma unroll
    for (int m = 0; m < 4; ++m) {
        int row = row0 + wr * 64 + m * 16 + crow;       // multiple of 4
#pragma unroll
        for (int n = 0; n < 4; ++n) {
            int gc = col0 + wc * 64 + n * 16 + fr;
            if (bx < 12) {
                ushort4 pk;
                pk.x = f2b(silu(acc[m][n][0]));
                pk.y = f2b(silu(acc[m][n][1]));
                pk.z = f2b(silu(acc[m][n][2]));
                pk.w = f2b(silu(acc[m][n][3]));
                *(ushort4*)(uT + (size_t)gc * Mrows + row) = pk;
            } else if (bx < 24) {
                int e = gc - Edim;
                int b = row >> 8, l = row & 255;
                ushort4 pk;
                pk.x = f2b(silu(acc[m][n][0]));
                pk.y = f2b(silu(acc[m][n][1]));
                pk.z = f2b(silu(acc[m][n][2]));
                pk.w = f2b(silu(acc[m][n][3]));
                *(ushort4*)(vT + ((size_t)b * Edim + e) * Ltok + l) = pk;
            } else {
                int col = gc - 2 * Edim;   // 0..255 (q:0-127, k:128-255)
#pragma unroll
                for (int j = 0; j < 4; ++j)
                    qk[(size_t)(row + j) * 256 + col] = acc[m][n][j];
            }
        }
    }
}

// ---------------- rope -> bf16 q̂ (pre-scaled), k̂ ----------------
__global__ void rope_kernel(const float* __restrict__ qk, const float* __restrict__ pe,
                            unsigned short* __restrict__ qh, unsigned short* __restrict__ kh) {
    int r = blockIdx.x;
    int d = threadIdx.x;      // 64
    int l = r & 255;
    float sn = pe[l * 128 + d];
    float cs = pe[l * 128 + 64 + d];
    const float* row = qk + (size_t)r * 256;
    const float scale = 0.08838834764831845f;   // 128^-0.5
    float q1 = row[d], q2 = row[d + 64];
    qh[(size_t)r * 128 + d]      = f2b((q1 * cs - q2 * sn) * scale);
    qh[(size_t)r * 128 + 64 + d] = f2b((q2 * cs + q1 * sn) * scale);
    float k1 = row[128 + d], k2 = row[192 + d];
    kh[(size_t)r * 128 + d]      = f2b(k1 * cs - k2 * sn);
    kh[(size_t)r * 128 + 64 + d] = f2b(k2 * cs + k1 * sn);
}

// ================= fused attention: softmax(q̂k̂ᵀ) @ V ⊙ u -> o_bf =================
// grid (ec=4, qt=4, b=16), 256 threads, 4 waves. Wave w: q-rows [qt*64+w*16, +16),
// e-range [ec*384, +384). No LDS, no barriers.
__launch_bounds__(256)
__global__ void fused_attn(const unsigned short* __restrict__ qh,
                           const unsigned short* __restrict__ kh,
                           const unsigned short* __restrict__ vT,
                           const unsigned short* __restrict__ uT,
                           unsigned short* __restrict__ ob) {
    int ec = blockIdx.x, qt = blockIdx.y, b = blockIdx.z;
    int tid  = threadIdx.x;
    int lane = tid & 63, w = tid >> 6;
    int fr = lane & 15, hi = lane >> 4;
    int qbase = b * 256 + qt * 64 + w * 16;

    // ---- S^T = mfma(A=k̂, B=q̂): lane holds q-row fr, kcols {mf*16+hi*4+j} ----
    bf16x8 qf[4];
#pragma unroll
    for (int ks = 0; ks < 4; ++ks)
        qf[ks] = *(const bf16x8*)(qh + (size_t)(qbase + fr) * 128 + ks * 32 + hi * 8);
    f32x4 sacc[16] = {};
#pragma unroll
    for (int mf = 0; mf < 16; ++mf) {
#pragma unroll
        for (int ks = 0; ks < 4; ++ks) {
            bf16x8 kf = *(const bf16x8*)(kh + (size_t)(b * 256 + mf * 16 + fr) * 128 + ks * 32 + hi * 8);
            sacc[mf] = __builtin_amdgcn_mfma_f32_16x16x32_bf16(kf, qf[ks], sacc[mf], 0, 0, 0);
        }
    }

    // ---- softmax over the row (in-lane 64 + xor16 + xor32) ----
    float mx = -3.4e38f;
#pragma unroll
    for (int mf = 0; mf < 16; ++mf)
#pragma unroll
        for (int j = 0; j < 4; ++j)
            mx = fmaxf(mx, sacc[mf][j]);
    mx = fmaxf(mx, __shfl_xor(mx, 16, 64));
    mx = fmaxf(mx, __shfl_xor(mx, 32, 64));
    float sum = 0.f;
#pragma unroll
    for (int mf = 0; mf < 16; ++mf)
#pragma unroll
        for (int j = 0; j < 4; ++j) {
            float e = expf(sacc[mf][j] - mx);
            sacc[mf][j] = e;
            sum += e;
        }
    sum += __shfl_xor(sum, 16, 64);
    sum += __shfl_xor(sum, 32, 64);
    float inv = 1.0f / sum;

    // ---- pack P to bf16 dwords: dw[mf][0]=(j0,j1), dw[mf][1]=(j2,j3) ----
    unsigned int dw[16][2];
#pragma unroll
    for (int mf = 0; mf < 16; ++mf) {
        dw[mf][0] = pk2(sacc[mf][0] * inv, sacc[mf][1] * inv);
        dw[mf][1] = pk2(sacc[mf][2] * inv, sacc[mf][3] * inv);
    }

    // ---- shuffle into PV A-frags: pa[ks] elem e = P[fr][ks*32 + hi*8 + e] ----
    int sA = fr + 32 * (hi & 1);
    int sB = sA + 16;
    bool up = (hi >> 1) != 0;
    unsigned int pa[8][4];
#pragma unroll
    for (int ks = 0; ks < 8; ++ks) {
        unsigned int a00 = __shfl((int)dw[2 * ks][0],     sA, 64);
        unsigned int a01 = __shfl((int)dw[2 * ks + 1][0], sA, 64);
        unsigned int a10 = __shfl((int)dw[2 * ks][1],     sA, 64);
        unsigned int a11 = __shfl((int)dw[2 * ks + 1][1], sA, 64);
        unsigned int b00 = __shfl((int)dw[2 * ks][0],     sB, 64);
        unsigned int b01 = __shfl((int)dw[2 * ks + 1][0], sB, 64);
        unsigned int b10 = __shfl((int)dw[2 * ks][1],     sB, 64);
        unsigned int b11 = __shfl((int)dw[2 * ks + 1][1], sB, 64);
        pa[ks][0] = up ? a01 : a00;
        pa[ks][1] = up ? a11 : a10;
        pa[ks][2] = up ? b01 : b00;
        pa[ks][3] = up ? b11 : b10;
    }

    // ---- PV + u-mul epilogue: O[m=qrow][n=e] ----
    const unsigned short* vb = vT + (size_t)b * Edim * Ltok;
    int e0 = ec * 384;
#pragma unroll 2
    for (int ef = 0; ef < 24; ++ef) {
        int e = e0 + ef * 16 + fr;
        f32x4 oacc = {};
#pragma unroll
        for (int ks = 0; ks < 8; ++ks) {
            bf16x8 vf = *(const bf16x8*)(vb + (size_t)e * Ltok + ks * 32 + hi * 8);
            oacc = __builtin_amdgcn_mfma_f32_16x16x32_bf16(*(const bf16x8*)&pa[ks], vf, oacc, 0, 0, 0);
        }
        ushort4 uv = *(const ushort4*)(uT + (size_t)e * Mrows + qbase + hi * 4);
        ob[(size_t)(qbase + hi * 4 + 0) * Edim + e] = f2b(oacc[0] * b2f(uv.x));
        ob[(size_t)(qbase + hi * 4 + 1) * Edim + e] = f2b(oacc[1] * b2f(uv.y));
        ob[(size_t)(qbase + hi * 4 + 2) * Edim + e] = f2b(oacc[2] * b2f(uv.z));
        ob[(size_t)(qbase + hi * 4 + 3) * Edim + e] = f2b(oacc[3] * b2f(uv.w));
    }
}

// ---------------- h += t_emb[t_idx[b]] ----------------
__global__ void bias_kernel(float* __restrict__ h, const float* __restrict__ t_emb,
                            const int* __restrict__ t_idx) {
    int r = blockIdx.x;
    int b = r >> 8;
    const float* e = t_emb + (size_t)t_idx[b] * Hdim;
    float* hr = h + (size_t)r * Hdim;
    for (int i = threadIdx.x; i < Hdim; i += 256) hr[i] += e[i];
}

// ---------------- rmsnorm -> bf16 ----------------
__global__ void rmsnorm_kernel(const float* __restrict__ x, const float* __restrict__ w,
                               unsigned short* __restrict__ y) {
    int r = blockIdx.x, tid = threadIdx.x;
    const float* xr = x + (size_t)r * Hdim;
    float v0 = xr[tid], v1 = xr[tid + 256], v2 = xr[tid + 512];
    __shared__ float red[256];
    red[tid] = v0 * v0 + v1 * v1 + v2 * v2;
    __syncthreads();
    for (int off = 128; off; off >>= 1) {
        if (tid < off) red[tid] += red[tid + off];
        __syncthreads();
    }
    float rms = sqrtf(red[0] / (float)Hdim);
    float s = 1.0f / (rms + 1e-6f);
    unsigned short* yr = y + (size_t)r * Hdim;
    yr[tid]       = f2b(v0 * s * w[tid]);
    yr[tid + 256] = f2b(v1 * s * w[tid + 256]);
    yr[tid + 512] = f2b(v2 * s * w[tid + 512]);
}

// ---------------- unpatchify ----------------
__global__ void unpatch_kernel(const float* __restrict__ y, float* __restrict__ out) {
    int bc = blockIdx.x;
    int iy = bc & 127;
    int t  = bc >> 7;
    int c  = t % 3;
    int b  = t / 3;
    int ix = threadIdx.x;
    int gy = iy >> 3, py = iy & 7, gx = ix >> 3, px = ix & 7;
    out[((size_t)(b * 3 + c) * IMG + iy) * IMG + ix] =
        y[(size_t)(b * Ltok + gy * 16 + gx) * PDim + (py * 8 + px) * 3 + c];
}

extern "C" void kernel_launch(void* const* d_in, const int* in_sizes, int n_in,
                              void* d_out, int out_size, void* d_ws, size_t ws_size,
                              hipStream_t stream) {
    const float* x        = (const float*)d_in[0];
    const int*   t_idx    = (const int*)  d_in[1];
    const float* patch_W  = (const float*)d_in[2];
    const float* t_emb    = (const float*)d_in[3];
    const float* Wuv      = (const float*)d_in[4];
    const float* Wout     = (const float*)d_in[5];
    const float* gnorm    = (const float*)d_in[6];
    const float* fnorm    = (const float*)d_in[7];
    const float* unpatchW = (const float*)d_in[8];
    float* out = (float*)d_out;

    // ---- workspace layout ----
    char* wsb = (char*)d_ws;
    size_t off = 0;
    auto alloc = [&](size_t bytes) { char* p = wsb + off; off += (bytes + 255) & ~(size_t)255; return p; };
    float* pe   = (float*)alloc(256 * 128 * 4);
    float* h    = (float*)alloc((size_t)Mrows * Hdim * 4);
    float* qk   = (float*)alloc((size_t)Mrows * 256 * 4);
    float* y    = (float*)alloc((size_t)Mrows * PDim * 4);
    unsigned short* xp   = (unsigned short*)alloc((size_t)Mrows * PDim * 2);
    unsigned short* xn   = (unsigned short*)alloc((size_t)Mrows * Hdim * 2);
    unsigned short* uT   = (unsigned short*)alloc((size_t)Edim * Mrows * 2);
    unsigned short* vT   = (unsigned short*)alloc((size_t)Bsz * Edim * Ltok * 2);
    unsigned short* qh   = (unsigned short*)alloc((size_t)Mrows * 128 * 2);
    unsigned short* kh   = (unsigned short*)alloc((size_t)Mrows * 128 * 2);
    unsigned short* o_bf = (unsigned short*)alloc((size_t)Mrows * Edim * 2);
    unsigned short* WuvT  = (unsigned short*)alloc((size_t)NLAY * UVW * Hdim * 2);
    unsigned short* WoutT = (unsigned short*)alloc((size_t)NLAY * Hdim * Edim * 2);
    unsigned short* patchWT   = (unsigned short*)alloc((size_t)Hdim * PDim * 2);
    unsigned short* unpatchWT = (unsigned short*)alloc((size_t)PDim * Hdim * 2);
    if (off > ws_size) return;   // distinct failure signature (out stays 0)

    pe_kernel<<<256, 128, 0, stream>>>(pe);
    patchify_kernel<<<Bsz * 3 * IMG, IMG, 0, stream>>>(x, xp);

    // weight transposes upfront (batched over layers)
    trans_kernel<<<dim3(Hdim / 32, PDim / 32, 1), dim3(32, 8), 0, stream>>>(
        patch_W, Hdim, 0, patchWT, PDim, 0);
    trans_kernel<<<dim3(PDim / 32, Hdim / 32, 1), dim3(32, 8), 0, stream>>>(
        unpatchW, PDim, 0, unpatchWT, Hdim, 0);
    trans_kernel<<<dim3(UVW / 32, Hdim / 32, NLAY), dim3(32, 8), 0, stream>>>(
        Wuv, UVW, (long long)Hdim * UVW, WuvT, Hdim, (long long)UVW * Hdim);
    trans_kernel<<<dim3(Hdim / 32, Edim / 32, NLAY), dim3(32, 8), 0, stream>>>(
        Wout, Hdim, (long long)Edim * Hdim, WoutT, Edim, (long long)Hdim * Edim);

    gemm_bf16<0><<<dim3(Hdim / 128, Mrows / 128, 1), 256, 0, stream>>>(
        xp, PDim, 0, patchWT, PDim, 0, h, Hdim, 0, PDim, Hdim);
    bias_kernel<<<Mrows, 256, 0, stream>>>(h, t_emb, t_idx);

    for (int l = 0; l < NLAY; ++l) {
        rmsnorm_kernel<<<Mrows, 256, 0, stream>>>(h, gnorm + (size_t)l * Hdim, xn);
        gemm_uvqk<<<dim3(UVW / 128, Mrows / 128, 1), 256, 0, stream>>>(
            xn, WuvT + (size_t)l * UVW * Hdim, uT, vT, qk);
        rope_kernel<<<Mrows, 64, 0, stream>>>(qk, pe, qh, kh);
        fused_attn<<<dim3(4, 4, Bsz), 256, 0, stream>>>(qh, kh, vT, uT, o_bf);
        gemm_bf16<1><<<dim3(Hdim / 128, Mrows / 128, 1), 256, 0, stream>>>(
            o_bf, Edim, 0, WoutT + (size_t)l * Hdim * Edim, Edim, 0, h, Hdim, 0, Edim, Hdim);
    }

    rmsnorm_kernel<<<Mrows, 256, 0, stream>>>(h, fnorm, xn);
    gemm_bf16<0><<<dim3(2, Mrows / 128, 1), 256, 0, stream>>>(
        xn, Hdim, 0, unpatchWT, Hdim, 0, y, PDim, 0, Hdim, PDim);
    unpatch_kernel<<<Bsz * 3 * IMG, IMG, 0, stream>>>(y, out);
}

// Round 5
// 3462.505 us; speedup vs baseline: 4.0415x; 1.0689x over previous
//
#include <hip/hip_runtime.h>
#include <math.h>

#define IMG   128
#define Hdim  768
#define Edim  1536
#define Ltok  256
#define PDim  192
#define NLAY  24
#define Bsz   16
#define Mrows 4096          // B * L
#define UVW   3328          // 2E + 2K

typedef __bf16 bf16x8 __attribute__((ext_vector_type(8)));
typedef float  f32x4  __attribute__((ext_vector_type(4)));

__device__ __forceinline__ unsigned short f2b(float f) {
    unsigned int u = __float_as_uint(f);
    unsigned int r = (u + 0x7FFF + ((u >> 16) & 1)) >> 16;
    return (unsigned short)r;
}
__device__ __forceinline__ float b2f(unsigned short s) {
    return __uint_as_float((unsigned int)s << 16);
}
__device__ __forceinline__ unsigned int pk2(float lo, float hi) {
    return (unsigned int)f2b(lo) | ((unsigned int)f2b(hi) << 16);
}
__device__ __forceinline__ float silu(float x) {
    return x / (1.0f + expf(-x));
}
__device__ __forceinline__ void gload16(const void* g, void* l) {
    __builtin_amdgcn_global_load_lds(
        (const __attribute__((address_space(1))) void*)g,
        (__attribute__((address_space(3))) void*)l, 16, 0, 0);
}
// bijective XCD-chunking remap (m204): same-XCD blocks get contiguous wg range
__device__ __forceinline__ void xcd_swz(int nbx, int& bx, int& by) {
    int nwg = gridDim.x;
    int orig = blockIdx.x;
    int q8 = nwg >> 3, r8 = nwg & 7;
    int xcd = orig & 7, loc = orig >> 3;
    int wg = (xcd < r8 ? xcd * (q8 + 1) : r8 * (q8 + 1) + (xcd - r8) * q8) + loc;
    bx = wg % nbx;
    by = wg / nbx;
}

// ---------------- RoPE table ----------------
__global__ void pe_kernel(float* __restrict__ pe) {
    int l = blockIdx.x;
    int j = threadIdx.x;
    const float c = -logf(1000.0f) / 31.0f;
    int   sub = j & 31;
    float f   = expf(c * (float)sub);
    float pos = (j < 64) ? (float)(l >> 4) : (float)(l & 15);
    float ang = pos * f;
    pe[l * 128 + j] = ((j & 32) == 0) ? sinf(ang) : cosf(ang);
}

// ---------------- patchify -> bf16 ----------------
__global__ void patchify_kernel(const float* __restrict__ x, unsigned short* __restrict__ xp) {
    int bc = blockIdx.x;
    int iy = bc & 127;
    int t  = bc >> 7;
    int c  = t % 3;
    int b  = t / 3;
    int ix = threadIdx.x;
    float v = x[((size_t)(b * 3 + c) * IMG + iy) * IMG + ix];
    int gy = iy >> 3, py = iy & 7, gx = ix >> 3, px = ix & 7;
    xp[(size_t)(b * Ltok + gy * 16 + gx) * PDim + (py * 8 + px) * 3 + c] = f2b(v);
}

// ---------------- fp32 [R][C] -> bf16 transposed [C][R] ----------------
__global__ void trans_kernel(const float* __restrict__ src, int ldS, long long sS,
                             unsigned short* __restrict__ dst, int ldD, long long sD) {
    src += (long long)blockIdx.z * sS;
    dst += (long long)blockIdx.z * sD;
    __shared__ float t[32][33];
    int c0 = blockIdx.x * 32, r0 = blockIdx.y * 32;
    int tx = threadIdx.x, ty = threadIdx.y;   // (32,8)
#pragma unroll
    for (int i = 0; i < 4; ++i)
        t[ty + 8 * i][tx] = src[(size_t)(r0 + ty + 8 * i) * ldS + c0 + tx];
    __syncthreads();
#pragma unroll
    for (int i = 0; i < 4; ++i)
        dst[(size_t)(c0 + ty + 8 * i) * ldD + r0 + tx] = f2b(t[tx][ty + 8 * i]);
}

// ================= generic bf16 MFMA GEMM, double-buffered, XCD-swizzled ====
// C[M,N] (+)= A[M,K] @ Bt[N,K]^T ; 128x128 tile, BK=32, 4 waves of 64x64.
template <int ACC>
__launch_bounds__(256)
__global__ void gemm_bf16(const unsigned short* __restrict__ A, int lda,
                          const unsigned short* __restrict__ Bt, int ldb,
                          float* __restrict__ C, int ldc,
                          int Kt, int Nt, int nbx) {
    __shared__ unsigned short lsA[2][4096];
    __shared__ unsigned short lsB[2][4096];
    int bx, by;
    xcd_swz(nbx, bx, by);
    int tid  = threadIdx.x;
    int lane = tid & 63, w = tid >> 6, wr = w >> 1, wc = w & 1;
    int row0 = by * 128, col0 = bx * 128;
    int fr = lane & 15, fk = (lane >> 4) * 8;
    f32x4 acc[4][4] = {};

    int c0 = tid, c1 = tid + 256;
    int ar0 = row0 + (c0 >> 2), ar1 = row0 + (c1 >> 2);
    int bn0 = col0 + (c0 >> 2), bn1 = col0 + (c1 >> 2);
    if (bn0 > Nt - 1) bn0 = Nt - 1;
    if (bn1 > Nt - 1) bn1 = Nt - 1;
    int ka0 = (c0 & 3) * 8, ka1 = (c1 & 3) * 8;

#define STAGE_G(buf, k0)                                                       \
    gload16(A  + (size_t)ar0 * lda + (k0) + ka0, &lsA[buf][c0 * 8]);           \
    gload16(A  + (size_t)ar1 * lda + (k0) + ka1, &lsA[buf][c1 * 8]);           \
    gload16(Bt + (size_t)bn0 * ldb + (k0) + ka0, &lsB[buf][c0 * 8]);           \
    gload16(Bt + (size_t)bn1 * ldb + (k0) + ka1, &lsB[buf][c1 * 8]);

    STAGE_G(0, 0);
    __syncthreads();
    int nt = Kt >> 5, cur = 0;
    for (int t = 0; t < nt; ++t) {
        if (t + 1 < nt) { STAGE_G(cur ^ 1, (t + 1) * 32); }
        bf16x8 af[4], bfr[4];
#pragma unroll
        for (int m = 0; m < 4; ++m)
            af[m] = *(const bf16x8*)(&lsA[cur][(wr * 64 + m * 16 + fr) * 32 + fk]);
#pragma unroll
        for (int n = 0; n < 4; ++n)
            bfr[n] = *(const bf16x8*)(&lsB[cur][(wc * 64 + n * 16 + fr) * 32 + fk]);
#pragma unroll
        for (int m = 0; m < 4; ++m)
#pragma unroll
            for (int n = 0; n < 4; ++n)
                acc[m][n] = __builtin_amdgcn_mfma_f32_16x16x32_bf16(af[m], bfr[n], acc[m][n], 0, 0, 0);
        __syncthreads();
        cur ^= 1;
    }
#undef STAGE_G

    int crow = (lane >> 4) * 4;
#pragma unroll
    for (int m = 0; m < 4; ++m) {
#pragma unroll
        for (int n = 0; n < 4; ++n) {
            int gc = col0 + wc * 64 + n * 16 + fr;
            if (gc >= Nt) continue;
#pragma unroll
            for (int j = 0; j < 4; ++j) {
                size_t idx = (size_t)(row0 + wr * 64 + m * 16 + crow + j) * ldc + gc;
                if (ACC) C[idx] += acc[m][n][j];
                else     C[idx]  = acc[m][n][j];
            }
        }
    }
}

// ================= uvqk GEMM: dbuf + XCD swizzle + fused silu/rope epilogue ==
// A = xn [4096][768] bf16, Bt = WuvT_l [3328][768] bf16.
// col-tiles 0-11: silu -> uT [1536][4096]; 12-23: silu -> vT [16][1536][256];
// 24: rope+scale -> qh [4096][128]; 25: rope -> kh [4096][128].
__launch_bounds__(256)
__global__ void gemm_uvqk(const unsigned short* __restrict__ A,
                          const unsigned short* __restrict__ Bt,
                          unsigned short* __restrict__ uT,
                          unsigned short* __restrict__ vT,
                          unsigned short* __restrict__ qh,
                          unsigned short* __restrict__ kh,
                          const float* __restrict__ pe) {
    __shared__ char smem[64 * 130 * 4];     // staging (32KB) + rope scratch (33280B)
    int bx, by;
    xcd_swz(26, bx, by);
    int tid  = threadIdx.x;
    int lane = tid & 63, w = tid >> 6, wr = w >> 1, wc = w & 1;
    int row0 = by * 128, col0 = bx * 128;
    int fr = lane & 15, fk = (lane >> 4) * 8;
    f32x4 acc[4][4] = {};

    int c0 = tid, c1 = tid + 256;
    int ar0 = row0 + (c0 >> 2), ar1 = row0 + (c1 >> 2);
    int bn0 = col0 + (c0 >> 2), bn1 = col0 + (c1 >> 2);
    int ka0 = (c0 & 3) * 8, ka1 = (c1 & 3) * 8;

#define STAGE_U(buf, k0)                                                             \
    gload16(A  + (size_t)ar0 * Hdim + (k0) + ka0, smem + (buf) * 8192 + c0 * 16);    \
    gload16(A  + (size_t)ar1 * Hdim + (k0) + ka1, smem + (buf) * 8192 + c1 * 16);    \
    gload16(Bt + (size_t)bn0 * Hdim + (k0) + ka0, smem + 16384 + (buf) * 8192 + c0 * 16); \
    gload16(Bt + (size_t)bn1 * Hdim + (k0) + ka1, smem + 16384 + (buf) * 8192 + c1 * 16);

    STAGE_U(0, 0);
    __syncthreads();
    int cur = 0;
    for (int t = 0; t < Hdim / 32; ++t) {
        if (t + 1 < Hdim / 32) { STAGE_U(cur ^ 1, (t + 1) * 32); }
        const unsigned short* lA = (const unsigned short*)(smem + cur * 8192);
        const unsigned short* lB = (const unsigned short*)(smem + 16384 + cur * 8192);
        bf16x8 af[4], bfr[4];
#pragma unroll
        for (int m = 0; m < 4; ++m)
            af[m] = *(const bf16x8*)(&lA[(wr * 64 + m * 16 + fr) * 32 + fk]);
#pragma unroll
        for (int n = 0; n < 4; ++n)
            bfr[n] = *(const bf16x8*)(&lB[(wc * 64 + n * 16 + fr) * 32 + fk]);
#pragma unroll
        for (int m = 0; m < 4; ++m)
#pragma unroll
            for (int n = 0; n < 4; ++n)
                acc[m][n] = __builtin_amdgcn_mfma_f32_16x16x32_bf16(af[m], bfr[n], acc[m][n], 0, 0, 0);
        __syncthreads();
        cur ^= 1;
    }
#undef STAGE_U

    int crow = (lane >> 4) * 4;

    if (bx >= 24) {
        // ---- rope epilogue: stage q/k tile (fp32) in LDS, pair (d, d+64) ----
        bool isq = (bx == 24);
        const float scale = isq ? 0.08838834764831845f : 1.0f;   // 128^-0.5 on q
        unsigned short* dst = isq ? qh : kh;
        float* S = (float*)smem;          // [64][130]
#pragma unroll
        for (int pass = 0; pass < 2; ++pass) {
            __syncthreads();
            if (wr == pass) {
#pragma unroll
                for (int m = 0; m < 4; ++m)
#pragma unroll
                    for (int n = 0; n < 4; ++n) {
                        int rl = m * 16 + crow;
                        int cl = wc * 64 + n * 16 + fr;
#pragma unroll
                        for (int j = 0; j < 4; ++j)
                            S[(rl + j) * 130 + cl] = acc[m][n][j];
                    }
            }
            __syncthreads();
            int r_loc  = tid >> 2;
            int r_glob = row0 + pass * 64 + r_loc;
            int l = r_glob & 255;
#pragma unroll
            for (int i = 0; i < 16; ++i) {
                int d = (tid & 3) * 16 + i;
                float x1 = S[r_loc * 130 + d];
                float x2 = S[r_loc * 130 + d + 64];
                float sn = pe[l * 128 + d];
                float cs = pe[l * 128 + 64 + d];
                dst[(size_t)r_glob * 128 + d]      = f2b((x1 * cs - x2 * sn) * scale);
                dst[(size_t)r_glob * 128 + d + 64] = f2b((x2 * cs + x1 * sn) * scale);
            }
        }
        return;
    }

#pragma unroll
    for (int m = 0; m < 4; ++m) {
        int row = row0 + wr * 64 + m * 16 + crow;       // multiple of 4
#pragma unroll
        for (int n = 0; n < 4; ++n) {
            int gc = col0 + wc * 64 + n * 16 + fr;
            ushort4 pk;
            pk.x = f2b(silu(acc[m][n][0]));
            pk.y = f2b(silu(acc[m][n][1]));
            pk.z = f2b(silu(acc[m][n][2]));
            pk.w = f2b(silu(acc[m][n][3]));
            if (bx < 12) {
                *(ushort4*)(uT + (size_t)gc * Mrows + row) = pk;
            } else {
                int e = gc - Edim;
                int b = row >> 8, l = row & 255;
                *(ushort4*)(vT + ((size_t)b * Edim + e) * Ltok + l) = pk;
            }
        }
    }
}

// ================= fused attention: softmax(q̂k̂ᵀ) @ V ⊙ u -> o_bf =================
// grid (ec=4, qt=4, b=16), 256 threads, 4 waves. No LDS, no barriers.
__launch_bounds__(256)
__global__ void fused_attn(const unsigned short* __restrict__ qh,
                           const unsigned short* __restrict__ kh,
                           const unsigned short* __restrict__ vT,
                           const unsigned short* __restrict__ uT,
                           unsigned short* __restrict__ ob) {
    int ec = blockIdx.x, qt = blockIdx.y, b = blockIdx.z;
    int tid  = threadIdx.x;
    int lane = tid & 63, w = tid >> 6;
    int fr = lane & 15, hi = lane >> 4;
    int qbase = b * 256 + qt * 64 + w * 16;

    // ---- S^T = mfma(A=k̂, B=q̂): lane holds q-row fr, kcols {mf*16+hi*4+j} ----
    bf16x8 qf[4];
#pragma unroll
    for (int ks = 0; ks < 4; ++ks)
        qf[ks] = *(const bf16x8*)(qh + (size_t)(qbase + fr) * 128 + ks * 32 + hi * 8);
    f32x4 sacc[16] = {};
#pragma unroll
    for (int mf = 0; mf < 16; ++mf) {
#pragma unroll
        for (int ks = 0; ks < 4; ++ks) {
            bf16x8 kf = *(const bf16x8*)(kh + (size_t)(b * 256 + mf * 16 + fr) * 128 + ks * 32 + hi * 8);
            sacc[mf] = __builtin_amdgcn_mfma_f32_16x16x32_bf16(kf, qf[ks], sacc[mf], 0, 0, 0);
        }
    }

    // ---- softmax over the row (in-lane + xor16 + xor32) ----
    float mx = -3.4e38f;
#pragma unroll
    for (int mf = 0; mf < 16; ++mf)
#pragma unroll
        for (int j = 0; j < 4; ++j)
            mx = fmaxf(mx, sacc[mf][j]);
    mx = fmaxf(mx, __shfl_xor(mx, 16, 64));
    mx = fmaxf(mx, __shfl_xor(mx, 32, 64));
    float sum = 0.f;
#pragma unroll
    for (int mf = 0; mf < 16; ++mf)
#pragma unroll
        for (int j = 0; j < 4; ++j) {
            float e = expf(sacc[mf][j] - mx);
            sacc[mf][j] = e;
            sum += e;
        }
    sum += __shfl_xor(sum, 16, 64);
    sum += __shfl_xor(sum, 32, 64);
    float inv = 1.0f / sum;

    // ---- pack P to bf16 dwords ----
    unsigned int dw[16][2];
#pragma unroll
    for (int mf = 0; mf < 16; ++mf) {
        dw[mf][0] = pk2(sacc[mf][0] * inv, sacc[mf][1] * inv);
        dw[mf][1] = pk2(sacc[mf][2] * inv, sacc[mf][3] * inv);
    }

    // ---- shuffle into PV A-frags ----
    int sA = fr + 32 * (hi & 1);
    int sB = sA + 16;
    bool up = (hi >> 1) != 0;
    unsigned int pa[8][4];
#pragma unroll
    for (int ks = 0; ks < 8; ++ks) {
        unsigned int a00 = __shfl((int)dw[2 * ks][0],     sA, 64);
        unsigned int a01 = __shfl((int)dw[2 * ks + 1][0], sA, 64);
        unsigned int a10 = __shfl((int)dw[2 * ks][1],     sA, 64);
        unsigned int a11 = __shfl((int)dw[2 * ks + 1][1], sA, 64);
        unsigned int b00 = __shfl((int)dw[2 * ks][0],     sB, 64);
        unsigned int b01 = __shfl((int)dw[2 * ks + 1][0], sB, 64);
        unsigned int b10 = __shfl((int)dw[2 * ks][1],     sB, 64);
        unsigned int b11 = __shfl((int)dw[2 * ks + 1][1], sB, 64);
        pa[ks][0] = up ? a01 : a00;
        pa[ks][1] = up ? a11 : a10;
        pa[ks][2] = up ? b01 : b00;
        pa[ks][3] = up ? b11 : b10;
    }

    // ---- PV + u-mul epilogue ----
    const unsigned short* vb = vT + (size_t)b * Edim * Ltok;
    int e0 = ec * 384;
#pragma unroll 2
    for (int ef = 0; ef < 24; ++ef) {
        int e = e0 + ef * 16 + fr;
        f32x4 oacc = {};
#pragma unroll
        for (int ks = 0; ks < 8; ++ks) {
            bf16x8 vf = *(const bf16x8*)(vb + (size_t)e * Ltok + ks * 32 + hi * 8);
            oacc = __builtin_amdgcn_mfma_f32_16x16x32_bf16(*(const bf16x8*)&pa[ks], vf, oacc, 0, 0, 0);
        }
        ushort4 uv = *(const ushort4*)(uT + (size_t)e * Mrows + qbase + hi * 4);
        ob[(size_t)(qbase + hi * 4 + 0) * Edim + e] = f2b(oacc[0] * b2f(uv.x));
        ob[(size_t)(qbase + hi * 4 + 1) * Edim + e] = f2b(oacc[1] * b2f(uv.y));
        ob[(size_t)(qbase + hi * 4 + 2) * Edim + e] = f2b(oacc[2] * b2f(uv.z));
        ob[(size_t)(qbase + hi * 4 + 3) * Edim + e] = f2b(oacc[3] * b2f(uv.w));
    }
}

// ---------------- h += t_emb[t_idx[b]] ----------------
__global__ void bias_kernel(float* __restrict__ h, const float* __restrict__ t_emb,
                            const int* __restrict__ t_idx) {
    int r = blockIdx.x;
    int b = r >> 8;
    const float* e = t_emb + (size_t)t_idx[b] * Hdim;
    float* hr = h + (size_t)r * Hdim;
    for (int i = threadIdx.x; i < Hdim; i += 256) hr[i] += e[i];
}

// ---------------- rmsnorm -> bf16 (4 rows/block, wave-shuffle reduce) --------
__global__ void rmsnorm_kernel(const float* __restrict__ x, const float* __restrict__ w,
                               unsigned short* __restrict__ y) {
    int r = blockIdx.x * 4 + (threadIdx.x >> 6);
    int lane = threadIdx.x & 63;
    const float* xr = x + (size_t)r * Hdim;
    float4 a = *(const float4*)&xr[lane * 4];
    float4 b = *(const float4*)&xr[lane * 4 + 256];
    float4 c = *(const float4*)&xr[lane * 4 + 512];
    float ss = a.x * a.x + a.y * a.y + a.z * a.z + a.w * a.w
             + b.x * b.x + b.y * b.y + b.z * b.z + b.w * b.w
             + c.x * c.x + c.y * c.y + c.z * c.z + c.w * c.w;
#pragma unroll
    for (int o = 1; o < 64; o <<= 1) ss += __shfl_xor(ss, o, 64);
    float s = 1.0f / (sqrtf(ss / (float)Hdim) + 1e-6f);
    float4 wa = *(const float4*)&w[lane * 4];
    float4 wb = *(const float4*)&w[lane * 4 + 256];
    float4 wc = *(const float4*)&w[lane * 4 + 512];
    unsigned short* yr = y + (size_t)r * Hdim;
    ushort4 o0, o1, o2;
    o0.x = f2b(a.x * s * wa.x); o0.y = f2b(a.y * s * wa.y);
    o0.z = f2b(a.z * s * wa.z); o0.w = f2b(a.w * s * wa.w);
    o1.x = f2b(b.x * s * wb.x); o1.y = f2b(b.y * s * wb.y);
    o1.z = f2b(b.z * s * wb.z); o1.w = f2b(b.w * s * wb.w);
    o2.x = f2b(c.x * s * wc.x); o2.y = f2b(c.y * s * wc.y);
    o2.z = f2b(c.z * s * wc.z); o2.w = f2b(c.w * s * wc.w);
    *(ushort4*)&yr[lane * 4]       = o0;
    *(ushort4*)&yr[lane * 4 + 256] = o1;
    *(ushort4*)&yr[lane * 4 + 512] = o2;
}

// ---------------- unpatchify ----------------
__global__ void unpatch_kernel(const float* __restrict__ y, float* __restrict__ out) {
    int bc = blockIdx.x;
    int iy = bc & 127;
    int t  = bc >> 7;
    int c  = t % 3;
    int b  = t / 3;
    int ix = threadIdx.x;
    int gy = iy >> 3, py = iy & 7, gx = ix >> 3, px = ix & 7;
    out[((size_t)(b * 3 + c) * IMG + iy) * IMG + ix] =
        y[(size_t)(b * Ltok + gy * 16 + gx) * PDim + (py * 8 + px) * 3 + c];
}

extern "C" void kernel_launch(void* const* d_in, const int* in_sizes, int n_in,
                              void* d_out, int out_size, void* d_ws, size_t ws_size,
                              hipStream_t stream) {
    const float* x        = (const float*)d_in[0];
    const int*   t_idx    = (const int*)  d_in[1];
    const float* patch_W  = (const float*)d_in[2];
    const float* t_emb    = (const float*)d_in[3];
    const float* Wuv      = (const float*)d_in[4];
    const float* Wout     = (const float*)d_in[5];
    const float* gnorm    = (const float*)d_in[6];
    const float* fnorm    = (const float*)d_in[7];
    const float* unpatchW = (const float*)d_in[8];
    float* out = (float*)d_out;

    // ---- workspace layout ----
    char* wsb = (char*)d_ws;
    size_t off = 0;
    auto alloc = [&](size_t bytes) { char* p = wsb + off; off += (bytes + 255) & ~(size_t)255; return p; };
    float* pe   = (float*)alloc(256 * 128 * 4);
    float* h    = (float*)alloc((size_t)Mrows * Hdim * 4);
    float* y    = (float*)alloc((size_t)Mrows * PDim * 4);
    unsigned short* xp   = (unsigned short*)alloc((size_t)Mrows * PDim * 2);
    unsigned short* xn   = (unsigned short*)alloc((size_t)Mrows * Hdim * 2);
    unsigned short* uT   = (unsigned short*)alloc((size_t)Edim * Mrows * 2);
    unsigned short* vT   = (unsigned short*)alloc((size_t)Bsz * Edim * Ltok * 2);
    unsigned short* qh   = (unsigned short*)alloc((size_t)Mrows * 128 * 2);
    unsigned short* kh   = (unsigned short*)alloc((size_t)Mrows * 128 * 2);
    unsigned short* o_bf = (unsigned short*)alloc((size_t)Mrows * Edim * 2);
    unsigned short* WuvT  = (unsigned short*)alloc((size_t)NLAY * UVW * Hdim * 2);
    unsigned short* WoutT = (unsigned short*)alloc((size_t)NLAY * Hdim * Edim * 2);
    unsigned short* patchWT   = (unsigned short*)alloc((size_t)Hdim * PDim * 2);
    unsigned short* unpatchWT = (unsigned short*)alloc((size_t)PDim * Hdim * 2);
    if (off > ws_size) return;   // distinct failure signature (out stays 0)

    pe_kernel<<<256, 128, 0, stream>>>(pe);
    patchify_kernel<<<Bsz * 3 * IMG, IMG, 0, stream>>>(x, xp);

    // weight transposes upfront (batched over layers)
    trans_kernel<<<dim3(Hdim / 32, PDim / 32, 1), dim3(32, 8), 0, stream>>>(
        patch_W, Hdim, 0, patchWT, PDim, 0);
    trans_kernel<<<dim3(PDim / 32, Hdim / 32, 1), dim3(32, 8), 0, stream>>>(
        unpatchW, PDim, 0, unpatchWT, Hdim, 0);
    trans_kernel<<<dim3(UVW / 32, Hdim / 32, NLAY), dim3(32, 8), 0, stream>>>(
        Wuv, UVW, (long long)Hdim * UVW, WuvT, Hdim, (long long)UVW * Hdim);
    trans_kernel<<<dim3(Hdim / 32, Edim / 32, NLAY), dim3(32, 8), 0, stream>>>(
        Wout, Hdim, (long long)Edim * Hdim, WoutT, Edim, (long long)Hdim * Edim);

    gemm_bf16<0><<<(Hdim / 128) * (Mrows / 128), 256, 0, stream>>>(
        xp, PDim, patchWT, PDim, h, Hdim, PDim, Hdim, Hdim / 128);
    bias_kernel<<<Mrows, 256, 0, stream>>>(h, t_emb, t_idx);

    for (int l = 0; l < NLAY; ++l) {
        rmsnorm_kernel<<<Mrows / 4, 256, 0, stream>>>(h, gnorm + (size_t)l * Hdim, xn);
        gemm_uvqk<<<(UVW / 128) * (Mrows / 128), 256, 0, stream>>>(
            xn, WuvT + (size_t)l * UVW * Hdim, uT, vT, qh, kh, pe);
        fused_attn<<<dim3(4, 4, Bsz), 256, 0, stream>>>(qh, kh, vT, uT, o_bf);
        gemm_bf16<1><<<(Hdim / 128) * (Mrows / 128), 256, 0, stream>>>(
            o_bf, Edim, WoutT + (size_t)l * Hdim * Edim, Edim, h, Hdim, Edim, Hdim, Hdim / 128);
    }

    rmsnorm_kernel<<<Mrows / 4, 256, 0, stream>>>(h, fnorm, xn);
    gemm_bf16<0><<<2 * (Mrows / 128), 256, 0, stream>>>(
        xn, Hdim, unpatchWT, Hdim, y, PDim, Hdim, PDim, 2);
    unpatch_kernel<<<Bsz * 3 * IMG, IMG, 0, stream>>>(y, out);
}

// Round 6
// 3148.153 us; speedup vs baseline: 4.4451x; 1.0999x over previous
//
#include <hip/hip_runtime.h>
#include <math.h>

#define IMG   128
#define Hdim  768
#define Edim  1536
#define Ltok  256
#define PDim  192
#define NLAY  24
#define Bsz   16
#define Mrows 4096          // B * L
#define UVW   3328          // 2E + 2K

typedef __bf16 bf16x8 __attribute__((ext_vector_type(8)));
typedef float  f32x4  __attribute__((ext_vector_type(4)));

__device__ __forceinline__ unsigned short f2b(float f) {
    unsigned int u = __float_as_uint(f);
    unsigned int r = (u + 0x7FFF + ((u >> 16) & 1)) >> 16;
    return (unsigned short)r;
}
__device__ __forceinline__ float b2f(unsigned short s) {
    return __uint_as_float((unsigned int)s << 16);
}
__device__ __forceinline__ unsigned int pk2(float lo, float hi) {
    return (unsigned int)f2b(lo) | ((unsigned int)f2b(hi) << 16);
}
__device__ __forceinline__ float silu(float x) {
    return x / (1.0f + expf(-x));
}
__device__ __forceinline__ void gload16(const void* g, void* l) {
    __builtin_amdgcn_global_load_lds(
        (const __attribute__((address_space(1))) void*)g,
        (__attribute__((address_space(3))) void*)l, 16, 0, 0);
}
// bijective XCD-chunking remap (m204)
__device__ __forceinline__ int xcd_wg() {
    int nwg = gridDim.x;
    int orig = blockIdx.x;
    int q8 = nwg >> 3, r8 = nwg & 7;
    int xcd = orig & 7, loc = orig >> 3;
    return (xcd < r8 ? xcd * (q8 + 1) : r8 * (q8 + 1) + (xcd - r8) * q8) + loc;
}

// ---------------- RoPE table ----------------
__global__ void pe_kernel(float* __restrict__ pe) {
    int l = blockIdx.x;
    int j = threadIdx.x;
    const float c = -logf(1000.0f) / 31.0f;
    int   sub = j & 31;
    float f   = expf(c * (float)sub);
    float pos = (j < 64) ? (float)(l >> 4) : (float)(l & 15);
    float ang = pos * f;
    pe[l * 128 + j] = ((j & 32) == 0) ? sinf(ang) : cosf(ang);
}

// ---------------- patchify -> bf16 ----------------
__global__ void patchify_kernel(const float* __restrict__ x, unsigned short* __restrict__ xp) {
    int bc = blockIdx.x;
    int iy = bc & 127;
    int t  = bc >> 7;
    int c  = t % 3;
    int b  = t / 3;
    int ix = threadIdx.x;
    float v = x[((size_t)(b * 3 + c) * IMG + iy) * IMG + ix];
    int gy = iy >> 3, py = iy & 7, gx = ix >> 3, px = ix & 7;
    xp[(size_t)(b * Ltok + gy * 16 + gx) * PDim + (py * 8 + px) * 3 + c] = f2b(v);
}

// ---------------- fp32 [R][C] -> bf16 transposed [C][R] ----------------
__global__ void trans_kernel(const float* __restrict__ src, int ldS, long long sS,
                             unsigned short* __restrict__ dst, int ldD, long long sD) {
    src += (long long)blockIdx.z * sS;
    dst += (long long)blockIdx.z * sD;
    __shared__ float t[32][33];
    int c0 = blockIdx.x * 32, r0 = blockIdx.y * 32;
    int tx = threadIdx.x, ty = threadIdx.y;   // (32,8)
#pragma unroll
    for (int i = 0; i < 4; ++i)
        t[ty + 8 * i][tx] = src[(size_t)(r0 + ty + 8 * i) * ldS + c0 + tx];
    __syncthreads();
#pragma unroll
    for (int i = 0; i < 4; ++i)
        dst[(size_t)(c0 + ty + 8 * i) * ldD + r0 + tx] = f2b(t[tx][ty + 8 * i]);
}

// ================= generic bf16 MFMA GEMM, double-buffered, XCD-swizzled ====
template <int ACC>
__launch_bounds__(256)
__global__ void gemm_bf16(const unsigned short* __restrict__ A, int lda,
                          const unsigned short* __restrict__ Bt, int ldb,
                          float* __restrict__ C, int ldc,
                          int Kt, int Nt, int nbx) {
    __shared__ unsigned short lsA[2][4096];
    __shared__ unsigned short lsB[2][4096];
    int wg = xcd_wg();
    int bx = wg % nbx, by = wg / nbx;
    int tid  = threadIdx.x;
    int lane = tid & 63, w = tid >> 6, wr = w >> 1, wc = w & 1;
    int row0 = by * 128, col0 = bx * 128;
    int fr = lane & 15, fk = (lane >> 4) * 8;
    f32x4 acc[4][4] = {};

    int c0 = tid, c1 = tid + 256;
    int ar0 = row0 + (c0 >> 2), ar1 = row0 + (c1 >> 2);
    int bn0 = col0 + (c0 >> 2), bn1 = col0 + (c1 >> 2);
    if (bn0 > Nt - 1) bn0 = Nt - 1;
    if (bn1 > Nt - 1) bn1 = Nt - 1;
    int ka0 = (c0 & 3) * 8, ka1 = (c1 & 3) * 8;

#define STAGE_G(buf, k0)                                                       \
    gload16(A  + (size_t)ar0 * lda + (k0) + ka0, &lsA[buf][c0 * 8]);           \
    gload16(A  + (size_t)ar1 * lda + (k0) + ka1, &lsA[buf][c1 * 8]);           \
    gload16(Bt + (size_t)bn0 * ldb + (k0) + ka0, &lsB[buf][c0 * 8]);           \
    gload16(Bt + (size_t)bn1 * ldb + (k0) + ka1, &lsB[buf][c1 * 8]);

    STAGE_G(0, 0);
    __syncthreads();
    int nt = Kt >> 5, cur = 0;
    for (int t = 0; t < nt; ++t) {
        if (t + 1 < nt) { STAGE_G(cur ^ 1, (t + 1) * 32); }
        bf16x8 af[4], bfr[4];
#pragma unroll
        for (int m = 0; m < 4; ++m)
            af[m] = *(const bf16x8*)(&lsA[cur][(wr * 64 + m * 16 + fr) * 32 + fk]);
#pragma unroll
        for (int n = 0; n < 4; ++n)
            bfr[n] = *(const bf16x8*)(&lsB[cur][(wc * 64 + n * 16 + fr) * 32 + fk]);
#pragma unroll
        for (int m = 0; m < 4; ++m)
#pragma unroll
            for (int n = 0; n < 4; ++n)
                acc[m][n] = __builtin_amdgcn_mfma_f32_16x16x32_bf16(af[m], bfr[n], acc[m][n], 0, 0, 0);
        __syncthreads();
        cur ^= 1;
    }
#undef STAGE_G

    int crow = (lane >> 4) * 4;
#pragma unroll
    for (int m = 0; m < 4; ++m) {
#pragma unroll
        for (int n = 0; n < 4; ++n) {
            int gc = col0 + wc * 64 + n * 16 + fr;
            if (gc >= Nt) continue;
#pragma unroll
            for (int j = 0; j < 4; ++j) {
                size_t idx = (size_t)(row0 + wr * 64 + m * 16 + crow + j) * ldc + gc;
                if (ACC) C[idx] += acc[m][n][j];
                else     C[idx]  = acc[m][n][j];
            }
        }
    }
}

// ================= wout GEMM, split-K=2 in one launch ========================
// A = o_bf [4096][1536], Bt = WoutT_l [768][1536]. grid 384: sk|by|bx.
// P[sk][4096][768] fp32 partials (residual add fused into next rmsnorm).
__launch_bounds__(256)
__global__ void gemm_wout(const unsigned short* __restrict__ A,
                          const unsigned short* __restrict__ Bt,
                          float* __restrict__ P) {
    __shared__ unsigned short lsA[2][4096];
    __shared__ unsigned short lsB[2][4096];
    int wg = xcd_wg();
    int sk = wg / 192, rem = wg % 192;
    int bx = rem % 6, by = rem / 6;
    int koff = sk * 768;
    float* C = P + (size_t)sk * Mrows * Hdim;
    int tid  = threadIdx.x;
    int lane = tid & 63, w = tid >> 6, wr = w >> 1, wc = w & 1;
    int row0 = by * 128, col0 = bx * 128;
    int fr = lane & 15, fk = (lane >> 4) * 8;
    f32x4 acc[4][4] = {};

    int c0 = tid, c1 = tid + 256;
    int ar0 = row0 + (c0 >> 2), ar1 = row0 + (c1 >> 2);
    int bn0 = col0 + (c0 >> 2), bn1 = col0 + (c1 >> 2);
    int ka0 = koff + (c0 & 3) * 8, ka1 = koff + (c1 & 3) * 8;

#define STAGE_W(buf, k0)                                                       \
    gload16(A  + (size_t)ar0 * Edim + (k0) + ka0, &lsA[buf][c0 * 8]);          \
    gload16(A  + (size_t)ar1 * Edim + (k0) + ka1, &lsA[buf][c1 * 8]);          \
    gload16(Bt + (size_t)bn0 * Edim + (k0) + ka0, &lsB[buf][c0 * 8]);          \
    gload16(Bt + (size_t)bn1 * Edim + (k0) + ka1, &lsB[buf][c1 * 8]);

    STAGE_W(0, 0);
    __syncthreads();
    int cur = 0;
    for (int t = 0; t < 24; ++t) {
        if (t + 1 < 24) { STAGE_W(cur ^ 1, (t + 1) * 32); }
        bf16x8 af[4], bfr[4];
#pragma unroll
        for (int m = 0; m < 4; ++m)
            af[m] = *(const bf16x8*)(&lsA[cur][(wr * 64 + m * 16 + fr) * 32 + fk]);
#pragma unroll
        for (int n = 0; n < 4; ++n)
            bfr[n] = *(const bf16x8*)(&lsB[cur][(wc * 64 + n * 16 + fr) * 32 + fk]);
#pragma unroll
        for (int m = 0; m < 4; ++m)
#pragma unroll
            for (int n = 0; n < 4; ++n)
                acc[m][n] = __builtin_amdgcn_mfma_f32_16x16x32_bf16(af[m], bfr[n], acc[m][n], 0, 0, 0);
        __syncthreads();
        cur ^= 1;
    }
#undef STAGE_W

    int crow = (lane >> 4) * 4;
#pragma unroll
    for (int m = 0; m < 4; ++m) {
#pragma unroll
        for (int n = 0; n < 4; ++n) {
            int gc = col0 + wc * 64 + n * 16 + fr;
#pragma unroll
            for (int j = 0; j < 4; ++j)
                C[(size_t)(row0 + wr * 64 + m * 16 + crow + j) * Hdim + gc] = acc[m][n][j];
        }
    }
}

// ================= uvqk GEMM: dbuf + XCD swizzle + fused silu/rope epilogue ==
__launch_bounds__(256)
__global__ void gemm_uvqk(const unsigned short* __restrict__ A,
                          const unsigned short* __restrict__ Bt,
                          unsigned short* __restrict__ uT,
                          unsigned short* __restrict__ vT,
                          unsigned short* __restrict__ qh,
                          unsigned short* __restrict__ kh,
                          const float* __restrict__ pe) {
    __shared__ char smem[64 * 130 * 4];     // staging (32KB) + rope scratch
    int wg = xcd_wg();
    int bx = wg % 26, by = wg / 26;
    int tid  = threadIdx.x;
    int lane = tid & 63, w = tid >> 6, wr = w >> 1, wc = w & 1;
    int row0 = by * 128, col0 = bx * 128;
    int fr = lane & 15, fk = (lane >> 4) * 8;
    f32x4 acc[4][4] = {};

    int c0 = tid, c1 = tid + 256;
    int ar0 = row0 + (c0 >> 2), ar1 = row0 + (c1 >> 2);
    int bn0 = col0 + (c0 >> 2), bn1 = col0 + (c1 >> 2);
    int ka0 = (c0 & 3) * 8, ka1 = (c1 & 3) * 8;

#define STAGE_U(buf, k0)                                                             \
    gload16(A  + (size_t)ar0 * Hdim + (k0) + ka0, smem + (buf) * 8192 + c0 * 16);    \
    gload16(A  + (size_t)ar1 * Hdim + (k0) + ka1, smem + (buf) * 8192 + c1 * 16);    \
    gload16(Bt + (size_t)bn0 * Hdim + (k0) + ka0, smem + 16384 + (buf) * 8192 + c0 * 16); \
    gload16(Bt + (size_t)bn1 * Hdim + (k0) + ka1, smem + 16384 + (buf) * 8192 + c1 * 16);

    STAGE_U(0, 0);
    __syncthreads();
    int cur = 0;
    for (int t = 0; t < Hdim / 32; ++t) {
        if (t + 1 < Hdim / 32) { STAGE_U(cur ^ 1, (t + 1) * 32); }
        const unsigned short* lA = (const unsigned short*)(smem + cur * 8192);
        const unsigned short* lB = (const unsigned short*)(smem + 16384 + cur * 8192);
        bf16x8 af[4], bfr[4];
#pragma unroll
        for (int m = 0; m < 4; ++m)
            af[m] = *(const bf16x8*)(&lA[(wr * 64 + m * 16 + fr) * 32 + fk]);
#pragma unroll
        for (int n = 0; n < 4; ++n)
            bfr[n] = *(const bf16x8*)(&lB[(wc * 64 + n * 16 + fr) * 32 + fk]);
#pragma unroll
        for (int m = 0; m < 4; ++m)
#pragma unroll
            for (int n = 0; n < 4; ++n)
                acc[m][n] = __builtin_amdgcn_mfma_f32_16x16x32_bf16(af[m], bfr[n], acc[m][n], 0, 0, 0);
        __syncthreads();
        cur ^= 1;
    }
#undef STAGE_U

    int crow = (lane >> 4) * 4;

    if (bx >= 24) {
        // ---- rope epilogue: stage q/k tile (fp32) in LDS, pair (d, d+64) ----
        bool isq = (bx == 24);
        const float scale = isq ? 0.08838834764831845f : 1.0f;   // 128^-0.5 on q
        unsigned short* dst = isq ? qh : kh;
        float* S = (float*)smem;          // [64][130]
#pragma unroll
        for (int pass = 0; pass < 2; ++pass) {
            __syncthreads();
            if (wr == pass) {
#pragma unroll
                for (int m = 0; m < 4; ++m)
#pragma unroll
                    for (int n = 0; n < 4; ++n) {
                        int rl = m * 16 + crow;
                        int cl = wc * 64 + n * 16 + fr;
#pragma unroll
                        for (int j = 0; j < 4; ++j)
                            S[(rl + j) * 130 + cl] = acc[m][n][j];
                    }
            }
            __syncthreads();
            int r_loc  = tid >> 2;
            int r_glob = row0 + pass * 64 + r_loc;
            int l = r_glob & 255;
#pragma unroll
            for (int i = 0; i < 16; ++i) {
                int d = (tid & 3) * 16 + i;
                float x1 = S[r_loc * 130 + d];
                float x2 = S[r_loc * 130 + d + 64];
                float sn = pe[l * 128 + d];
                float cs = pe[l * 128 + 64 + d];
                dst[(size_t)r_glob * 128 + d]      = f2b((x1 * cs - x2 * sn) * scale);
                dst[(size_t)r_glob * 128 + d + 64] = f2b((x2 * cs + x1 * sn) * scale);
            }
        }
        return;
    }

#pragma unroll
    for (int m = 0; m < 4; ++m) {
        int row = row0 + wr * 64 + m * 16 + crow;       // multiple of 4
#pragma unroll
        for (int n = 0; n < 4; ++n) {
            int gc = col0 + wc * 64 + n * 16 + fr;
            ushort4 pk;
            pk.x = f2b(silu(acc[m][n][0]));
            pk.y = f2b(silu(acc[m][n][1]));
            pk.z = f2b(silu(acc[m][n][2]));
            pk.w = f2b(silu(acc[m][n][3]));
            if (bx < 12) {
                *(ushort4*)(uT + (size_t)gc * Mrows + row) = pk;
            } else {
                int e = gc - Edim;
                int b = row >> 8, l = row & 255;
                *(ushort4*)(vT + ((size_t)b * Edim + e) * Ltok + l) = pk;
            }
        }
    }
}

// ================= fused attention: softmax(q̂k̂ᵀ) @ V ⊙ u -> o_bf =================
// grid (ec=8, qt=4, b=16) = 512 blocks (2/CU), 4 waves. No LDS, no barriers.
__launch_bounds__(256)
__global__ void fused_attn(const unsigned short* __restrict__ qh,
                           const unsigned short* __restrict__ kh,
                           const unsigned short* __restrict__ vT,
                           const unsigned short* __restrict__ uT,
                           unsigned short* __restrict__ ob) {
    int ec = blockIdx.x, qt = blockIdx.y, b = blockIdx.z;
    int tid  = threadIdx.x;
    int lane = tid & 63, w = tid >> 6;
    int fr = lane & 15, hi = lane >> 4;
    int qbase = b * 256 + qt * 64 + w * 16;

    // ---- S^T = mfma(A=k̂, B=q̂): lane holds q-row fr, kcols {mf*16+hi*4+j} ----
    bf16x8 qf[4];
#pragma unroll
    for (int ks = 0; ks < 4; ++ks)
        qf[ks] = *(const bf16x8*)(qh + (size_t)(qbase + fr) * 128 + ks * 32 + hi * 8);
    f32x4 sacc[16] = {};
#pragma unroll
    for (int mf = 0; mf < 16; ++mf) {
#pragma unroll
        for (int ks = 0; ks < 4; ++ks) {
            bf16x8 kf = *(const bf16x8*)(kh + (size_t)(b * 256 + mf * 16 + fr) * 128 + ks * 32 + hi * 8);
            sacc[mf] = __builtin_amdgcn_mfma_f32_16x16x32_bf16(kf, qf[ks], sacc[mf], 0, 0, 0);
        }
    }

    // ---- softmax over the row (in-lane + xor16 + xor32) ----
    float mx = -3.4e38f;
#pragma unroll
    for (int mf = 0; mf < 16; ++mf)
#pragma unroll
        for (int j = 0; j < 4; ++j)
            mx = fmaxf(mx, sacc[mf][j]);
    mx = fmaxf(mx, __shfl_xor(mx, 16, 64));
    mx = fmaxf(mx, __shfl_xor(mx, 32, 64));
    float sum = 0.f;
#pragma unroll
    for (int mf = 0; mf < 16; ++mf)
#pragma unroll
        for (int j = 0; j < 4; ++j) {
            float e = expf(sacc[mf][j] - mx);
            sacc[mf][j] = e;
            sum += e;
        }
    sum += __shfl_xor(sum, 16, 64);
    sum += __shfl_xor(sum, 32, 64);
    float inv = 1.0f / sum;

    // ---- pack P to bf16 dwords ----
    unsigned int dw[16][2];
#pragma unroll
    for (int mf = 0; mf < 16; ++mf) {
        dw[mf][0] = pk2(sacc[mf][0] * inv, sacc[mf][1] * inv);
        dw[mf][1] = pk2(sacc[mf][2] * inv, sacc[mf][3] * inv);
    }

    // ---- shuffle into PV A-frags ----
    int sA = fr + 32 * (hi & 1);
    int sB = sA + 16;
    bool up = (hi >> 1) != 0;
    unsigned int pa[8][4];
#pragma unroll
    for (int ks = 0; ks < 8; ++ks) {
        unsigned int a00 = __shfl((int)dw[2 * ks][0],     sA, 64);
        unsigned int a01 = __shfl((int)dw[2 * ks + 1][0], sA, 64);
        unsigned int a10 = __shfl((int)dw[2 * ks][1],     sA, 64);
        unsigned int a11 = __shfl((int)dw[2 * ks + 1][1], sA, 64);
        unsigned int b00 = __shfl((int)dw[2 * ks][0],     sB, 64);
        unsigned int b01 = __shfl((int)dw[2 * ks + 1][0], sB, 64);
        unsigned int b10 = __shfl((int)dw[2 * ks][1],     sB, 64);
        unsigned int b11 = __shfl((int)dw[2 * ks + 1][1], sB, 64);
        pa[ks][0] = up ? a01 : a00;
        pa[ks][1] = up ? a11 : a10;
        pa[ks][2] = up ? b01 : b00;
        pa[ks][3] = up ? b11 : b10;
    }

    // ---- PV + u-mul epilogue over e-chunk of 192 ----
    const unsigned short* vb = vT + (size_t)b * Edim * Ltok;
    int e0 = ec * 192;
#pragma unroll 2
    for (int ef = 0; ef < 12; ++ef) {
        int e = e0 + ef * 16 + fr;
        f32x4 oacc = {};
#pragma unroll
        for (int ks = 0; ks < 8; ++ks) {
            bf16x8 vf = *(const bf16x8*)(vb + (size_t)e * Ltok + ks * 32 + hi * 8);
            oacc = __builtin_amdgcn_mfma_f32_16x16x32_bf16(*(const bf16x8*)&pa[ks], vf, oacc, 0, 0, 0);
        }
        ushort4 uv = *(const ushort4*)(uT + (size_t)e * Mrows + qbase + hi * 4);
        ob[(size_t)(qbase + hi * 4 + 0) * Edim + e] = f2b(oacc[0] * b2f(uv.x));
        ob[(size_t)(qbase + hi * 4 + 1) * Edim + e] = f2b(oacc[1] * b2f(uv.y));
        ob[(size_t)(qbase + hi * 4 + 2) * Edim + e] = f2b(oacc[2] * b2f(uv.z));
        ob[(size_t)(qbase + hi * 4 + 3) * Edim + e] = f2b(oacc[3] * b2f(uv.w));
    }
}

// ---------------- h += t_emb[t_idx[b]] ----------------
__global__ void bias_kernel(float* __restrict__ h, const float* __restrict__ t_emb,
                            const int* __restrict__ t_idx) {
    int r = blockIdx.x;
    int b = r >> 8;
    const float* e = t_emb + (size_t)t_idx[b] * Hdim;
    float* hr = h + (size_t)r * Hdim;
    for (int i = threadIdx.x; i < Hdim; i += 256) hr[i] += e[i];
}

// ------ rmsnorm (4 rows/block, wave reduce); ADD=1: h = h + p0 + p1 first ----
template <int ADD>
__global__ void rmsnorm_kernel(float* __restrict__ x, const float* __restrict__ p,
                               const float* __restrict__ w, unsigned short* __restrict__ y) {
    int r = blockIdx.x * 4 + (threadIdx.x >> 6);
    int lane = threadIdx.x & 63;
    float* xr = x + (size_t)r * Hdim;
    float4 a = *(const float4*)&xr[lane * 4];
    float4 b = *(const float4*)&xr[lane * 4 + 256];
    float4 c = *(const float4*)&xr[lane * 4 + 512];
    if (ADD) {
        const float* p0 = p + (size_t)r * Hdim;
        const float* p1 = p + (size_t)(Mrows + r) * Hdim;
        float4 a0 = *(const float4*)&p0[lane * 4];
        float4 b0 = *(const float4*)&p0[lane * 4 + 256];
        float4 c0 = *(const float4*)&p0[lane * 4 + 512];
        float4 a1 = *(const float4*)&p1[lane * 4];
        float4 b1 = *(const float4*)&p1[lane * 4 + 256];
        float4 c1 = *(const float4*)&p1[lane * 4 + 512];
        a.x += a0.x + a1.x; a.y += a0.y + a1.y; a.z += a0.z + a1.z; a.w += a0.w + a1.w;
        b.x += b0.x + b1.x; b.y += b0.y + b1.y; b.z += b0.z + b1.z; b.w += b0.w + b1.w;
        c.x += c0.x + c1.x; c.y += c0.y + c1.y; c.z += c0.z + c1.z; c.w += c0.w + c1.w;
        *(float4*)&xr[lane * 4]       = a;
        *(float4*)&xr[lane * 4 + 256] = b;
        *(float4*)&xr[lane * 4 + 512] = c;
    }
    float ss = a.x * a.x + a.y * a.y + a.z * a.z + a.w * a.w
             + b.x * b.x + b.y * b.y + b.z * b.z + b.w * b.w
             + c.x * c.x + c.y * c.y + c.z * c.z + c.w * c.w;
#pragma unroll
    for (int o = 1; o < 64; o <<= 1) ss += __shfl_xor(ss, o, 64);
    float s = 1.0f / (sqrtf(ss / (float)Hdim) + 1e-6f);
    float4 wa = *(const float4*)&w[lane * 4];
    float4 wb = *(const float4*)&w[lane * 4 + 256];
    float4 wc = *(const float4*)&w[lane * 4 + 512];
    unsigned short* yr = y + (size_t)r * Hdim;
    ushort4 o0, o1, o2;
    o0.x = f2b(a.x * s * wa.x); o0.y = f2b(a.y * s * wa.y);
    o0.z = f2b(a.z * s * wa.z); o0.w = f2b(a.w * s * wa.w);
    o1.x = f2b(b.x * s * wb.x); o1.y = f2b(b.y * s * wb.y);
    o1.z = f2b(b.z * s * wb.z); o1.w = f2b(b.w * s * wb.w);
    o2.x = f2b(c.x * s * wc.x); o2.y = f2b(c.y * s * wc.y);
    o2.z = f2b(c.z * s * wc.z); o2.w = f2b(c.w * s * wc.w);
    *(ushort4*)&yr[lane * 4]       = o0;
    *(ushort4*)&yr[lane * 4 + 256] = o1;
    *(ushort4*)&yr[lane * 4 + 512] = o2;
}

// ---------------- unpatchify ----------------
__global__ void unpatch_kernel(const float* __restrict__ y, float* __restrict__ out) {
    int bc = blockIdx.x;
    int iy = bc & 127;
    int t  = bc >> 7;
    int c  = t % 3;
    int b  = t / 3;
    int ix = threadIdx.x;
    int gy = iy >> 3, py = iy & 7, gx = ix >> 3, px = ix & 7;
    out[((size_t)(b * 3 + c) * IMG + iy) * IMG + ix] =
        y[(size_t)(b * Ltok + gy * 16 + gx) * PDim + (py * 8 + px) * 3 + c];
}

extern "C" void kernel_launch(void* const* d_in, const int* in_sizes, int n_in,
                              void* d_out, int out_size, void* d_ws, size_t ws_size,
                              hipStream_t stream) {
    const float* x        = (const float*)d_in[0];
    const int*   t_idx    = (const int*)  d_in[1];
    const float* patch_W  = (const float*)d_in[2];
    const float* t_emb    = (const float*)d_in[3];
    const float* Wuv      = (const float*)d_in[4];
    const float* Wout     = (const float*)d_in[5];
    const float* gnorm    = (const float*)d_in[6];
    const float* fnorm    = (const float*)d_in[7];
    const float* unpatchW = (const float*)d_in[8];
    float* out = (float*)d_out;

    // ---- workspace layout ----
    char* wsb = (char*)d_ws;
    size_t off = 0;
    auto alloc = [&](size_t bytes) { char* p = wsb + off; off += (bytes + 255) & ~(size_t)255; return p; };
    float* pe   = (float*)alloc(256 * 128 * 4);
    float* h    = (float*)alloc((size_t)Mrows * Hdim * 4);
    float* pbuf = (float*)alloc((size_t)2 * Mrows * Hdim * 4);
    float* y    = (float*)alloc((size_t)Mrows * PDim * 4);
    unsigned short* xp   = (unsigned short*)alloc((size_t)Mrows * PDim * 2);
    unsigned short* xn   = (unsigned short*)alloc((size_t)Mrows * Hdim * 2);
    unsigned short* uT   = (unsigned short*)alloc((size_t)Edim * Mrows * 2);
    unsigned short* vT   = (unsigned short*)alloc((size_t)Bsz * Edim * Ltok * 2);
    unsigned short* qh   = (unsigned short*)alloc((size_t)Mrows * 128 * 2);
    unsigned short* kh   = (unsigned short*)alloc((size_t)Mrows * 128 * 2);
    unsigned short* o_bf = (unsigned short*)alloc((size_t)Mrows * Edim * 2);
    unsigned short* WuvT  = (unsigned short*)alloc((size_t)NLAY * UVW * Hdim * 2);
    unsigned short* WoutT = (unsigned short*)alloc((size_t)NLAY * Hdim * Edim * 2);
    unsigned short* patchWT   = (unsigned short*)alloc((size_t)Hdim * PDim * 2);
    unsigned short* unpatchWT = (unsigned short*)alloc((size_t)PDim * Hdim * 2);
    if (off > ws_size) return;   // distinct failure signature (out stays 0)

    pe_kernel<<<256, 128, 0, stream>>>(pe);
    patchify_kernel<<<Bsz * 3 * IMG, IMG, 0, stream>>>(x, xp);

    // weight transposes upfront (batched over layers)
    trans_kernel<<<dim3(Hdim / 32, PDim / 32, 1), dim3(32, 8), 0, stream>>>(
        patch_W, Hdim, 0, patchWT, PDim, 0);
    trans_kernel<<<dim3(PDim / 32, Hdim / 32, 1), dim3(32, 8), 0, stream>>>(
        unpatchW, PDim, 0, unpatchWT, Hdim, 0);
    trans_kernel<<<dim3(UVW / 32, Hdim / 32, NLAY), dim3(32, 8), 0, stream>>>(
        Wuv, UVW, (long long)Hdim * UVW, WuvT, Hdim, (long long)UVW * Hdim);
    trans_kernel<<<dim3(Hdim / 32, Edim / 32, NLAY), dim3(32, 8), 0, stream>>>(
        Wout, Hdim, (long long)Edim * Hdim, WoutT, Edim, (long long)Hdim * Edim);

    gemm_bf16<0><<<(Hdim / 128) * (Mrows / 128), 256, 0, stream>>>(
        xp, PDim, patchWT, PDim, h, Hdim, PDim, Hdim, Hdim / 128);
    bias_kernel<<<Mrows, 256, 0, stream>>>(h, t_emb, t_idx);

    rmsnorm_kernel<0><<<Mrows / 4, 256, 0, stream>>>(h, nullptr, gnorm, xn);
    for (int l = 0; l < NLAY; ++l) {
        gemm_uvqk<<<(UVW / 128) * (Mrows / 128), 256, 0, stream>>>(
            xn, WuvT + (size_t)l * UVW * Hdim, uT, vT, qh, kh, pe);
        fused_attn<<<dim3(8, 4, Bsz), 256, 0, stream>>>(qh, kh, vT, uT, o_bf);
        gemm_wout<<<384, 256, 0, stream>>>(
            o_bf, WoutT + (size_t)l * Hdim * Edim, pbuf);
        const float* nw = (l + 1 < NLAY) ? gnorm + (size_t)(l + 1) * Hdim : fnorm;
        rmsnorm_kernel<1><<<Mrows / 4, 256, 0, stream>>>(h, pbuf, nw, xn);
    }

    gemm_bf16<0><<<2 * (Mrows / 128), 256, 0, stream>>>(
        xn, Hdim, unpatchWT, Hdim, y, PDim, Hdim, PDim, 2);
    unpatch_kernel<<<Bsz * 3 * IMG, IMG, 0, stream>>>(y, out);
}

// Round 7
// 2997.177 us; speedup vs baseline: 4.6690x; 1.0504x over previous
//
#include <hip/hip_runtime.h>
#include <math.h>

#define IMG   128
#define Hdim  768
#define Edim  1536
#define Ltok  256
#define PDim  192
#define NLAY  24
#define Bsz   16
#define Mrows 4096          // B * L
#define UVW   3328          // 2E + 2K

typedef __bf16 bf16x8 __attribute__((ext_vector_type(8)));
typedef float  f32x4  __attribute__((ext_vector_type(4)));

__device__ __forceinline__ unsigned short f2b(float f) {
    unsigned int u = __float_as_uint(f);
    unsigned int r = (u + 0x7FFF + ((u >> 16) & 1)) >> 16;
    return (unsigned short)r;
}
__device__ __forceinline__ float b2f(unsigned short s) {
    return __uint_as_float((unsigned int)s << 16);
}
__device__ __forceinline__ unsigned int pk2(float lo, float hi) {
    return (unsigned int)f2b(lo) | ((unsigned int)f2b(hi) << 16);
}
__device__ __forceinline__ float silu(float x) {
    return x / (1.0f + expf(-x));
}
__device__ __forceinline__ void gload16(const void* g, void* l) {
    __builtin_amdgcn_global_load_lds(
        (const __attribute__((address_space(1))) void*)g,
        (__attribute__((address_space(3))) void*)l, 16, 0, 0);
}
// bijective XCD-chunking remap (m204)
__device__ __forceinline__ int xcd_wg() {
    int nwg = gridDim.x;
    int orig = blockIdx.x;
    int q8 = nwg >> 3, r8 = nwg & 7;
    int xcd = orig & 7, loc = orig >> 3;
    return (xcd < r8 ? xcd * (q8 + 1) : r8 * (q8 + 1) + (xcd - r8) * q8) + loc;
}

// ---------------- RoPE table ----------------
__global__ void pe_kernel(float* __restrict__ pe) {
    int l = blockIdx.x;
    int j = threadIdx.x;
    const float c = -logf(1000.0f) / 31.0f;
    int   sub = j & 31;
    float f   = expf(c * (float)sub);
    float pos = (j < 64) ? (float)(l >> 4) : (float)(l & 15);
    float ang = pos * f;
    pe[l * 128 + j] = ((j & 32) == 0) ? sinf(ang) : cosf(ang);
}

// ---------------- patchify -> bf16 ----------------
__global__ void patchify_kernel(const float* __restrict__ x, unsigned short* __restrict__ xp) {
    int bc = blockIdx.x;
    int iy = bc & 127;
    int t  = bc >> 7;
    int c  = t % 3;
    int b  = t / 3;
    int ix = threadIdx.x;
    float v = x[((size_t)(b * 3 + c) * IMG + iy) * IMG + ix];
    int gy = iy >> 3, py = iy & 7, gx = ix >> 3, px = ix & 7;
    xp[(size_t)(b * Ltok + gy * 16 + gx) * PDim + (py * 8 + px) * 3 + c] = f2b(v);
}

// ---------------- fp32 [R][C] -> bf16 transposed [C][R] ----------------
__global__ void trans_kernel(const float* __restrict__ src, int ldS, long long sS,
                             unsigned short* __restrict__ dst, int ldD, long long sD) {
    src += (long long)blockIdx.z * sS;
    dst += (long long)blockIdx.z * sD;
    __shared__ float t[32][33];
    int c0 = blockIdx.x * 32, r0 = blockIdx.y * 32;
    int tx = threadIdx.x, ty = threadIdx.y;   // (32,8)
#pragma unroll
    for (int i = 0; i < 4; ++i)
        t[ty + 8 * i][tx] = src[(size_t)(r0 + ty + 8 * i) * ldS + c0 + tx];
    __syncthreads();
#pragma unroll
    for (int i = 0; i < 4; ++i)
        dst[(size_t)(c0 + ty + 8 * i) * ldD + r0 + tx] = f2b(t[tx][ty + 8 * i]);
}

// ================= generic bf16 MFMA GEMM, double-buffered, XCD-swizzled ====
template <int ACC>
__launch_bounds__(256)
__global__ void gemm_bf16(const unsigned short* __restrict__ A, int lda,
                          const unsigned short* __restrict__ Bt, int ldb,
                          float* __restrict__ C, int ldc,
                          int Kt, int Nt, int nbx) {
    __shared__ unsigned short lsA[2][4096];
    __shared__ unsigned short lsB[2][4096];
    int wg = xcd_wg();
    int bx = wg % nbx, by = wg / nbx;
    int tid  = threadIdx.x;
    int lane = tid & 63, w = tid >> 6, wr = w >> 1, wc = w & 1;
    int row0 = by * 128, col0 = bx * 128;
    int fr = lane & 15, fk = (lane >> 4) * 8;
    f32x4 acc[4][4] = {};

    int c0 = tid, c1 = tid + 256;
    int ar0 = row0 + (c0 >> 2), ar1 = row0 + (c1 >> 2);
    int bn0 = col0 + (c0 >> 2), bn1 = col0 + (c1 >> 2);
    if (bn0 > Nt - 1) bn0 = Nt - 1;
    if (bn1 > Nt - 1) bn1 = Nt - 1;
    int ka0 = (c0 & 3) * 8, ka1 = (c1 & 3) * 8;

#define STAGE_G(buf, k0)                                                       \
    gload16(A  + (size_t)ar0 * lda + (k0) + ka0, &lsA[buf][c0 * 8]);           \
    gload16(A  + (size_t)ar1 * lda + (k0) + ka1, &lsA[buf][c1 * 8]);           \
    gload16(Bt + (size_t)bn0 * ldb + (k0) + ka0, &lsB[buf][c0 * 8]);           \
    gload16(Bt + (size_t)bn1 * ldb + (k0) + ka1, &lsB[buf][c1 * 8]);

    STAGE_G(0, 0);
    __syncthreads();
    int nt = Kt >> 5, cur = 0;
    for (int t = 0; t < nt; ++t) {
        if (t + 1 < nt) { STAGE_G(cur ^ 1, (t + 1) * 32); }
        bf16x8 af[4], bfr[4];
#pragma unroll
        for (int m = 0; m < 4; ++m)
            af[m] = *(const bf16x8*)(&lsA[cur][(wr * 64 + m * 16 + fr) * 32 + fk]);
#pragma unroll
        for (int n = 0; n < 4; ++n)
            bfr[n] = *(const bf16x8*)(&lsB[cur][(wc * 64 + n * 16 + fr) * 32 + fk]);
#pragma unroll
        for (int m = 0; m < 4; ++m)
#pragma unroll
            for (int n = 0; n < 4; ++n)
                acc[m][n] = __builtin_amdgcn_mfma_f32_16x16x32_bf16(af[m], bfr[n], acc[m][n], 0, 0, 0);
        __syncthreads();
        cur ^= 1;
    }
#undef STAGE_G

    int crow = (lane >> 4) * 4;
#pragma unroll
    for (int m = 0; m < 4; ++m) {
#pragma unroll
        for (int n = 0; n < 4; ++n) {
            int gc = col0 + wc * 64 + n * 16 + fr;
            if (gc >= Nt) continue;
#pragma unroll
            for (int j = 0; j < 4; ++j) {
                size_t idx = (size_t)(row0 + wr * 64 + m * 16 + crow + j) * ldc + gc;
                if (ACC) C[idx] += acc[m][n][j];
                else     C[idx]  = acc[m][n][j];
            }
        }
    }
}

// ================= wout GEMM, split-K=2 in one launch ========================
__launch_bounds__(256)
__global__ void gemm_wout(const unsigned short* __restrict__ A,
                          const unsigned short* __restrict__ Bt,
                          float* __restrict__ P) {
    __shared__ unsigned short lsA[2][4096];
    __shared__ unsigned short lsB[2][4096];
    int wg = xcd_wg();
    int sk = wg / 192, rem = wg % 192;
    int bx = rem % 6, by = rem / 6;
    int koff = sk * 768;
    float* C = P + (size_t)sk * Mrows * Hdim;
    int tid  = threadIdx.x;
    int lane = tid & 63, w = tid >> 6, wr = w >> 1, wc = w & 1;
    int row0 = by * 128, col0 = bx * 128;
    int fr = lane & 15, fk = (lane >> 4) * 8;
    f32x4 acc[4][4] = {};

    int c0 = tid, c1 = tid + 256;
    int ar0 = row0 + (c0 >> 2), ar1 = row0 + (c1 >> 2);
    int bn0 = col0 + (c0 >> 2), bn1 = col0 + (c1 >> 2);
    int ka0 = koff + (c0 & 3) * 8, ka1 = koff + (c1 & 3) * 8;

#define STAGE_W(buf, k0)                                                       \
    gload16(A  + (size_t)ar0 * Edim + (k0) + ka0, &lsA[buf][c0 * 8]);          \
    gload16(A  + (size_t)ar1 * Edim + (k0) + ka1, &lsA[buf][c1 * 8]);          \
    gload16(Bt + (size_t)bn0 * Edim + (k0) + ka0, &lsB[buf][c0 * 8]);          \
    gload16(Bt + (size_t)bn1 * Edim + (k0) + ka1, &lsB[buf][c1 * 8]);

    STAGE_W(0, 0);
    __syncthreads();
    int cur = 0;
    for (int t = 0; t < 24; ++t) {
        if (t + 1 < 24) { STAGE_W(cur ^ 1, (t + 1) * 32); }
        bf16x8 af[4], bfr[4];
#pragma unroll
        for (int m = 0; m < 4; ++m)
            af[m] = *(const bf16x8*)(&lsA[cur][(wr * 64 + m * 16 + fr) * 32 + fk]);
#pragma unroll
        for (int n = 0; n < 4; ++n)
            bfr[n] = *(const bf16x8*)(&lsB[cur][(wc * 64 + n * 16 + fr) * 32 + fk]);
#pragma unroll
        for (int m = 0; m < 4; ++m)
#pragma unroll
            for (int n = 0; n < 4; ++n)
                acc[m][n] = __builtin_amdgcn_mfma_f32_16x16x32_bf16(af[m], bfr[n], acc[m][n], 0, 0, 0);
        __syncthreads();
        cur ^= 1;
    }
#undef STAGE_W

    int crow = (lane >> 4) * 4;
#pragma unroll
    for (int m = 0; m < 4; ++m) {
#pragma unroll
        for (int n = 0; n < 4; ++n) {
            int gc = col0 + wc * 64 + n * 16 + fr;
#pragma unroll
            for (int j = 0; j < 4; ++j)
                C[(size_t)(row0 + wr * 64 + m * 16 + crow + j) * Hdim + gc] = acc[m][n][j];
        }
    }
}

// ================= uvqk GEMM: 256x256 tile, 8-phase counted-vmcnt pipeline ===
// A = xn [4096][768], Bt = WuvT_l [3328][768]. Grid 208 = 13 bx * 16 by, 512 thr.
// BK=64, 2-K-tile double buffer, T2 XOR-swizzle, T5 setprio.
// col-tiles 0-5: silu->uT; 6-11: silu->vT; 12: rope->qh/kh.
__global__ __launch_bounds__(512, 2)
void gemm_uvqk8(const unsigned short* __restrict__ A,
                const unsigned short* __restrict__ Bt,
                unsigned short* __restrict__ uT,
                unsigned short* __restrict__ vT,
                unsigned short* __restrict__ qh,
                unsigned short* __restrict__ kh,
                const float* __restrict__ pe) {
    __shared__ char smem[131072];   // 2 bufs * (A 2x16KB + B 2x16KB)
    int wg = xcd_wg();
    int bx = wg % 13, by = wg / 13;
    int tid = threadIdx.x, lane = tid & 63, wid = tid >> 6;
    int wm = wid >> 2, wn = wid & 3;            // 2 x 4 wave grid
    int row0 = by * 256, col0 = bx * 256;
    int fr = lane & 15, hi = lane >> 4;
    f32x4 acc[8][4] = {};

    // ---- staging: linear LDS dest, pre-swizzled global source ----
    int d0 = tid * 16, d1 = d0 + 8192;
    int s0 = d0 ^ (((d0 >> 7) & 7) << 4);
    int s1 = d1 ^ (((d1 >> 7) & 7) << 4);
    int sr0 = s0 >> 7, sc0 = (s0 & 127) >> 1;
    int sr1 = s1 >> 7, sc1 = (s1 & 127) >> 1;

#define STG_A(bufo, h, kt) do {                                                            \
    gload16(A + (size_t)(row0 + (h) * 128 + sr0) * Hdim + (kt) * 64 + sc0,                 \
            smem + (bufo) + (h) * 16384 + d0);                                             \
    gload16(A + (size_t)(row0 + (h) * 128 + sr1) * Hdim + (kt) * 64 + sc1,                 \
            smem + (bufo) + (h) * 16384 + d1); } while (0)
#define STG_B(bufo, h, kt) do {                                                            \
    gload16(Bt + (size_t)(col0 + (h) * 128 + sr0) * Hdim + (kt) * 64 + sc0,                \
            smem + (bufo) + 32768 + (h) * 16384 + d0);                                     \
    gload16(Bt + (size_t)(col0 + (h) * 128 + sr1) * Hdim + (kt) * 64 + sc1,                \
            smem + (bufo) + 32768 + (h) * 16384 + d1); } while (0)

    // ---- ds_read fragment addressing (swizzled) ----
    int axor = (fr & 7) << 4;
    int abase = wm * 16384 + fr * 128;
    int bbase = 32768 + (wn >> 1) * 16384 + ((wn & 1) * 64 + fr) * 128;
    int koff0 = (hi * 16) ^ axor;
    int koff1 = (hi * 16 + 64) ^ axor;

    // ---- prologue: kt0 (all 4 halves) + kt1 A-halves ----
    STG_A(0, 0, 0); STG_A(0, 1, 0); STG_B(0, 0, 0); STG_B(0, 1, 0);
    STG_A(65536, 0, 1); STG_A(65536, 1, 1);
    asm volatile("s_waitcnt vmcnt(4)" ::: "memory");
    __builtin_amdgcn_s_barrier();
    __builtin_amdgcn_sched_barrier(0);

    bf16x8 af[4][2], bf0[2][2], bf1[2][2];
    const int NKT = Hdim / 64;   // 12
    for (int kt = 0; kt < NKT; ++kt) {
        int curo = (kt & 1) << 16, nxto = curo ^ 65536;
        const char* bufc = smem + curo;

        // ---- phase 0: (mh0, nh0) ----
#pragma unroll
        for (int m = 0; m < 4; ++m) {
            af[m][0] = *(const bf16x8*)(bufc + abase + m * 2048 + koff0);
            af[m][1] = *(const bf16x8*)(bufc + abase + m * 2048 + koff1);
        }
#pragma unroll
        for (int n = 0; n < 2; ++n) {
            bf0[n][0] = *(const bf16x8*)(bufc + bbase + n * 2048 + koff0);
            bf0[n][1] = *(const bf16x8*)(bufc + bbase + n * 2048 + koff1);
        }
        if (kt + 1 < NKT) STG_B(nxto, 0, kt + 1);
        __builtin_amdgcn_s_setprio(1);
#pragma unroll
        for (int m = 0; m < 4; ++m)
#pragma unroll
            for (int n = 0; n < 2; ++n) {
                acc[m][n] = __builtin_amdgcn_mfma_f32_16x16x32_bf16(af[m][0], bf0[n][0], acc[m][n], 0, 0, 0);
                acc[m][n] = __builtin_amdgcn_mfma_f32_16x16x32_bf16(af[m][1], bf0[n][1], acc[m][n], 0, 0, 0);
            }
        __builtin_amdgcn_s_setprio(0);
        __builtin_amdgcn_s_barrier();
        __builtin_amdgcn_sched_barrier(0);

        // ---- phase 1: (mh0, nh1) ----
#pragma unroll
        for (int n = 0; n < 2; ++n) {
            bf1[n][0] = *(const bf16x8*)(bufc + bbase + (n + 2) * 2048 + koff0);
            bf1[n][1] = *(const bf16x8*)(bufc + bbase + (n + 2) * 2048 + koff1);
        }
        if (kt + 1 < NKT) STG_B(nxto, 1, kt + 1);
        __builtin_amdgcn_s_setprio(1);
#pragma unroll
        for (int m = 0; m < 4; ++m)
#pragma unroll
            for (int n = 0; n < 2; ++n) {
                acc[m][n + 2] = __builtin_amdgcn_mfma_f32_16x16x32_bf16(af[m][0], bf1[n][0], acc[m][n + 2], 0, 0, 0);
                acc[m][n + 2] = __builtin_amdgcn_mfma_f32_16x16x32_bf16(af[m][1], bf1[n][1], acc[m][n + 2], 0, 0, 0);
            }
        __builtin_amdgcn_s_setprio(0);
        __builtin_amdgcn_s_barrier();
        __builtin_amdgcn_sched_barrier(0);

        // ---- phase 2: (mh1, nh0) ----
#pragma unroll
        for (int m = 0; m < 4; ++m) {
            af[m][0] = *(const bf16x8*)(bufc + abase + (m + 4) * 2048 + koff0);
            af[m][1] = *(const bf16x8*)(bufc + abase + (m + 4) * 2048 + koff1);
        }
        __builtin_amdgcn_s_setprio(1);
#pragma unroll
        for (int m = 0; m < 4; ++m)
#pragma unroll
            for (int n = 0; n < 2; ++n) {
                acc[m + 4][n] = __builtin_amdgcn_mfma_f32_16x16x32_bf16(af[m][0], bf0[n][0], acc[m + 4][n], 0, 0, 0);
                acc[m + 4][n] = __builtin_amdgcn_mfma_f32_16x16x32_bf16(af[m][1], bf0[n][1], acc[m + 4][n], 0, 0, 0);
            }
        __builtin_amdgcn_s_setprio(0);
        __builtin_amdgcn_s_barrier();
        __builtin_amdgcn_sched_barrier(0);

        // ---- phase 3: (mh1, nh1) ----
        if (kt + 2 < NKT) { STG_A(curo, 0, kt + 2); STG_A(curo, 1, kt + 2); }
        __builtin_amdgcn_s_setprio(1);
#pragma unroll
        for (int m = 0; m < 4; ++m)
#pragma unroll
            for (int n = 0; n < 2; ++n) {
                acc[m + 4][n + 2] = __builtin_amdgcn_mfma_f32_16x16x32_bf16(af[m][0], bf1[n][0], acc[m + 4][n + 2], 0, 0, 0);
                acc[m + 4][n + 2] = __builtin_amdgcn_mfma_f32_16x16x32_bf16(af[m][1], bf1[n][1], acc[m + 4][n + 2], 0, 0, 0);
            }
        __builtin_amdgcn_s_setprio(0);
        asm volatile("s_waitcnt vmcnt(4)" ::: "memory");
        __builtin_amdgcn_s_barrier();
        __builtin_amdgcn_sched_barrier(0);
    }
#undef STG_A
#undef STG_B

    // ================= epilogue =================
    if (bx == 12) {
        // rope: 4 passes of 64 rows through LDS (fp32), q cols 0-127, k 128-255
        float* S = (float*)smem;
        const float qscale = 0.08838834764831845f;   // 128^-0.5
#pragma unroll
        for (int p = 0; p < 4; ++p) {
            __syncthreads();
            if (wm == (p >> 1)) {
#pragma unroll
                for (int m = 0; m < 4; ++m) {
                    int mf = (p & 1) * 4 + m;
                    int rl = m * 16 + hi * 4;
#pragma unroll
                    for (int n = 0; n < 4; ++n) {
                        int cl = wn * 64 + n * 16 + fr;
#pragma unroll
                        for (int j = 0; j < 4; ++j)
                            S[(rl + j) * 256 + cl] = acc[mf][n][j];
                    }
                }
            }
            __syncthreads();
            int r = tid >> 3;
            int dbase = (tid & 7) * 8;
            int row_g = row0 + p * 64 + r;
            int l = row_g & 255;
#pragma unroll
            for (int i = 0; i < 8; ++i) {
                int d = dbase + i;
                float sn = pe[l * 128 + d], cs = pe[l * 128 + 64 + d];
                float q1 = S[r * 256 + d],       q2 = S[r * 256 + d + 64];
                float k1 = S[r * 256 + d + 128], k2 = S[r * 256 + d + 192];
                qh[(size_t)row_g * 128 + d]      = f2b((q1 * cs - q2 * sn) * qscale);
                qh[(size_t)row_g * 128 + d + 64] = f2b((q2 * cs + q1 * sn) * qscale);
                kh[(size_t)row_g * 128 + d]      = f2b(k1 * cs - k2 * sn);
                kh[(size_t)row_g * 128 + d + 64] = f2b(k2 * cs + k1 * sn);
            }
        }
        return;
    }

#pragma unroll
    for (int mf = 0; mf < 8; ++mf) {
        int row = row0 + wm * 128 + mf * 16 + hi * 4;   // multiple of 4
#pragma unroll
        for (int nf = 0; nf < 4; ++nf) {
            int gc = col0 + wn * 64 + nf * 16 + fr;
            ushort4 pk;
            pk.x = f2b(silu(acc[mf][nf][0]));
            pk.y = f2b(silu(acc[mf][nf][1]));
            pk.z = f2b(silu(acc[mf][nf][2]));
            pk.w = f2b(silu(acc[mf][nf][3]));
            if (bx < 6) {
                *(ushort4*)(uT + (size_t)gc * Mrows + row) = pk;
            } else {
                int e = gc - Edim;
                int b = row >> 8, l = row & 255;
                *(ushort4*)(vT + ((size_t)b * Edim + e) * Ltok + l) = pk;
            }
        }
    }
}

// ================= fused attention: softmax(q̂k̂ᵀ) @ V ⊙ u -> o_bf =================
__launch_bounds__(256)
__global__ void fused_attn(const unsigned short* __restrict__ qh,
                           const unsigned short* __restrict__ kh,
                           const unsigned short* __restrict__ vT,
                           const unsigned short* __restrict__ uT,
                           unsigned short* __restrict__ ob) {
    int ec = blockIdx.x, qt = blockIdx.y, b = blockIdx.z;
    int tid  = threadIdx.x;
    int lane = tid & 63, w = tid >> 6;
    int fr = lane & 15, hi = lane >> 4;
    int qbase = b * 256 + qt * 64 + w * 16;

    bf16x8 qf[4];
#pragma unroll
    for (int ks = 0; ks < 4; ++ks)
        qf[ks] = *(const bf16x8*)(qh + (size_t)(qbase + fr) * 128 + ks * 32 + hi * 8);
    f32x4 sacc[16] = {};
#pragma unroll
    for (int mf = 0; mf < 16; ++mf) {
#pragma unroll
        for (int ks = 0; ks < 4; ++ks) {
            bf16x8 kf = *(const bf16x8*)(kh + (size_t)(b * 256 + mf * 16 + fr) * 128 + ks * 32 + hi * 8);
            sacc[mf] = __builtin_amdgcn_mfma_f32_16x16x32_bf16(kf, qf[ks], sacc[mf], 0, 0, 0);
        }
    }

    float mx = -3.4e38f;
#pragma unroll
    for (int mf = 0; mf < 16; ++mf)
#pragma unroll
        for (int j = 0; j < 4; ++j)
            mx = fmaxf(mx, sacc[mf][j]);
    mx = fmaxf(mx, __shfl_xor(mx, 16, 64));
    mx = fmaxf(mx, __shfl_xor(mx, 32, 64));
    float sum = 0.f;
#pragma unroll
    for (int mf = 0; mf < 16; ++mf)
#pragma unroll
        for (int j = 0; j < 4; ++j) {
            float e = expf(sacc[mf][j] - mx);
            sacc[mf][j] = e;
            sum += e;
        }
    sum += __shfl_xor(sum, 16, 64);
    sum += __shfl_xor(sum, 32, 64);
    float inv = 1.0f / sum;

    unsigned int dw[16][2];
#pragma unroll
    for (int mf = 0; mf < 16; ++mf) {
        dw[mf][0] = pk2(sacc[mf][0] * inv, sacc[mf][1] * inv);
        dw[mf][1] = pk2(sacc[mf][2] * inv, sacc[mf][3] * inv);
    }

    int sA = fr + 32 * (hi & 1);
    int sB = sA + 16;
    bool up = (hi >> 1) != 0;
    unsigned int pa[8][4];
#pragma unroll
    for (int ks = 0; ks < 8; ++ks) {
        unsigned int a00 = __shfl((int)dw[2 * ks][0],     sA, 64);
        unsigned int a01 = __shfl((int)dw[2 * ks + 1][0], sA, 64);
        unsigned int a10 = __shfl((int)dw[2 * ks][1],     sA, 64);
        unsigned int a11 = __shfl((int)dw[2 * ks + 1][1], sA, 64);
        unsigned int b00 = __shfl((int)dw[2 * ks][0],     sB, 64);
        unsigned int b01 = __shfl((int)dw[2 * ks + 1][0], sB, 64);
        unsigned int b10 = __shfl((int)dw[2 * ks][1],     sB, 64);
        unsigned int b11 = __shfl((int)dw[2 * ks + 1][1], sB, 64);
        pa[ks][0] = up ? a01 : a00;
        pa[ks][1] = up ? a11 : a10;
        pa[ks][2] = up ? b01 : b00;
        pa[ks][3] = up ? b11 : b10;
    }

    const unsigned short* vb = vT + (size_t)b * Edim * Ltok;
    int e0 = ec * 192;
#pragma unroll 2
    for (int ef = 0; ef < 12; ++ef) {
        int e = e0 + ef * 16 + fr;
        f32x4 oacc = {};
#pragma unroll
        for (int ks = 0; ks < 8; ++ks) {
            bf16x8 vf = *(const bf16x8*)(vb + (size_t)e * Ltok + ks * 32 + hi * 8);
            oacc = __builtin_amdgcn_mfma_f32_16x16x32_bf16(*(const bf16x8*)&pa[ks], vf, oacc, 0, 0, 0);
        }
        ushort4 uv = *(const ushort4*)(uT + (size_t)e * Mrows + qbase + hi * 4);
        ob[(size_t)(qbase + hi * 4 + 0) * Edim + e] = f2b(oacc[0] * b2f(uv.x));
        ob[(size_t)(qbase + hi * 4 + 1) * Edim + e] = f2b(oacc[1] * b2f(uv.y));
        ob[(size_t)(qbase + hi * 4 + 2) * Edim + e] = f2b(oacc[2] * b2f(uv.z));
        ob[(size_t)(qbase + hi * 4 + 3) * Edim + e] = f2b(oacc[3] * b2f(uv.w));
    }
}

// ---------------- h += t_emb[t_idx[b]] ----------------
__global__ void bias_kernel(float* __restrict__ h, const float* __restrict__ t_emb,
                            const int* __restrict__ t_idx) {
    int r = blockIdx.x;
    int b = r >> 8;
    const float* e = t_emb + (size_t)t_idx[b] * Hdim;
    float* hr = h + (size_t)r * Hdim;
    for (int i = threadIdx.x; i < Hdim; i += 256) hr[i] += e[i];
}

// ------ rmsnorm (4 rows/block, wave reduce); ADD=1: h = h + p0 + p1 first ----
template <int ADD>
__global__ void rmsnorm_kernel(float* __restrict__ x, const float* __restrict__ p,
                               const float* __restrict__ w, unsigned short* __restrict__ y) {
    int r = blockIdx.x * 4 + (threadIdx.x >> 6);
    int lane = threadIdx.x & 63;
    float* xr = x + (size_t)r * Hdim;
    float4 a = *(const float4*)&xr[lane * 4];
    float4 b = *(const float4*)&xr[lane * 4 + 256];
    float4 c = *(const float4*)&xr[lane * 4 + 512];
    if (ADD) {
        const float* p0 = p + (size_t)r * Hdim;
        const float* p1 = p + (size_t)(Mrows + r) * Hdim;
        float4 a0 = *(const float4*)&p0[lane * 4];
        float4 b0 = *(const float4*)&p0[lane * 4 + 256];
        float4 c0 = *(const float4*)&p0[lane * 4 + 512];
        float4 a1 = *(const float4*)&p1[lane * 4];
        float4 b1 = *(const float4*)&p1[lane * 4 + 256];
        float4 c1 = *(const float4*)&p1[lane * 4 + 512];
        a.x += a0.x + a1.x; a.y += a0.y + a1.y; a.z += a0.z + a1.z; a.w += a0.w + a1.w;
        b.x += b0.x + b1.x; b.y += b0.y + b1.y; b.z += b0.z + b1.z; b.w += b0.w + b1.w;
        c.x += c0.x + c1.x; c.y += c0.y + c1.y; c.z += c0.z + c1.z; c.w += c0.w + c1.w;
        *(float4*)&xr[lane * 4]       = a;
        *(float4*)&xr[lane * 4 + 256] = b;
        *(float4*)&xr[lane * 4 + 512] = c;
    }
    float ss = a.x * a.x + a.y * a.y + a.z * a.z + a.w * a.w
             + b.x * b.x + b.y * b.y + b.z * b.z + b.w * b.w
             + c.x * c.x + c.y * c.y + c.z * c.z + c.w * c.w;
#pragma unroll
    for (int o = 1; o < 64; o <<= 1) ss += __shfl_xor(ss, o, 64);
    float s = 1.0f / (sqrtf(ss / (float)Hdim) + 1e-6f);
    float4 wa = *(const float4*)&w[lane * 4];
    float4 wb = *(const float4*)&w[lane * 4 + 256];
    float4 wc = *(const float4*)&w[lane * 4 + 512];
    unsigned short* yr = y + (size_t)r * Hdim;
    ushort4 o0, o1, o2;
    o0.x = f2b(a.x * s * wa.x); o0.y = f2b(a.y * s * wa.y);
    o0.z = f2b(a.z * s * wa.z); o0.w = f2b(a.w * s * wa.w);
    o1.x = f2b(b.x * s * wb.x); o1.y = f2b(b.y * s * wb.y);
    o1.z = f2b(b.z * s * wb.z); o1.w = f2b(b.w * s * wb.w);
    o2.x = f2b(c.x * s * wc.x); o2.y = f2b(c.y * s * wc.y);
    o2.z = f2b(c.z * s * wc.z); o2.w = f2b(c.w * s * wc.w);
    *(ushort4*)&yr[lane * 4]       = o0;
    *(ushort4*)&yr[lane * 4 + 256] = o1;
    *(ushort4*)&yr[lane * 4 + 512] = o2;
}

// ---------------- unpatchify ----------------
__global__ void unpatch_kernel(const float* __restrict__ y, float* __restrict__ out) {
    int bc = blockIdx.x;
    int iy = bc & 127;
    int t  = bc >> 7;
    int c  = t % 3;
    int b  = t / 3;
    int ix = threadIdx.x;
    int gy = iy >> 3, py = iy & 7, gx = ix >> 3, px = ix & 7;
    out[((size_t)(b * 3 + c) * IMG + iy) * IMG + ix] =
        y[(size_t)(b * Ltok + gy * 16 + gx) * PDim + (py * 8 + px) * 3 + c];
}

extern "C" void kernel_launch(void* const* d_in, const int* in_sizes, int n_in,
                              void* d_out, int out_size, void* d_ws, size_t ws_size,
                              hipStream_t stream) {
    const float* x        = (const float*)d_in[0];
    const int*   t_idx    = (const int*)  d_in[1];
    const float* patch_W  = (const float*)d_in[2];
    const float* t_emb    = (const float*)d_in[3];
    const float* Wuv      = (const float*)d_in[4];
    const float* Wout     = (const float*)d_in[5];
    const float* gnorm    = (const float*)d_in[6];
    const float* fnorm    = (const float*)d_in[7];
    const float* unpatchW = (const float*)d_in[8];
    float* out = (float*)d_out;

    // ---- workspace layout ----
    char* wsb = (char*)d_ws;
    size_t off = 0;
    auto alloc = [&](size_t bytes) { char* p = wsb + off; off += (bytes + 255) & ~(size_t)255; return p; };
    float* pe   = (float*)alloc(256 * 128 * 4);
    float* h    = (float*)alloc((size_t)Mrows * Hdim * 4);
    float* pbuf = (float*)alloc((size_t)2 * Mrows * Hdim * 4);
    float* y    = (float*)alloc((size_t)Mrows * PDim * 4);
    unsigned short* xp   = (unsigned short*)alloc((size_t)Mrows * PDim * 2);
    unsigned short* xn   = (unsigned short*)alloc((size_t)Mrows * Hdim * 2);
    unsigned short* uT   = (unsigned short*)alloc((size_t)Edim * Mrows * 2);
    unsigned short* vT   = (unsigned short*)alloc((size_t)Bsz * Edim * Ltok * 2);
    unsigned short* qh   = (unsigned short*)alloc((size_t)Mrows * 128 * 2);
    unsigned short* kh   = (unsigned short*)alloc((size_t)Mrows * 128 * 2);
    unsigned short* o_bf = (unsigned short*)alloc((size_t)Mrows * Edim * 2);
    unsigned short* WuvT  = (unsigned short*)alloc((size_t)NLAY * UVW * Hdim * 2);
    unsigned short* WoutT = (unsigned short*)alloc((size_t)NLAY * Hdim * Edim * 2);
    unsigned short* patchWT   = (unsigned short*)alloc((size_t)Hdim * PDim * 2);
    unsigned short* unpatchWT = (unsigned short*)alloc((size_t)PDim * Hdim * 2);
    if (off > ws_size) return;   // distinct failure signature (out stays 0)

    pe_kernel<<<256, 128, 0, stream>>>(pe);
    patchify_kernel<<<Bsz * 3 * IMG, IMG, 0, stream>>>(x, xp);

    // weight transposes upfront (batched over layers)
    trans_kernel<<<dim3(Hdim / 32, PDim / 32, 1), dim3(32, 8), 0, stream>>>(
        patch_W, Hdim, 0, patchWT, PDim, 0);
    trans_kernel<<<dim3(PDim / 32, Hdim / 32, 1), dim3(32, 8), 0, stream>>>(
        unpatchW, PDim, 0, unpatchWT, Hdim, 0);
    trans_kernel<<<dim3(UVW / 32, Hdim / 32, NLAY), dim3(32, 8), 0, stream>>>(
        Wuv, UVW, (long long)Hdim * UVW, WuvT, Hdim, (long long)UVW * Hdim);
    trans_kernel<<<dim3(Hdim / 32, Edim / 32, NLAY), dim3(32, 8), 0, stream>>>(
        Wout, Hdim, (long long)Edim * Hdim, WoutT, Edim, (long long)Hdim * Edim);

    gemm_bf16<0><<<(Hdim / 128) * (Mrows / 128), 256, 0, stream>>>(
        xp, PDim, patchWT, PDim, h, Hdim, PDim, Hdim, Hdim / 128);
    bias_kernel<<<Mrows, 256, 0, stream>>>(h, t_emb, t_idx);

    rmsnorm_kernel<0><<<Mrows / 4, 256, 0, stream>>>(h, nullptr, gnorm, xn);
    for (int l = 0; l < NLAY; ++l) {
        gemm_uvqk8<<<13 * (Mrows / 256), 512, 0, stream>>>(
            xn, WuvT + (size_t)l * UVW * Hdim, uT, vT, qh, kh, pe);
        fused_attn<<<dim3(8, 4, Bsz), 256, 0, stream>>>(qh, kh, vT, uT, o_bf);
        gemm_wout<<<384, 256, 0, stream>>>(
            o_bf, WoutT + (size_t)l * Hdim * Edim, pbuf);
        const float* nw = (l + 1 < NLAY) ? gnorm + (size_t)(l + 1) * Hdim : fnorm;
        rmsnorm_kernel<1><<<Mrows / 4, 256, 0, stream>>>(h, pbuf, nw, xn);
    }

    gemm_bf16<0><<<2 * (Mrows / 128), 256, 0, stream>>>(
        xn, Hdim, unpatchWT, Hdim, y, PDim, Hdim, PDim, 2);
    unpatch_kernel<<<Bsz * 3 * IMG, IMG, 0, stream>>>(y, out);
}

// Round 8
// 2820.889 us; speedup vs baseline: 4.9608x; 1.0625x over previous
//
#include <hip/hip_runtime.h>
#include <math.h>

#define IMG   128
#define Hdim  768
#define Edim  1536
#define Ltok  256
#define PDim  192
#define NLAY  24
#define Bsz   16
#define Mrows 4096          // B * L
#define UVW   3328          // 2E + 2K

typedef __bf16 bf16x8 __attribute__((ext_vector_type(8)));
typedef float  f32x4  __attribute__((ext_vector_type(4)));

__device__ __forceinline__ unsigned short f2b(float f) {
    unsigned int u = __float_as_uint(f);
    unsigned int r = (u + 0x7FFF + ((u >> 16) & 1)) >> 16;
    return (unsigned short)r;
}
__device__ __forceinline__ float b2f(unsigned short s) {
    return __uint_as_float((unsigned int)s << 16);
}
__device__ __forceinline__ unsigned int pk2(float lo, float hi) {
    return (unsigned int)f2b(lo) | ((unsigned int)f2b(hi) << 16);
}
__device__ __forceinline__ float silu(float x) {
    return x / (1.0f + expf(-x));
}
__device__ __forceinline__ void gload16(const void* g, void* l) {
    __builtin_amdgcn_global_load_lds(
        (const __attribute__((address_space(1))) void*)g,
        (__attribute__((address_space(3))) void*)l, 16, 0, 0);
}
// bijective XCD-chunking remap (m204)
__device__ __forceinline__ int xcd_wg() {
    int nwg = gridDim.x;
    int orig = blockIdx.x;
    int q8 = nwg >> 3, r8 = nwg & 7;
    int xcd = orig & 7, loc = orig >> 3;
    return (xcd < r8 ? xcd * (q8 + 1) : r8 * (q8 + 1) + (xcd - r8) * q8) + loc;
}

// ---------------- RoPE table ----------------
__global__ void pe_kernel(float* __restrict__ pe) {
    int l = blockIdx.x;
    int j = threadIdx.x;
    const float c = -logf(1000.0f) / 31.0f;
    int   sub = j & 31;
    float f   = expf(c * (float)sub);
    float pos = (j < 64) ? (float)(l >> 4) : (float)(l & 15);
    float ang = pos * f;
    pe[l * 128 + j] = ((j & 32) == 0) ? sinf(ang) : cosf(ang);
}

// ---------------- patchify -> bf16 ----------------
__global__ void patchify_kernel(const float* __restrict__ x, unsigned short* __restrict__ xp) {
    int bc = blockIdx.x;
    int iy = bc & 127;
    int t  = bc >> 7;
    int c  = t % 3;
    int b  = t / 3;
    int ix = threadIdx.x;
    float v = x[((size_t)(b * 3 + c) * IMG + iy) * IMG + ix];
    int gy = iy >> 3, py = iy & 7, gx = ix >> 3, px = ix & 7;
    xp[(size_t)(b * Ltok + gy * 16 + gx) * PDim + (py * 8 + px) * 3 + c] = f2b(v);
}

// ---------------- fp32 [R][C] -> bf16 transposed [C][R] ----------------
__global__ void trans_kernel(const float* __restrict__ src, int ldS, long long sS,
                             unsigned short* __restrict__ dst, int ldD, long long sD) {
    src += (long long)blockIdx.z * sS;
    dst += (long long)blockIdx.z * sD;
    __shared__ float t[32][33];
    int c0 = blockIdx.x * 32, r0 = blockIdx.y * 32;
    int tx = threadIdx.x, ty = threadIdx.y;   // (32,8)
#pragma unroll
    for (int i = 0; i < 4; ++i)
        t[ty + 8 * i][tx] = src[(size_t)(r0 + ty + 8 * i) * ldS + c0 + tx];
    __syncthreads();
#pragma unroll
    for (int i = 0; i < 4; ++i)
        dst[(size_t)(c0 + ty + 8 * i) * ldD + r0 + tx] = f2b(t[tx][ty + 8 * i]);
}

// ================= generic bf16 MFMA GEMM, double-buffered, XCD-swizzled ====
template <int ACC>
__launch_bounds__(256)
__global__ void gemm_bf16(const unsigned short* __restrict__ A, int lda,
                          const unsigned short* __restrict__ Bt, int ldb,
                          float* __restrict__ C, int ldc,
                          int Kt, int Nt, int nbx) {
    __shared__ unsigned short lsA[2][4096];
    __shared__ unsigned short lsB[2][4096];
    int wg = xcd_wg();
    int bx = wg % nbx, by = wg / nbx;
    int tid  = threadIdx.x;
    int lane = tid & 63, w = tid >> 6, wr = w >> 1, wc = w & 1;
    int row0 = by * 128, col0 = bx * 128;
    int fr = lane & 15, fk = (lane >> 4) * 8;
    f32x4 acc[4][4] = {};

    int c0 = tid, c1 = tid + 256;
    int ar0 = row0 + (c0 >> 2), ar1 = row0 + (c1 >> 2);
    int bn0 = col0 + (c0 >> 2), bn1 = col0 + (c1 >> 2);
    if (bn0 > Nt - 1) bn0 = Nt - 1;
    if (bn1 > Nt - 1) bn1 = Nt - 1;
    int ka0 = (c0 & 3) * 8, ka1 = (c1 & 3) * 8;

#define STAGE_G(buf, k0)                                                       \
    gload16(A  + (size_t)ar0 * lda + (k0) + ka0, &lsA[buf][c0 * 8]);           \
    gload16(A  + (size_t)ar1 * lda + (k0) + ka1, &lsA[buf][c1 * 8]);           \
    gload16(Bt + (size_t)bn0 * ldb + (k0) + ka0, &lsB[buf][c0 * 8]);           \
    gload16(Bt + (size_t)bn1 * ldb + (k0) + ka1, &lsB[buf][c1 * 8]);

    STAGE_G(0, 0);
    __syncthreads();
    int nt = Kt >> 5, cur = 0;
    for (int t = 0; t < nt; ++t) {
        if (t + 1 < nt) { STAGE_G(cur ^ 1, (t + 1) * 32); }
        bf16x8 af[4], bfr[4];
#pragma unroll
        for (int m = 0; m < 4; ++m)
            af[m] = *(const bf16x8*)(&lsA[cur][(wr * 64 + m * 16 + fr) * 32 + fk]);
#pragma unroll
        for (int n = 0; n < 4; ++n)
            bfr[n] = *(const bf16x8*)(&lsB[cur][(wc * 64 + n * 16 + fr) * 32 + fk]);
#pragma unroll
        for (int m = 0; m < 4; ++m)
#pragma unroll
            for (int n = 0; n < 4; ++n)
                acc[m][n] = __builtin_amdgcn_mfma_f32_16x16x32_bf16(af[m], bfr[n], acc[m][n], 0, 0, 0);
        __syncthreads();
        cur ^= 1;
    }
#undef STAGE_G

    int crow = (lane >> 4) * 4;
#pragma unroll
    for (int m = 0; m < 4; ++m) {
#pragma unroll
        for (int n = 0; n < 4; ++n) {
            int gc = col0 + wc * 64 + n * 16 + fr;
            if (gc >= Nt) continue;
#pragma unroll
            for (int j = 0; j < 4; ++j) {
                size_t idx = (size_t)(row0 + wr * 64 + m * 16 + crow + j) * ldc + gc;
                if (ACC) C[idx] += acc[m][n][j];
                else     C[idx]  = acc[m][n][j];
            }
        }
    }
}

// ================= wout GEMM, split-K=4 in one launch ========================
// A = o_bf [4096][1536], Bt = WoutT_l [768][1536]. grid 768: sk|by|bx.
// P[sk][4096][768] fp32 partials (residual add fused into next rmsnorm).
__launch_bounds__(256)
__global__ void gemm_wout(const unsigned short* __restrict__ A,
                          const unsigned short* __restrict__ Bt,
                          float* __restrict__ P) {
    __shared__ unsigned short lsA[2][4096];
    __shared__ unsigned short lsB[2][4096];
    int wg = xcd_wg();
    int sk = wg / 192, rem = wg % 192;
    int bx = rem % 6, by = rem / 6;
    int koff = sk * 384;
    float* C = P + (size_t)sk * Mrows * Hdim;
    int tid  = threadIdx.x;
    int lane = tid & 63, w = tid >> 6, wr = w >> 1, wc = w & 1;
    int row0 = by * 128, col0 = bx * 128;
    int fr = lane & 15, fk = (lane >> 4) * 8;
    f32x4 acc[4][4] = {};

    int c0 = tid, c1 = tid + 256;
    int ar0 = row0 + (c0 >> 2), ar1 = row0 + (c1 >> 2);
    int bn0 = col0 + (c0 >> 2), bn1 = col0 + (c1 >> 2);
    int ka0 = koff + (c0 & 3) * 8, ka1 = koff + (c1 & 3) * 8;

#define STAGE_W(buf, k0)                                                       \
    gload16(A  + (size_t)ar0 * Edim + (k0) + ka0, &lsA[buf][c0 * 8]);          \
    gload16(A  + (size_t)ar1 * Edim + (k0) + ka1, &lsA[buf][c1 * 8]);          \
    gload16(Bt + (size_t)bn0 * Edim + (k0) + ka0, &lsB[buf][c0 * 8]);          \
    gload16(Bt + (size_t)bn1 * Edim + (k0) + ka1, &lsB[buf][c1 * 8]);

    STAGE_W(0, 0);
    __syncthreads();
    int cur = 0;
    for (int t = 0; t < 12; ++t) {
        if (t + 1 < 12) { STAGE_W(cur ^ 1, (t + 1) * 32); }
        bf16x8 af[4], bfr[4];
#pragma unroll
        for (int m = 0; m < 4; ++m)
            af[m] = *(const bf16x8*)(&lsA[cur][(wr * 64 + m * 16 + fr) * 32 + fk]);
#pragma unroll
        for (int n = 0; n < 4; ++n)
            bfr[n] = *(const bf16x8*)(&lsB[cur][(wc * 64 + n * 16 + fr) * 32 + fk]);
#pragma unroll
        for (int m = 0; m < 4; ++m)
#pragma unroll
            for (int n = 0; n < 4; ++n)
                acc[m][n] = __builtin_amdgcn_mfma_f32_16x16x32_bf16(af[m], bfr[n], acc[m][n], 0, 0, 0);
        __syncthreads();
        cur ^= 1;
    }
#undef STAGE_W

    int crow = (lane >> 4) * 4;
#pragma unroll
    for (int m = 0; m < 4; ++m) {
#pragma unroll
        for (int n = 0; n < 4; ++n) {
            int gc = col0 + wc * 64 + n * 16 + fr;
#pragma unroll
            for (int j = 0; j < 4; ++j)
                C[(size_t)(row0 + wr * 64 + m * 16 + crow + j) * Hdim + gc] = acc[m][n][j];
        }
    }
}

// ================= uvqk GEMM: 256x256 tile, 8-phase counted-vmcnt pipeline ===
// A = xn [4096][768], Bt = WuvT_l [3328][768]. Grid 208 = 13 bx * 16 by, 512 thr.
// BK=64, 2-K-tile double buffer, T2 XOR-swizzle, T5 setprio.
// col-tiles 0-5: silu->uT; 6-11: silu->vT; 12: rope->qh/kh.
// Epilogue: LDS-transposed coalesced stores (512B-contiguous per e-row).
__global__ __launch_bounds__(512, 2)
void gemm_uvqk8(const unsigned short* __restrict__ A,
                const unsigned short* __restrict__ Bt,
                unsigned short* __restrict__ uT,
                unsigned short* __restrict__ vT,
                unsigned short* __restrict__ qh,
                unsigned short* __restrict__ kh,
                const float* __restrict__ pe) {
    __shared__ char smem[131072];   // 2 bufs * (A 2x16KB + B 2x16KB)
    int wg = xcd_wg();
    int bx = wg % 13, by = wg / 13;
    int tid = threadIdx.x, lane = tid & 63, wid = tid >> 6;
    int wm = wid >> 2, wn = wid & 3;            // 2 x 4 wave grid
    int row0 = by * 256, col0 = bx * 256;
    int fr = lane & 15, hi = lane >> 4;
    f32x4 acc[8][4] = {};

    // ---- staging: linear LDS dest, pre-swizzled global source ----
    int d0 = tid * 16, d1 = d0 + 8192;
    int s0 = d0 ^ (((d0 >> 7) & 7) << 4);
    int s1 = d1 ^ (((d1 >> 7) & 7) << 4);
    int sr0 = s0 >> 7, sc0 = (s0 & 127) >> 1;
    int sr1 = s1 >> 7, sc1 = (s1 & 127) >> 1;

#define STG_A(bufo, h, kt) do {                                                            \
    gload16(A + (size_t)(row0 + (h) * 128 + sr0) * Hdim + (kt) * 64 + sc0,                 \
            smem + (bufo) + (h) * 16384 + d0);                                             \
    gload16(A + (size_t)(row0 + (h) * 128 + sr1) * Hdim + (kt) * 64 + sc1,                 \
            smem + (bufo) + (h) * 16384 + d1); } while (0)
#define STG_B(bufo, h, kt) do {                                                            \
    gload16(Bt + (size_t)(col0 + (h) * 128 + sr0) * Hdim + (kt) * 64 + sc0,                \
            smem + (bufo) + 32768 + (h) * 16384 + d0);                                     \
    gload16(Bt + (size_t)(col0 + (h) * 128 + sr1) * Hdim + (kt) * 64 + sc1,                \
            smem + (bufo) + 32768 + (h) * 16384 + d1); } while (0)

    // ---- ds_read fragment addressing (swizzled) ----
    int axor = (fr & 7) << 4;
    int abase = wm * 16384 + fr * 128;
    int bbase = 32768 + (wn >> 1) * 16384 + ((wn & 1) * 64 + fr) * 128;
    int koff0 = (hi * 16) ^ axor;
    int koff1 = (hi * 16 + 64) ^ axor;

    // ---- prologue: kt0 (all 4 halves) + kt1 A-halves ----
    STG_A(0, 0, 0); STG_A(0, 1, 0); STG_B(0, 0, 0); STG_B(0, 1, 0);
    STG_A(65536, 0, 1); STG_A(65536, 1, 1);
    asm volatile("s_waitcnt vmcnt(4)" ::: "memory");
    __builtin_amdgcn_s_barrier();
    __builtin_amdgcn_sched_barrier(0);

    bf16x8 af[4][2], bf0[2][2], bf1[2][2];
    const int NKT = Hdim / 64;   // 12
    for (int kt = 0; kt < NKT; ++kt) {
        int curo = (kt & 1) << 16, nxto = curo ^ 65536;
        const char* bufc = smem + curo;

        // ---- phase 0: (mh0, nh0) ----
#pragma unroll
        for (int m = 0; m < 4; ++m) {
            af[m][0] = *(const bf16x8*)(bufc + abase + m * 2048 + koff0);
            af[m][1] = *(const bf16x8*)(bufc + abase + m * 2048 + koff1);
        }
#pragma unroll
        for (int n = 0; n < 2; ++n) {
            bf0[n][0] = *(const bf16x8*)(bufc + bbase + n * 2048 + koff0);
            bf0[n][1] = *(const bf16x8*)(bufc + bbase + n * 2048 + koff1);
        }
        if (kt + 1 < NKT) STG_B(nxto, 0, kt + 1);
        __builtin_amdgcn_s_setprio(1);
#pragma unroll
        for (int m = 0; m < 4; ++m)
#pragma unroll
            for (int n = 0; n < 2; ++n) {
                acc[m][n] = __builtin_amdgcn_mfma_f32_16x16x32_bf16(af[m][0], bf0[n][0], acc[m][n], 0, 0, 0);
                acc[m][n] = __builtin_amdgcn_mfma_f32_16x16x32_bf16(af[m][1], bf0[n][1], acc[m][n], 0, 0, 0);
            }
        __builtin_amdgcn_s_setprio(0);
        __builtin_amdgcn_s_barrier();
        __builtin_amdgcn_sched_barrier(0);

        // ---- phase 1: (mh0, nh1) ----
#pragma unroll
        for (int n = 0; n < 2; ++n) {
            bf1[n][0] = *(const bf16x8*)(bufc + bbase + (n + 2) * 2048 + koff0);
            bf1[n][1] = *(const bf16x8*)(bufc + bbase + (n + 2) * 2048 + koff1);
        }
        if (kt + 1 < NKT) STG_B(nxto, 1, kt + 1);
        __builtin_amdgcn_s_setprio(1);
#pragma unroll
        for (int m = 0; m < 4; ++m)
#pragma unroll
            for (int n = 0; n < 2; ++n) {
                acc[m][n + 2] = __builtin_amdgcn_mfma_f32_16x16x32_bf16(af[m][0], bf1[n][0], acc[m][n + 2], 0, 0, 0);
                acc[m][n + 2] = __builtin_amdgcn_mfma_f32_16x16x32_bf16(af[m][1], bf1[n][1], acc[m][n + 2], 0, 0, 0);
            }
        __builtin_amdgcn_s_setprio(0);
        __builtin_amdgcn_s_barrier();
        __builtin_amdgcn_sched_barrier(0);

        // ---- phase 2: (mh1, nh0) ----
#pragma unroll
        for (int m = 0; m < 4; ++m) {
            af[m][0] = *(const bf16x8*)(bufc + abase + (m + 4) * 2048 + koff0);
            af[m][1] = *(const bf16x8*)(bufc + abase + (m + 4) * 2048 + koff1);
        }
        __builtin_amdgcn_s_setprio(1);
#pragma unroll
        for (int m = 0; m < 4; ++m)
#pragma unroll
            for (int n = 0; n < 2; ++n) {
                acc[m + 4][n] = __builtin_amdgcn_mfma_f32_16x16x32_bf16(af[m][0], bf0[n][0], acc[m + 4][n], 0, 0, 0);
                acc[m + 4][n] = __builtin_amdgcn_mfma_f32_16x16x32_bf16(af[m][1], bf0[n][1], acc[m + 4][n], 0, 0, 0);
            }
        __builtin_amdgcn_s_setprio(0);
        __builtin_amdgcn_s_barrier();
        __builtin_amdgcn_sched_barrier(0);

        // ---- phase 3: (mh1, nh1) ----
        if (kt + 2 < NKT) { STG_A(curo, 0, kt + 2); STG_A(curo, 1, kt + 2); }
        __builtin_amdgcn_s_setprio(1);
#pragma unroll
        for (int m = 0; m < 4; ++m)
#pragma unroll
            for (int n = 0; n < 2; ++n) {
                acc[m + 4][n + 2] = __builtin_amdgcn_mfma_f32_16x16x32_bf16(af[m][0], bf1[n][0], acc[m + 4][n + 2], 0, 0, 0);
                acc[m + 4][n + 2] = __builtin_amdgcn_mfma_f32_16x16x32_bf16(af[m][1], bf1[n][1], acc[m + 4][n + 2], 0, 0, 0);
            }
        __builtin_amdgcn_s_setprio(0);
        asm volatile("s_waitcnt vmcnt(4)" ::: "memory");
        __builtin_amdgcn_s_barrier();
        __builtin_amdgcn_sched_barrier(0);
    }
#undef STG_A
#undef STG_B

    // ================= epilogue =================
    if (bx == 12) {
        // rope: 4 passes of 64 rows through LDS (fp32), q cols 0-127, k 128-255
        float* S = (float*)smem;
        const float qscale = 0.08838834764831845f;   // 128^-0.5
#pragma unroll
        for (int p = 0; p < 4; ++p) {
            __syncthreads();
            if (wm == (p >> 1)) {
#pragma unroll
                for (int m = 0; m < 4; ++m) {
                    int mf = (p & 1) * 4 + m;
                    int rl = m * 16 + hi * 4;
#pragma unroll
                    for (int n = 0; n < 4; ++n) {
                        int cl = wn * 64 + n * 16 + fr;
#pragma unroll
                        for (int j = 0; j < 4; ++j)
                            S[(rl + j) * 256 + cl] = acc[mf][n][j];
                    }
                }
            }
            __syncthreads();
            int r = tid >> 3;
            int dbase = (tid & 7) * 8;
            int row_g = row0 + p * 64 + r;
            int l = row_g & 255;
#pragma unroll
            for (int i = 0; i < 8; ++i) {
                int d = dbase + i;
                float sn = pe[l * 128 + d], cs = pe[l * 128 + 64 + d];
                float q1 = S[r * 256 + d],       q2 = S[r * 256 + d + 64];
                float k1 = S[r * 256 + d + 128], k2 = S[r * 256 + d + 192];
                qh[(size_t)row_g * 128 + d]      = f2b((q1 * cs - q2 * sn) * qscale);
                qh[(size_t)row_g * 128 + d + 64] = f2b((q2 * cs + q1 * sn) * qscale);
                kh[(size_t)row_g * 128 + d]      = f2b(k1 * cs - k2 * sn);
                kh[(size_t)row_g * 128 + d + 64] = f2b(k2 * cs + k1 * sn);
            }
        }
        return;
    }

    // ---- silu tiles: stage bf16 [e_local][m_local] in LDS (swizzled), ----
    // ---- then write 512B-contiguous rows (uT[e][m] / vT[b][e][l]).     ----
    __syncthreads();
#pragma unroll
    for (int mf = 0; mf < 8; ++mf) {
        int m_l = wm * 128 + mf * 16 + hi * 4;
#pragma unroll
        for (int nf = 0; nf < 4; ++nf) {
            int e_l = wn * 64 + nf * 16 + fr;
            ushort4 pk;
            pk.x = f2b(silu(acc[mf][nf][0]));
            pk.y = f2b(silu(acc[mf][nf][1]));
            pk.z = f2b(silu(acc[mf][nf][2]));
            pk.w = f2b(silu(acc[mf][nf][3]));
            int byte = (e_l * 512 + m_l * 2) ^ ((e_l & 7) << 4);
            *(ushort4*)(smem + byte) = pk;
        }
    }
    __syncthreads();
    int er = tid >> 5;                 // 0..15
    int ch = (tid & 31) * 16;          // byte chunk within 512B row
#pragma unroll
    for (int it = 0; it < 16; ++it) {
        int e_l = it * 16 + er;
        int byte = (e_l * 512 + ch) ^ ((e_l & 7) << 4);
        int4 v = *(const int4*)(smem + byte);
        unsigned short* dst;
        if (bx < 6) {
            dst = uT + (size_t)(col0 + e_l) * Mrows + row0;
        } else {
            int e = col0 + e_l - Edim;
            dst = vT + ((size_t)(row0 >> 8) * Edim + e) * Ltok;
        }
        *(int4*)((char*)dst + ch) = v;
    }
}

// ================= fused attention: softmax(q̂k̂ᵀ) @ V ⊙ u -> o_bf =================
__launch_bounds__(256)
__global__ void fused_attn(const unsigned short* __restrict__ qh,
                           const unsigned short* __restrict__ kh,
                           const unsigned short* __restrict__ vT,
                           const unsigned short* __restrict__ uT,
                           unsigned short* __restrict__ ob) {
    int ec = blockIdx.x, qt = blockIdx.y, b = blockIdx.z;
    int tid  = threadIdx.x;
    int lane = tid & 63, w = tid >> 6;
    int fr = lane & 15, hi = lane >> 4;
    int qbase = b * 256 + qt * 64 + w * 16;

    bf16x8 qf[4];
#pragma unroll
    for (int ks = 0; ks < 4; ++ks)
        qf[ks] = *(const bf16x8*)(qh + (size_t)(qbase + fr) * 128 + ks * 32 + hi * 8);
    f32x4 sacc[16] = {};
#pragma unroll
    for (int mf = 0; mf < 16; ++mf) {
#pragma unroll
        for (int ks = 0; ks < 4; ++ks) {
            bf16x8 kf = *(const bf16x8*)(kh + (size_t)(b * 256 + mf * 16 + fr) * 128 + ks * 32 + hi * 8);
            sacc[mf] = __builtin_amdgcn_mfma_f32_16x16x32_bf16(kf, qf[ks], sacc[mf], 0, 0, 0);
        }
    }

    float mx = -3.4e38f;
#pragma unroll
    for (int mf = 0; mf < 16; ++mf)
#pragma unroll
        for (int j = 0; j < 4; ++j)
            mx = fmaxf(mx, sacc[mf][j]);
    mx = fmaxf(mx, __shfl_xor(mx, 16, 64));
    mx = fmaxf(mx, __shfl_xor(mx, 32, 64));
    float sum = 0.f;
#pragma unroll
    for (int mf = 0; mf < 16; ++mf)
#pragma unroll
        for (int j = 0; j < 4; ++j) {
            float e = expf(sacc[mf][j] - mx);
            sacc[mf][j] = e;
            sum += e;
        }
    sum += __shfl_xor(sum, 16, 64);
    sum += __shfl_xor(sum, 32, 64);
    float inv = 1.0f / sum;

    unsigned int dw[16][2];
#pragma unroll
    for (int mf = 0; mf < 16; ++mf) {
        dw[mf][0] = pk2(sacc[mf][0] * inv, sacc[mf][1] * inv);
        dw[mf][1] = pk2(sacc[mf][2] * inv, sacc[mf][3] * inv);
    }

    int sA = fr + 32 * (hi & 1);
    int sB = sA + 16;
    bool up = (hi >> 1) != 0;
    unsigned int pa[8][4];
#pragma unroll
    for (int ks = 0; ks < 8; ++ks) {
        unsigned int a00 = __shfl((int)dw[2 * ks][0],     sA, 64);
        unsigned int a01 = __shfl((int)dw[2 * ks + 1][0], sA, 64);
        unsigned int a10 = __shfl((int)dw[2 * ks][1],     sA, 64);
        unsigned int a11 = __shfl((int)dw[2 * ks + 1][1], sA, 64);
        unsigned int b00 = __shfl((int)dw[2 * ks][0],     sB, 64);
        unsigned int b01 = __shfl((int)dw[2 * ks + 1][0], sB, 64);
        unsigned int b10 = __shfl((int)dw[2 * ks][1],     sB, 64);
        unsigned int b11 = __shfl((int)dw[2 * ks + 1][1], sB, 64);
        pa[ks][0] = up ? a01 : a00;
        pa[ks][1] = up ? a11 : a10;
        pa[ks][2] = up ? b01 : b00;
        pa[ks][3] = up ? b11 : b10;
    }

    const unsigned short* vb = vT + (size_t)b * Edim * Ltok;
    int e0 = ec * 192;
#pragma unroll 2
    for (int ef = 0; ef < 12; ++ef) {
        int e = e0 + ef * 16 + fr;
        f32x4 oacc = {};
#pragma unroll
        for (int ks = 0; ks < 8; ++ks) {
            bf16x8 vf = *(const bf16x8*)(vb + (size_t)e * Ltok + ks * 32 + hi * 8);
            oacc = __builtin_amdgcn_mfma_f32_16x16x32_bf16(*(const bf16x8*)&pa[ks], vf, oacc, 0, 0, 0);
        }
        ushort4 uv = *(const ushort4*)(uT + (size_t)e * Mrows + qbase + hi * 4);
        ob[(size_t)(qbase + hi * 4 + 0) * Edim + e] = f2b(oacc[0] * b2f(uv.x));
        ob[(size_t)(qbase + hi * 4 + 1) * Edim + e] = f2b(oacc[1] * b2f(uv.y));
        ob[(size_t)(qbase + hi * 4 + 2) * Edim + e] = f2b(oacc[2] * b2f(uv.z));
        ob[(size_t)(qbase + hi * 4 + 3) * Edim + e] = f2b(oacc[3] * b2f(uv.w));
    }
}

// ---------------- h += t_emb[t_idx[b]] ----------------
__global__ void bias_kernel(float* __restrict__ h, const float* __restrict__ t_emb,
                            const int* __restrict__ t_idx) {
    int r = blockIdx.x;
    int b = r >> 8;
    const float* e = t_emb + (size_t)t_idx[b] * Hdim;
    float* hr = h + (size_t)r * Hdim;
    for (int i = threadIdx.x; i < Hdim; i += 256) hr[i] += e[i];
}

// ------ rmsnorm (4 rows/block, wave reduce); ADD=1: h += p0..p3 first --------
template <int ADD>
__global__ void rmsnorm_kernel(float* __restrict__ x, const float* __restrict__ p,
                               const float* __restrict__ w, unsigned short* __restrict__ y) {
    int r = blockIdx.x * 4 + (threadIdx.x >> 6);
    int lane = threadIdx.x & 63;
    float* xr = x + (size_t)r * Hdim;
    float4 a = *(const float4*)&xr[lane * 4];
    float4 b = *(const float4*)&xr[lane * 4 + 256];
    float4 c = *(const float4*)&xr[lane * 4 + 512];
    if (ADD) {
#pragma unroll
        for (int s = 0; s < 4; ++s) {
            const float* ps = p + (size_t)(s * Mrows + r) * Hdim;
            float4 a0 = *(const float4*)&ps[lane * 4];
            float4 b0 = *(const float4*)&ps[lane * 4 + 256];
            float4 c0 = *(const float4*)&ps[lane * 4 + 512];
            a.x += a0.x; a.y += a0.y; a.z += a0.z; a.w += a0.w;
            b.x += b0.x; b.y += b0.y; b.z += b0.z; b.w += b0.w;
            c.x += c0.x; c.y += c0.y; c.z += c0.z; c.w += c0.w;
        }
        *(float4*)&xr[lane * 4]       = a;
        *(float4*)&xr[lane * 4 + 256] = b;
        *(float4*)&xr[lane * 4 + 512] = c;
    }
    float ss = a.x * a.x + a.y * a.y + a.z * a.z + a.w * a.w
             + b.x * b.x + b.y * b.y + b.z * b.z + b.w * b.w
             + c.x * c.x + c.y * c.y + c.z * c.z + c.w * c.w;
#pragma unroll
    for (int o = 1; o < 64; o <<= 1) ss += __shfl_xor(ss, o, 64);
    float s = 1.0f / (sqrtf(ss / (float)Hdim) + 1e-6f);
    float4 wa = *(const float4*)&w[lane * 4];
    float4 wb = *(const float4*)&w[lane * 4 + 256];
    float4 wc = *(const float4*)&w[lane * 4 + 512];
    unsigned short* yr = y + (size_t)r * Hdim;
    ushort4 o0, o1, o2;
    o0.x = f2b(a.x * s * wa.x); o0.y = f2b(a.y * s * wa.y);
    o0.z = f2b(a.z * s * wa.z); o0.w = f2b(a.w * s * wa.w);
    o1.x = f2b(b.x * s * wb.x); o1.y = f2b(b.y * s * wb.y);
    o1.z = f2b(b.z * s * wb.z); o1.w = f2b(b.w * s * wb.w);
    o2.x = f2b(c.x * s * wc.x); o2.y = f2b(c.y * s * wc.y);
    o2.z = f2b(c.z * s * wc.z); o2.w = f2b(c.w * s * wc.w);
    *(ushort4*)&yr[lane * 4]       = o0;
    *(ushort4*)&yr[lane * 4 + 256] = o1;
    *(ushort4*)&yr[lane * 4 + 512] = o2;
}

// ---------------- unpatchify ----------------
__global__ void unpatch_kernel(const float* __restrict__ y, float* __restrict__ out) {
    int bc = blockIdx.x;
    int iy = bc & 127;
    int t  = bc >> 7;
    int c  = t % 3;
    int b  = t / 3;
    int ix = threadIdx.x;
    int gy = iy >> 3, py = iy & 7, gx = ix >> 3, px = ix & 7;
    out[((size_t)(b * 3 + c) * IMG + iy) * IMG + ix] =
        y[(size_t)(b * Ltok + gy * 16 + gx) * PDim + (py * 8 + px) * 3 + c];
}

extern "C" void kernel_launch(void* const* d_in, const int* in_sizes, int n_in,
                              void* d_out, int out_size, void* d_ws, size_t ws_size,
                              hipStream_t stream) {
    const float* x        = (const float*)d_in[0];
    const int*   t_idx    = (const int*)  d_in[1];
    const float* patch_W  = (const float*)d_in[2];
    const float* t_emb    = (const float*)d_in[3];
    const float* Wuv      = (const float*)d_in[4];
    const float* Wout     = (const float*)d_in[5];
    const float* gnorm    = (const float*)d_in[6];
    const float* fnorm    = (const float*)d_in[7];
    const float* unpatchW = (const float*)d_in[8];
    float* out = (float*)d_out;

    // ---- workspace layout ----
    char* wsb = (char*)d_ws;
    size_t off = 0;
    auto alloc = [&](size_t bytes) { char* p = wsb + off; off += (bytes + 255) & ~(size_t)255; return p; };
    float* pe   = (float*)alloc(256 * 128 * 4);
    float* h    = (float*)alloc((size_t)Mrows * Hdim * 4);
    float* pbuf = (float*)alloc((size_t)4 * Mrows * Hdim * 4);
    float* y    = (float*)alloc((size_t)Mrows * PDim * 4);
    unsigned short* xp   = (unsigned short*)alloc((size_t)Mrows * PDim * 2);
    unsigned short* xn   = (unsigned short*)alloc((size_t)Mrows * Hdim * 2);
    unsigned short* uT   = (unsigned short*)alloc((size_t)Edim * Mrows * 2);
    unsigned short* vT   = (unsigned short*)alloc((size_t)Bsz * Edim * Ltok * 2);
    unsigned short* qh   = (unsigned short*)alloc((size_t)Mrows * 128 * 2);
    unsigned short* kh   = (unsigned short*)alloc((size_t)Mrows * 128 * 2);
    unsigned short* o_bf = (unsigned short*)alloc((size_t)Mrows * Edim * 2);
    unsigned short* WuvT  = (unsigned short*)alloc((size_t)NLAY * UVW * Hdim * 2);
    unsigned short* WoutT = (unsigned short*)alloc((size_t)NLAY * Hdim * Edim * 2);
    unsigned short* patchWT   = (unsigned short*)alloc((size_t)Hdim * PDim * 2);
    unsigned short* unpatchWT = (unsigned short*)alloc((size_t)PDim * Hdim * 2);
    if (off > ws_size) return;   // distinct failure signature (out stays 0)

    pe_kernel<<<256, 128, 0, stream>>>(pe);
    patchify_kernel<<<Bsz * 3 * IMG, IMG, 0, stream>>>(x, xp);

    // weight transposes upfront (batched over layers)
    trans_kernel<<<dim3(Hdim / 32, PDim / 32, 1), dim3(32, 8), 0, stream>>>(
        patch_W, Hdim, 0, patchWT, PDim, 0);
    trans_kernel<<<dim3(PDim / 32, Hdim / 32, 1), dim3(32, 8), 0, stream>>>(
        unpatchW, PDim, 0, unpatchWT, Hdim, 0);
    trans_kernel<<<dim3(UVW / 32, Hdim / 32, NLAY), dim3(32, 8), 0, stream>>>(
        Wuv, UVW, (long long)Hdim * UVW, WuvT, Hdim, (long long)UVW * Hdim);
    trans_kernel<<<dim3(Hdim / 32, Edim / 32, NLAY), dim3(32, 8), 0, stream>>>(
        Wout, Hdim, (long long)Edim * Hdim, WoutT, Edim, (long long)Hdim * Edim);

    gemm_bf16<0><<<(Hdim / 128) * (Mrows / 128), 256, 0, stream>>>(
        xp, PDim, patchWT, PDim, h, Hdim, PDim, Hdim, Hdim / 128);
    bias_kernel<<<Mrows, 256, 0, stream>>>(h, t_emb, t_idx);

    rmsnorm_kernel<0><<<Mrows / 4, 256, 0, stream>>>(h, nullptr, gnorm, xn);
    for (int l = 0; l < NLAY; ++l) {
        gemm_uvqk8<<<13 * (Mrows / 256), 512, 0, stream>>>(
            xn, WuvT + (size_t)l * UVW * Hdim, uT, vT, qh, kh, pe);
        fused_attn<<<dim3(8, 4, Bsz), 256, 0, stream>>>(qh, kh, vT, uT, o_bf);
        gemm_wout<<<768, 256, 0, stream>>>(
            o_bf, WoutT + (size_t)l * Hdim * Edim, pbuf);
        const float* nw = (l + 1 < NLAY) ? gnorm + (size_t)(l + 1) * Hdim : fnorm;
        rmsnorm_kernel<1><<<Mrows / 4, 256, 0, stream>>>(h, pbuf, nw, xn);
    }

    gemm_bf16<0><<<2 * (Mrows / 128), 256, 0, stream>>>(
        xn, Hdim, unpatchWT, Hdim, y, PDim, Hdim, PDim, 2);
    unpatch_kernel<<<Bsz * 3 * IMG, IMG, 0, stream>>>(y, out);
}

// Round 9
// 2685.395 us; speedup vs baseline: 5.2111x; 1.0505x over previous
//
#include <hip/hip_runtime.h>
#include <math.h>

#define IMG   128
#define Hdim  768
#define Edim  1536
#define Ltok  256
#define PDim  192
#define NLAY  24
#define Bsz   16
#define Mrows 4096          // B * L
#define UVW   3328          // 2E + 2K

typedef __bf16 bf16x8 __attribute__((ext_vector_type(8)));
typedef float  f32x4  __attribute__((ext_vector_type(4)));

__device__ __forceinline__ unsigned short f2b(float f) {
    unsigned int u = __float_as_uint(f);
    unsigned int r = (u + 0x7FFF + ((u >> 16) & 1)) >> 16;
    return (unsigned short)r;
}
__device__ __forceinline__ float b2f(unsigned short s) {
    return __uint_as_float((unsigned int)s << 16);
}
__device__ __forceinline__ unsigned int pk2(float lo, float hi) {
    return (unsigned int)f2b(lo) | ((unsigned int)f2b(hi) << 16);
}
__device__ __forceinline__ float silu(float x) {
    return x / (1.0f + expf(-x));
}
__device__ __forceinline__ void gload16(const void* g, void* l) {
    __builtin_amdgcn_global_load_lds(
        (const __attribute__((address_space(1))) void*)g,
        (__attribute__((address_space(3))) void*)l, 16, 0, 0);
}
// bijective XCD-chunking remap (m204)
__device__ __forceinline__ int xcd_wg() {
    int nwg = gridDim.x;
    int orig = blockIdx.x;
    int q8 = nwg >> 3, r8 = nwg & 7;
    int xcd = orig & 7, loc = orig >> 3;
    return (xcd < r8 ? xcd * (q8 + 1) : r8 * (q8 + 1) + (xcd - r8) * q8) + loc;
}

// ---------------- RoPE table ----------------
__global__ void pe_kernel(float* __restrict__ pe) {
    int l = blockIdx.x;
    int j = threadIdx.x;
    const float c = -logf(1000.0f) / 31.0f;
    int   sub = j & 31;
    float f   = expf(c * (float)sub);
    float pos = (j < 64) ? (float)(l >> 4) : (float)(l & 15);
    float ang = pos * f;
    pe[l * 128 + j] = ((j & 32) == 0) ? sinf(ang) : cosf(ang);
}

// ---------------- patchify -> bf16 ----------------
__global__ void patchify_kernel(const float* __restrict__ x, unsigned short* __restrict__ xp) {
    int bc = blockIdx.x;
    int iy = bc & 127;
    int t  = bc >> 7;
    int c  = t % 3;
    int b  = t / 3;
    int ix = threadIdx.x;
    float v = x[((size_t)(b * 3 + c) * IMG + iy) * IMG + ix];
    int gy = iy >> 3, py = iy & 7, gx = ix >> 3, px = ix & 7;
    xp[(size_t)(b * Ltok + gy * 16 + gx) * PDim + (py * 8 + px) * 3 + c] = f2b(v);
}

// ---------------- fp32 [R][C] -> bf16 transposed [C][R] ----------------
__global__ void trans_kernel(const float* __restrict__ src, int ldS, long long sS,
                             unsigned short* __restrict__ dst, int ldD, long long sD) {
    src += (long long)blockIdx.z * sS;
    dst += (long long)blockIdx.z * sD;
    __shared__ float t[32][33];
    int c0 = blockIdx.x * 32, r0 = blockIdx.y * 32;
    int tx = threadIdx.x, ty = threadIdx.y;   // (32,8)
#pragma unroll
    for (int i = 0; i < 4; ++i)
        t[ty + 8 * i][tx] = src[(size_t)(r0 + ty + 8 * i) * ldS + c0 + tx];
    __syncthreads();
#pragma unroll
    for (int i = 0; i < 4; ++i)
        dst[(size_t)(c0 + ty + 8 * i) * ldD + r0 + tx] = f2b(t[tx][ty + 8 * i]);
}

// ================= generic bf16 MFMA GEMM, double-buffered, XCD-swizzled ====
template <int ACC>
__launch_bounds__(256)
__global__ void gemm_bf16(const unsigned short* __restrict__ A, int lda,
                          const unsigned short* __restrict__ Bt, int ldb,
                          float* __restrict__ C, int ldc,
                          int Kt, int Nt, int nbx) {
    __shared__ unsigned short lsA[2][4096];
    __shared__ unsigned short lsB[2][4096];
    int wg = xcd_wg();
    int bx = wg % nbx, by = wg / nbx;
    int tid  = threadIdx.x;
    int lane = tid & 63, w = tid >> 6, wr = w >> 1, wc = w & 1;
    int row0 = by * 128, col0 = bx * 128;
    int fr = lane & 15, fk = (lane >> 4) * 8;
    f32x4 acc[4][4] = {};

    int c0 = tid, c1 = tid + 256;
    int ar0 = row0 + (c0 >> 2), ar1 = row0 + (c1 >> 2);
    int bn0 = col0 + (c0 >> 2), bn1 = col0 + (c1 >> 2);
    if (bn0 > Nt - 1) bn0 = Nt - 1;
    if (bn1 > Nt - 1) bn1 = Nt - 1;
    int ka0 = (c0 & 3) * 8, ka1 = (c1 & 3) * 8;

#define STAGE_G(buf, k0)                                                       \
    gload16(A  + (size_t)ar0 * lda + (k0) + ka0, &lsA[buf][c0 * 8]);           \
    gload16(A  + (size_t)ar1 * lda + (k0) + ka1, &lsA[buf][c1 * 8]);           \
    gload16(Bt + (size_t)bn0 * ldb + (k0) + ka0, &lsB[buf][c0 * 8]);           \
    gload16(Bt + (size_t)bn1 * ldb + (k0) + ka1, &lsB[buf][c1 * 8]);

    STAGE_G(0, 0);
    __syncthreads();
    int nt = Kt >> 5, cur = 0;
    for (int t = 0; t < nt; ++t) {
        if (t + 1 < nt) { STAGE_G(cur ^ 1, (t + 1) * 32); }
        bf16x8 af[4], bfr[4];
#pragma unroll
        for (int m = 0; m < 4; ++m)
            af[m] = *(const bf16x8*)(&lsA[cur][(wr * 64 + m * 16 + fr) * 32 + fk]);
#pragma unroll
        for (int n = 0; n < 4; ++n)
            bfr[n] = *(const bf16x8*)(&lsB[cur][(wc * 64 + n * 16 + fr) * 32 + fk]);
#pragma unroll
        for (int m = 0; m < 4; ++m)
#pragma unroll
            for (int n = 0; n < 4; ++n)
                acc[m][n] = __builtin_amdgcn_mfma_f32_16x16x32_bf16(af[m], bfr[n], acc[m][n], 0, 0, 0);
        __syncthreads();
        cur ^= 1;
    }
#undef STAGE_G

    int crow = (lane >> 4) * 4;
#pragma unroll
    for (int m = 0; m < 4; ++m) {
#pragma unroll
        for (int n = 0; n < 4; ++n) {
            int gc = col0 + wc * 64 + n * 16 + fr;
            if (gc >= Nt) continue;
#pragma unroll
            for (int j = 0; j < 4; ++j) {
                size_t idx = (size_t)(row0 + wr * 64 + m * 16 + crow + j) * ldc + gc;
                if (ACC) C[idx] += acc[m][n][j];
                else     C[idx]  = acc[m][n][j];
            }
        }
    }
}

// ================= wout GEMM, split-K=4, bf16 partials =======================
// A = o_bf [4096][1536], Bt = WoutT_l [768][1536]. grid 768: sk|by|bx.
// P[sk][4096][768] bf16 partials (residual add fused into next rmsnorm).
__launch_bounds__(256)
__global__ void gemm_wout(const unsigned short* __restrict__ A,
                          const unsigned short* __restrict__ Bt,
                          unsigned short* __restrict__ P) {
    __shared__ unsigned short lsA[2][4096];
    __shared__ unsigned short lsB[2][4096];
    int wg = xcd_wg();
    int sk = wg / 192, rem = wg % 192;
    int bx = rem % 6, by = rem / 6;
    int koff = sk * 384;
    unsigned short* C = P + (size_t)sk * Mrows * Hdim;
    int tid  = threadIdx.x;
    int lane = tid & 63, w = tid >> 6, wr = w >> 1, wc = w & 1;
    int row0 = by * 128, col0 = bx * 128;
    int fr = lane & 15, fk = (lane >> 4) * 8;
    f32x4 acc[4][4] = {};

    int c0 = tid, c1 = tid + 256;
    int ar0 = row0 + (c0 >> 2), ar1 = row0 + (c1 >> 2);
    int bn0 = col0 + (c0 >> 2), bn1 = col0 + (c1 >> 2);
    int ka0 = koff + (c0 & 3) * 8, ka1 = koff + (c1 & 3) * 8;

#define STAGE_W(buf, k0)                                                       \
    gload16(A  + (size_t)ar0 * Edim + (k0) + ka0, &lsA[buf][c0 * 8]);          \
    gload16(A  + (size_t)ar1 * Edim + (k0) + ka1, &lsA[buf][c1 * 8]);          \
    gload16(Bt + (size_t)bn0 * Edim + (k0) + ka0, &lsB[buf][c0 * 8]);          \
    gload16(Bt + (size_t)bn1 * Edim + (k0) + ka1, &lsB[buf][c1 * 8]);

    STAGE_W(0, 0);
    __syncthreads();
    int cur = 0;
    for (int t = 0; t < 12; ++t) {
        if (t + 1 < 12) { STAGE_W(cur ^ 1, (t + 1) * 32); }
        bf16x8 af[4], bfr[4];
#pragma unroll
        for (int m = 0; m < 4; ++m)
            af[m] = *(const bf16x8*)(&lsA[cur][(wr * 64 + m * 16 + fr) * 32 + fk]);
#pragma unroll
        for (int n = 0; n < 4; ++n)
            bfr[n] = *(const bf16x8*)(&lsB[cur][(wc * 64 + n * 16 + fr) * 32 + fk]);
#pragma unroll
        for (int m = 0; m < 4; ++m)
#pragma unroll
            for (int n = 0; n < 4; ++n)
                acc[m][n] = __builtin_amdgcn_mfma_f32_16x16x32_bf16(af[m], bfr[n], acc[m][n], 0, 0, 0);
        __syncthreads();
        cur ^= 1;
    }
#undef STAGE_W

    int crow = (lane >> 4) * 4;
#pragma unroll
    for (int m = 0; m < 4; ++m) {
#pragma unroll
        for (int n = 0; n < 4; ++n) {
            int gc = col0 + wc * 64 + n * 16 + fr;
#pragma unroll
            for (int j = 0; j < 4; ++j)
                C[(size_t)(row0 + wr * 64 + m * 16 + crow + j) * Hdim + gc] = f2b(acc[m][n][j]);
        }
    }
}

// ================= uvqk GEMM: 256x256 tile, 8-phase counted-vmcnt pipeline ===
// A = xn [4096][768], Bt = WuvT_l [3328][768]. Grid 208 = 13 bx * 16 by, 512 thr.
// BK=64, 2-K-tile double buffer, T2 XOR-swizzle, T5 setprio.
// col-tiles 0-5: silu->uT; 6-11: silu->vT; 12: rope->qh/kh.
// Epilogue: LDS-transposed coalesced stores (512B-contiguous per e-row).
__global__ __launch_bounds__(512, 2)
void gemm_uvqk8(const unsigned short* __restrict__ A,
                const unsigned short* __restrict__ Bt,
                unsigned short* __restrict__ uT,
                unsigned short* __restrict__ vT,
                unsigned short* __restrict__ qh,
                unsigned short* __restrict__ kh,
                const float* __restrict__ pe) {
    __shared__ char smem[131072];   // 2 bufs * (A 2x16KB + B 2x16KB)
    int wg = xcd_wg();
    int bx = wg % 13, by = wg / 13;
    int tid = threadIdx.x, lane = tid & 63, wid = tid >> 6;
    int wm = wid >> 2, wn = wid & 3;            // 2 x 4 wave grid
    int row0 = by * 256, col0 = bx * 256;
    int fr = lane & 15, hi = lane >> 4;
    f32x4 acc[8][4] = {};

    // ---- staging: linear LDS dest, pre-swizzled global source ----
    int d0 = tid * 16, d1 = d0 + 8192;
    int s0 = d0 ^ (((d0 >> 7) & 7) << 4);
    int s1 = d1 ^ (((d1 >> 7) & 7) << 4);
    int sr0 = s0 >> 7, sc0 = (s0 & 127) >> 1;
    int sr1 = s1 >> 7, sc1 = (s1 & 127) >> 1;

#define STG_A(bufo, h, kt) do {                                                            \
    gload16(A + (size_t)(row0 + (h) * 128 + sr0) * Hdim + (kt) * 64 + sc0,                 \
            smem + (bufo) + (h) * 16384 + d0);                                             \
    gload16(A + (size_t)(row0 + (h) * 128 + sr1) * Hdim + (kt) * 64 + sc1,                 \
            smem + (bufo) + (h) * 16384 + d1); } while (0)
#define STG_B(bufo, h, kt) do {                                                            \
    gload16(Bt + (size_t)(col0 + (h) * 128 + sr0) * Hdim + (kt) * 64 + sc0,                \
            smem + (bufo) + 32768 + (h) * 16384 + d0);                                     \
    gload16(Bt + (size_t)(col0 + (h) * 128 + sr1) * Hdim + (kt) * 64 + sc1,                \
            smem + (bufo) + 32768 + (h) * 16384 + d1); } while (0)

    // ---- ds_read fragment addressing (swizzled) ----
    int axor = (fr & 7) << 4;
    int abase = wm * 16384 + fr * 128;
    int bbase = 32768 + (wn >> 1) * 16384 + ((wn & 1) * 64 + fr) * 128;
    int koff0 = (hi * 16) ^ axor;
    int koff1 = (hi * 16 + 64) ^ axor;

    // ---- prologue: kt0 (all 4 halves) + kt1 A-halves ----
    STG_A(0, 0, 0); STG_A(0, 1, 0); STG_B(0, 0, 0); STG_B(0, 1, 0);
    STG_A(65536, 0, 1); STG_A(65536, 1, 1);
    asm volatile("s_waitcnt vmcnt(4)" ::: "memory");
    __builtin_amdgcn_s_barrier();
    __builtin_amdgcn_sched_barrier(0);

    bf16x8 af[4][2], bf0[2][2], bf1[2][2];
    const int NKT = Hdim / 64;   // 12
    for (int kt = 0; kt < NKT; ++kt) {
        int curo = (kt & 1) << 16, nxto = curo ^ 65536;
        const char* bufc = smem + curo;

        // ---- phase 0: (mh0, nh0) ----
#pragma unroll
        for (int m = 0; m < 4; ++m) {
            af[m][0] = *(const bf16x8*)(bufc + abase + m * 2048 + koff0);
            af[m][1] = *(const bf16x8*)(bufc + abase + m * 2048 + koff1);
        }
#pragma unroll
        for (int n = 0; n < 2; ++n) {
            bf0[n][0] = *(const bf16x8*)(bufc + bbase + n * 2048 + koff0);
            bf0[n][1] = *(const bf16x8*)(bufc + bbase + n * 2048 + koff1);
        }
        if (kt + 1 < NKT) STG_B(nxto, 0, kt + 1);
        __builtin_amdgcn_s_setprio(1);
#pragma unroll
        for (int m = 0; m < 4; ++m)
#pragma unroll
            for (int n = 0; n < 2; ++n) {
                acc[m][n] = __builtin_amdgcn_mfma_f32_16x16x32_bf16(af[m][0], bf0[n][0], acc[m][n], 0, 0, 0);
                acc[m][n] = __builtin_amdgcn_mfma_f32_16x16x32_bf16(af[m][1], bf0[n][1], acc[m][n], 0, 0, 0);
            }
        __builtin_amdgcn_s_setprio(0);
        __builtin_amdgcn_s_barrier();
        __builtin_amdgcn_sched_barrier(0);

        // ---- phase 1: (mh0, nh1) ----
#pragma unroll
        for (int n = 0; n < 2; ++n) {
            bf1[n][0] = *(const bf16x8*)(bufc + bbase + (n + 2) * 2048 + koff0);
            bf1[n][1] = *(const bf16x8*)(bufc + bbase + (n + 2) * 2048 + koff1);
        }
        if (kt + 1 < NKT) STG_B(nxto, 1, kt + 1);
        __builtin_amdgcn_s_setprio(1);
#pragma unroll
        for (int m = 0; m < 4; ++m)
#pragma unroll
            for (int n = 0; n < 2; ++n) {
                acc[m][n + 2] = __builtin_amdgcn_mfma_f32_16x16x32_bf16(af[m][0], bf1[n][0], acc[m][n + 2], 0, 0, 0);
                acc[m][n + 2] = __builtin_amdgcn_mfma_f32_16x16x32_bf16(af[m][1], bf1[n][1], acc[m][n + 2], 0, 0, 0);
            }
        __builtin_amdgcn_s_setprio(0);
        __builtin_amdgcn_s_barrier();
        __builtin_amdgcn_sched_barrier(0);

        // ---- phase 2: (mh1, nh0) ----
#pragma unroll
        for (int m = 0; m < 4; ++m) {
            af[m][0] = *(const bf16x8*)(bufc + abase + (m + 4) * 2048 + koff0);
            af[m][1] = *(const bf16x8*)(bufc + abase + (m + 4) * 2048 + koff1);
        }
        __builtin_amdgcn_s_setprio(1);
#pragma unroll
        for (int m = 0; m < 4; ++m)
#pragma unroll
            for (int n = 0; n < 2; ++n) {
                acc[m + 4][n] = __builtin_amdgcn_mfma_f32_16x16x32_bf16(af[m][0], bf0[n][0], acc[m + 4][n], 0, 0, 0);
                acc[m + 4][n] = __builtin_amdgcn_mfma_f32_16x16x32_bf16(af[m][1], bf0[n][1], acc[m + 4][n], 0, 0, 0);
            }
        __builtin_amdgcn_s_setprio(0);
        __builtin_amdgcn_s_barrier();
        __builtin_amdgcn_sched_barrier(0);

        // ---- phase 3: (mh1, nh1) ----
        if (kt + 2 < NKT) { STG_A(curo, 0, kt + 2); STG_A(curo, 1, kt + 2); }
        __builtin_amdgcn_s_setprio(1);
#pragma unroll
        for (int m = 0; m < 4; ++m)
#pragma unroll
            for (int n = 0; n < 2; ++n) {
                acc[m + 4][n + 2] = __builtin_amdgcn_mfma_f32_16x16x32_bf16(af[m][0], bf1[n][0], acc[m + 4][n + 2], 0, 0, 0);
                acc[m + 4][n + 2] = __builtin_amdgcn_mfma_f32_16x16x32_bf16(af[m][1], bf1[n][1], acc[m + 4][n + 2], 0, 0, 0);
            }
        __builtin_amdgcn_s_setprio(0);
        asm volatile("s_waitcnt vmcnt(4)" ::: "memory");
        __builtin_amdgcn_s_barrier();
        __builtin_amdgcn_sched_barrier(0);
    }
#undef STG_A
#undef STG_B

    // ================= epilogue =================
    if (bx == 12) {
        // rope: 4 passes of 64 rows through LDS (fp32), q cols 0-127, k 128-255
        float* S = (float*)smem;
        const float qscale = 0.08838834764831845f;   // 128^-0.5
#pragma unroll
        for (int p = 0; p < 4; ++p) {
            __syncthreads();
            if (wm == (p >> 1)) {
#pragma unroll
                for (int m = 0; m < 4; ++m) {
                    int mf = (p & 1) * 4 + m;
                    int rl = m * 16 + hi * 4;
#pragma unroll
                    for (int n = 0; n < 4; ++n) {
                        int cl = wn * 64 + n * 16 + fr;
#pragma unroll
                        for (int j = 0; j < 4; ++j)
                            S[(rl + j) * 256 + cl] = acc[mf][n][j];
                    }
                }
            }
            __syncthreads();
            int r = tid >> 3;
            int dbase = (tid & 7) * 8;
            int row_g = row0 + p * 64 + r;
            int l = row_g & 255;
#pragma unroll
            for (int i = 0; i < 8; ++i) {
                int d = dbase + i;
                float sn = pe[l * 128 + d], cs = pe[l * 128 + 64 + d];
                float q1 = S[r * 256 + d],       q2 = S[r * 256 + d + 64];
                float k1 = S[r * 256 + d + 128], k2 = S[r * 256 + d + 192];
                qh[(size_t)row_g * 128 + d]      = f2b((q1 * cs - q2 * sn) * qscale);
                qh[(size_t)row_g * 128 + d + 64] = f2b((q2 * cs + q1 * sn) * qscale);
                kh[(size_t)row_g * 128 + d]      = f2b(k1 * cs - k2 * sn);
                kh[(size_t)row_g * 128 + d + 64] = f2b(k2 * cs + k1 * sn);
            }
        }
        return;
    }

    // ---- silu tiles: stage bf16 [e_local][m_local] in LDS (swizzled), ----
    // ---- then write 512B-contiguous rows (uT[e][m] / vT[b][e][l]).     ----
    __syncthreads();
#pragma unroll
    for (int mf = 0; mf < 8; ++mf) {
        int m_l = wm * 128 + mf * 16 + hi * 4;
#pragma unroll
        for (int nf = 0; nf < 4; ++nf) {
            int e_l = wn * 64 + nf * 16 + fr;
            ushort4 pk;
            pk.x = f2b(silu(acc[mf][nf][0]));
            pk.y = f2b(silu(acc[mf][nf][1]));
            pk.z = f2b(silu(acc[mf][nf][2]));
            pk.w = f2b(silu(acc[mf][nf][3]));
            int byte = (e_l * 512 + m_l * 2) ^ ((e_l & 7) << 4);
            *(ushort4*)(smem + byte) = pk;
        }
    }
    __syncthreads();
    int er = tid >> 5;                 // 0..15
    int ch = (tid & 31) * 16;          // byte chunk within 512B row
#pragma unroll
    for (int it = 0; it < 16; ++it) {
        int e_l = it * 16 + er;
        int byte = (e_l * 512 + ch) ^ ((e_l & 7) << 4);
        int4 v = *(const int4*)(smem + byte);
        unsigned short* dst;
        if (bx < 6) {
            dst = uT + (size_t)(col0 + e_l) * Mrows + row0;
        } else {
            int e = col0 + e_l - Edim;
            dst = vT + ((size_t)(row0 >> 8) * Edim + e) * Ltok;
        }
        *(int4*)((char*)dst + ch) = v;
    }
}

// ================= fused attention: softmax(q̂k̂ᵀ) @ V ⊙ u -> o_bf =================
__launch_bounds__(256)
__global__ void fused_attn(const unsigned short* __restrict__ qh,
                           const unsigned short* __restrict__ kh,
                           const unsigned short* __restrict__ vT,
                           const unsigned short* __restrict__ uT,
                           unsigned short* __restrict__ ob) {
    int ec = blockIdx.x, qt = blockIdx.y, b = blockIdx.z;
    int tid  = threadIdx.x;
    int lane = tid & 63, w = tid >> 6;
    int fr = lane & 15, hi = lane >> 4;
    int qbase = b * 256 + qt * 64 + w * 16;

    bf16x8 qf[4];
#pragma unroll
    for (int ks = 0; ks < 4; ++ks)
        qf[ks] = *(const bf16x8*)(qh + (size_t)(qbase + fr) * 128 + ks * 32 + hi * 8);
    f32x4 sacc[16] = {};
#pragma unroll
    for (int mf = 0; mf < 16; ++mf) {
#pragma unroll
        for (int ks = 0; ks < 4; ++ks) {
            bf16x8 kf = *(const bf16x8*)(kh + (size_t)(b * 256 + mf * 16 + fr) * 128 + ks * 32 + hi * 8);
            sacc[mf] = __builtin_amdgcn_mfma_f32_16x16x32_bf16(kf, qf[ks], sacc[mf], 0, 0, 0);
        }
    }

    float mx = -3.4e38f;
#pragma unroll
    for (int mf = 0; mf < 16; ++mf)
#pragma unroll
        for (int j = 0; j < 4; ++j)
            mx = fmaxf(mx, sacc[mf][j]);
    mx = fmaxf(mx, __shfl_xor(mx, 16, 64));
    mx = fmaxf(mx, __shfl_xor(mx, 32, 64));
    float sum = 0.f;
#pragma unroll
    for (int mf = 0; mf < 16; ++mf)
#pragma unroll
        for (int j = 0; j < 4; ++j) {
            float e = expf(sacc[mf][j] - mx);
            sacc[mf][j] = e;
            sum += e;
        }
    sum += __shfl_xor(sum, 16, 64);
    sum += __shfl_xor(sum, 32, 64);
    float inv = 1.0f / sum;

    unsigned int dw[16][2];
#pragma unroll
    for (int mf = 0; mf < 16; ++mf) {
        dw[mf][0] = pk2(sacc[mf][0] * inv, sacc[mf][1] * inv);
        dw[mf][1] = pk2(sacc[mf][2] * inv, sacc[mf][3] * inv);
    }

    int sA = fr + 32 * (hi & 1);
    int sB = sA + 16;
    bool up = (hi >> 1) != 0;
    unsigned int pa[8][4];
#pragma unroll
    for (int ks = 0; ks < 8; ++ks) {
        unsigned int a00 = __shfl((int)dw[2 * ks][0],     sA, 64);
        unsigned int a01 = __shfl((int)dw[2 * ks + 1][0], sA, 64);
        unsigned int a10 = __shfl((int)dw[2 * ks][1],     sA, 64);
        unsigned int a11 = __shfl((int)dw[2 * ks + 1][1], sA, 64);
        unsigned int b00 = __shfl((int)dw[2 * ks][0],     sB, 64);
        unsigned int b01 = __shfl((int)dw[2 * ks + 1][0], sB, 64);
        unsigned int b10 = __shfl((int)dw[2 * ks][1],     sB, 64);
        unsigned int b11 = __shfl((int)dw[2 * ks + 1][1], sB, 64);
        pa[ks][0] = up ? a01 : a00;
        pa[ks][1] = up ? a11 : a10;
        pa[ks][2] = up ? b01 : b00;
        pa[ks][3] = up ? b11 : b10;
    }

    const unsigned short* vb = vT + (size_t)b * Edim * Ltok;
    int e0 = ec * 192;
#pragma unroll 2
    for (int ef = 0; ef < 12; ++ef) {
        int e = e0 + ef * 16 + fr;
        f32x4 oacc = {};
#pragma unroll
        for (int ks = 0; ks < 8; ++ks) {
            bf16x8 vf = *(const bf16x8*)(vb + (size_t)e * Ltok + ks * 32 + hi * 8);
            oacc = __builtin_amdgcn_mfma_f32_16x16x32_bf16(*(const bf16x8*)&pa[ks], vf, oacc, 0, 0, 0);
        }
        ushort4 uv = *(const ushort4*)(uT + (size_t)e * Mrows + qbase + hi * 4);
        ob[(size_t)(qbase + hi * 4 + 0) * Edim + e] = f2b(oacc[0] * b2f(uv.x));
        ob[(size_t)(qbase + hi * 4 + 1) * Edim + e] = f2b(oacc[1] * b2f(uv.y));
        ob[(size_t)(qbase + hi * 4 + 2) * Edim + e] = f2b(oacc[2] * b2f(uv.z));
        ob[(size_t)(qbase + hi * 4 + 3) * Edim + e] = f2b(oacc[3] * b2f(uv.w));
    }
}

// ------ rmsnorm + t_emb bias (entry): h += emb; y = norm(h) -----------------
__global__ void rmsnorm_bias(float* __restrict__ x, const float* __restrict__ t_emb,
                             const int* __restrict__ t_idx, const float* __restrict__ w,
                             unsigned short* __restrict__ y) {
    int r = blockIdx.x * 4 + (threadIdx.x >> 6);
    int lane = threadIdx.x & 63;
    const float* e = t_emb + (size_t)t_idx[r >> 8] * Hdim;
    float* xr = x + (size_t)r * Hdim;
    float4 a = *(const float4*)&xr[lane * 4];
    float4 b = *(const float4*)&xr[lane * 4 + 256];
    float4 c = *(const float4*)&xr[lane * 4 + 512];
    float4 ea = *(const float4*)&e[lane * 4];
    float4 eb = *(const float4*)&e[lane * 4 + 256];
    float4 ec = *(const float4*)&e[lane * 4 + 512];
    a.x += ea.x; a.y += ea.y; a.z += ea.z; a.w += ea.w;
    b.x += eb.x; b.y += eb.y; b.z += eb.z; b.w += eb.w;
    c.x += ec.x; c.y += ec.y; c.z += ec.z; c.w += ec.w;
    *(float4*)&xr[lane * 4]       = a;
    *(float4*)&xr[lane * 4 + 256] = b;
    *(float4*)&xr[lane * 4 + 512] = c;
    float ss = a.x * a.x + a.y * a.y + a.z * a.z + a.w * a.w
             + b.x * b.x + b.y * b.y + b.z * b.z + b.w * b.w
             + c.x * c.x + c.y * c.y + c.z * c.z + c.w * c.w;
#pragma unroll
    for (int o = 1; o < 64; o <<= 1) ss += __shfl_xor(ss, o, 64);
    float s = 1.0f / (sqrtf(ss / (float)Hdim) + 1e-6f);
    float4 wa = *(const float4*)&w[lane * 4];
    float4 wb = *(const float4*)&w[lane * 4 + 256];
    float4 wc = *(const float4*)&w[lane * 4 + 512];
    unsigned short* yr = y + (size_t)r * Hdim;
    ushort4 o0, o1, o2;
    o0.x = f2b(a.x * s * wa.x); o0.y = f2b(a.y * s * wa.y);
    o0.z = f2b(a.z * s * wa.z); o0.w = f2b(a.w * s * wa.w);
    o1.x = f2b(b.x * s * wb.x); o1.y = f2b(b.y * s * wb.y);
    o1.z = f2b(b.z * s * wb.z); o1.w = f2b(b.w * s * wb.w);
    o2.x = f2b(c.x * s * wc.x); o2.y = f2b(c.y * s * wc.y);
    o2.z = f2b(c.z * s * wc.z); o2.w = f2b(c.w * s * wc.w);
    *(ushort4*)&yr[lane * 4]       = o0;
    *(ushort4*)&yr[lane * 4 + 256] = o1;
    *(ushort4*)&yr[lane * 4 + 512] = o2;
}

// ------ rmsnorm with bf16 split-K partial fold: h += Σ p[s]; y = norm(h) ----
__global__ void rmsnorm_acc(float* __restrict__ x, const unsigned short* __restrict__ p,
                            const float* __restrict__ w, unsigned short* __restrict__ y) {
    int r = blockIdx.x * 4 + (threadIdx.x >> 6);
    int lane = threadIdx.x & 63;
    float* xr = x + (size_t)r * Hdim;
    float4 a = *(const float4*)&xr[lane * 4];
    float4 b = *(const float4*)&xr[lane * 4 + 256];
    float4 c = *(const float4*)&xr[lane * 4 + 512];
#pragma unroll
    for (int s = 0; s < 4; ++s) {
        const unsigned short* ps = p + (size_t)(s * Mrows + r) * Hdim;
        ushort4 a0 = *(const ushort4*)&ps[lane * 4];
        ushort4 b0 = *(const ushort4*)&ps[lane * 4 + 256];
        ushort4 c0 = *(const ushort4*)&ps[lane * 4 + 512];
        a.x += b2f(a0.x); a.y += b2f(a0.y); a.z += b2f(a0.z); a.w += b2f(a0.w);
        b.x += b2f(b0.x); b.y += b2f(b0.y); b.z += b2f(b0.z); b.w += b2f(b0.w);
        c.x += b2f(c0.x); c.y += b2f(c0.y); c.z += b2f(c0.z); c.w += b2f(c0.w);
    }
    *(float4*)&xr[lane * 4]       = a;
    *(float4*)&xr[lane * 4 + 256] = b;
    *(float4*)&xr[lane * 4 + 512] = c;
    float ss = a.x * a.x + a.y * a.y + a.z * a.z + a.w * a.w
             + b.x * b.x + b.y * b.y + b.z * b.z + b.w * b.w
             + c.x * c.x + c.y * c.y + c.z * c.z + c.w * c.w;
#pragma unroll
    for (int o = 1; o < 64; o <<= 1) ss += __shfl_xor(ss, o, 64);
    float s = 1.0f / (sqrtf(ss / (float)Hdim) + 1e-6f);
    float4 wa = *(const float4*)&w[lane * 4];
    float4 wb = *(const float4*)&w[lane * 4 + 256];
    float4 wc = *(const float4*)&w[lane * 4 + 512];
    unsigned short* yr = y + (size_t)r * Hdim;
    ushort4 o0, o1, o2;
    o0.x = f2b(a.x * s * wa.x); o0.y = f2b(a.y * s * wa.y);
    o0.z = f2b(a.z * s * wa.z); o0.w = f2b(a.w * s * wa.w);
    o1.x = f2b(b.x * s * wb.x); o1.y = f2b(b.y * s * wb.y);
    o1.z = f2b(b.z * s * wb.z); o1.w = f2b(b.w * s * wb.w);
    o2.x = f2b(c.x * s * wc.x); o2.y = f2b(c.y * s * wc.y);
    o2.z = f2b(c.z * s * wc.z); o2.w = f2b(c.w * s * wc.w);
    *(ushort4*)&yr[lane * 4]       = o0;
    *(ushort4*)&yr[lane * 4 + 256] = o1;
    *(ushort4*)&yr[lane * 4 + 512] = o2;
}

// ---------------- unpatchify ----------------
__global__ void unpatch_kernel(const float* __restrict__ y, float* __restrict__ out) {
    int bc = blockIdx.x;
    int iy = bc & 127;
    int t  = bc >> 7;
    int c  = t % 3;
    int b  = t / 3;
    int ix = threadIdx.x;
    int gy = iy >> 3, py = iy & 7, gx = ix >> 3, px = ix & 7;
    out[((size_t)(b * 3 + c) * IMG + iy) * IMG + ix] =
        y[(size_t)(b * Ltok + gy * 16 + gx) * PDim + (py * 8 + px) * 3 + c];
}

extern "C" void kernel_launch(void* const* d_in, const int* in_sizes, int n_in,
                              void* d_out, int out_size, void* d_ws, size_t ws_size,
                              hipStream_t stream) {
    const float* x        = (const float*)d_in[0];
    const int*   t_idx    = (const int*)  d_in[1];
    const float* patch_W  = (const float*)d_in[2];
    const float* t_emb    = (const float*)d_in[3];
    const float* Wuv      = (const float*)d_in[4];
    const float* Wout     = (const float*)d_in[5];
    const float* gnorm    = (const float*)d_in[6];
    const float* fnorm    = (const float*)d_in[7];
    const float* unpatchW = (const float*)d_in[8];
    float* out = (float*)d_out;

    // ---- workspace layout ----
    char* wsb = (char*)d_ws;
    size_t off = 0;
    auto alloc = [&](size_t bytes) { char* p = wsb + off; off += (bytes + 255) & ~(size_t)255; return p; };
    float* pe   = (float*)alloc(256 * 128 * 4);
    float* h    = (float*)alloc((size_t)Mrows * Hdim * 4);
    float* y    = (float*)alloc((size_t)Mrows * PDim * 4);
    unsigned short* pbuf = (unsigned short*)alloc((size_t)4 * Mrows * Hdim * 2);
    unsigned short* xp   = (unsigned short*)alloc((size_t)Mrows * PDim * 2);
    unsigned short* xn   = (unsigned short*)alloc((size_t)Mrows * Hdim * 2);
    unsigned short* uT   = (unsigned short*)alloc((size_t)Edim * Mrows * 2);
    unsigned short* vT   = (unsigned short*)alloc((size_t)Bsz * Edim * Ltok * 2);
    unsigned short* qh   = (unsigned short*)alloc((size_t)Mrows * 128 * 2);
    unsigned short* kh   = (unsigned short*)alloc((size_t)Mrows * 128 * 2);
    unsigned short* o_bf = (unsigned short*)alloc((size_t)Mrows * Edim * 2);
    unsigned short* WuvT  = (unsigned short*)alloc((size_t)NLAY * UVW * Hdim * 2);
    unsigned short* WoutT = (unsigned short*)alloc((size_t)NLAY * Hdim * Edim * 2);
    unsigned short* patchWT   = (unsigned short*)alloc((size_t)Hdim * PDim * 2);
    unsigned short* unpatchWT = (unsigned short*)alloc((size_t)PDim * Hdim * 2);
    if (off > ws_size) return;   // distinct failure signature (out stays 0)

    pe_kernel<<<256, 128, 0, stream>>>(pe);
    patchify_kernel<<<Bsz * 3 * IMG, IMG, 0, stream>>>(x, xp);

    // weight transposes upfront (batched over layers)
    trans_kernel<<<dim3(Hdim / 32, PDim / 32, 1), dim3(32, 8), 0, stream>>>(
        patch_W, Hdim, 0, patchWT, PDim, 0);
    trans_kernel<<<dim3(PDim / 32, Hdim / 32, 1), dim3(32, 8), 0, stream>>>(
        unpatchW, PDim, 0, unpatchWT, Hdim, 0);
    trans_kernel<<<dim3(UVW / 32, Hdim / 32, NLAY), dim3(32, 8), 0, stream>>>(
        Wuv, UVW, (long long)Hdim * UVW, WuvT, Hdim, (long long)UVW * Hdim);
    trans_kernel<<<dim3(Hdim / 32, Edim / 32, NLAY), dim3(32, 8), 0, stream>>>(
        Wout, Hdim, (long long)Edim * Hdim, WoutT, Edim, (long long)Hdim * Edim);

    gemm_bf16<0><<<(Hdim / 128) * (Mrows / 128), 256, 0, stream>>>(
        xp, PDim, patchWT, PDim, h, Hdim, PDim, Hdim, Hdim / 128);

    rmsnorm_bias<<<Mrows / 4, 256, 0, stream>>>(h, t_emb, t_idx, gnorm, xn);
    for (int l = 0; l < NLAY; ++l) {
        gemm_uvqk8<<<13 * (Mrows / 256), 512, 0, stream>>>(
            xn, WuvT + (size_t)l * UVW * Hdim, uT, vT, qh, kh, pe);
        fused_attn<<<dim3(8, 4, Bsz), 256, 0, stream>>>(qh, kh, vT, uT, o_bf);
        gemm_wout<<<768, 256, 0, stream>>>(
            o_bf, WoutT + (size_t)l * Hdim * Edim, pbuf);
        const float* nw = (l + 1 < NLAY) ? gnorm + (size_t)(l + 1) * Hdim : fnorm;
        rmsnorm_acc<<<Mrows / 4, 256, 0, stream>>>(h, pbuf, nw, xn);
    }

    gemm_bf16<0><<<2 * (Mrows / 128), 256, 0, stream>>>(
        xn, Hdim, unpatchWT, Hdim, y, PDim, Hdim, PDim, 2);
    unpatch_kernel<<<Bsz * 3 * IMG, IMG, 0, stream>>>(y, out);
}